// Round 11
// baseline (4399.246 us; speedup 1.0000x reference)
//
#include <hip/hip_runtime.h>
#include <hip/hip_bf16.h>

typedef __hip_bfloat16 bf16;
typedef __attribute__((ext_vector_type(8))) short v8bf;     // 8 bf16 (4 VGPR)
typedef __attribute__((ext_vector_type(16))) float f32x16;
typedef __attribute__((ext_vector_type(4))) float f32x4;
typedef unsigned long long ull;

#define B_    256
#define SEED_ 120
#define PRED_ 24
#define D_    126
#define H_    1024
#define F_    61
#define HEADS_ 4
#define DH_   256

#define GLD16(lds, g) __builtin_amdgcn_global_load_lds( \
    (const __attribute__((address_space(1))) unsigned int*)(g), \
    (__attribute__((address_space(3))) unsigned int*)(lds), 16, 0, 0)
#define VMWAIT(n) asm volatile("s_waitcnt vmcnt(" #n ")" ::: "memory")
#define BARRIER() do { __builtin_amdgcn_s_barrier(); __builtin_amdgcn_sched_barrier(0); } while(0)
#define AL(P) __hip_atomic_load((P), __ATOMIC_RELAXED, __HIP_MEMORY_SCOPE_AGENT)

// ---------------- small precompute kernels ----------------
__global__ void k_cos(float* cosT){
  int i = blockIdx.x*256 + threadIdx.x;
  if (i < F_*SEED_){
    int f = i / SEED_, t = i % SEED_;
    int ph = (f*t) % SEED_;
    cosT[i] = cosf(6.283185307179586f * (float)ph / (float)SEED_);
  }
}

__global__ __launch_bounds__(256) void k_dft2(const float* __restrict__ poses,
                      const float* __restrict__ cosT, bf16* __restrict__ freqbf){
  __shared__ float pl[SEED_*128];      // 60 KB
  int b = blockIdx.x, tid = threadIdx.x;
  for (int i = tid; i < SEED_*D_; i += 256){
    int t = i / D_, d = i - t*D_;
    pl[t*128 + d] = poses[((size_t)b*(SEED_+PRED_) + t)*D_ + d];
  }
  __syncthreads();
  int d = tid & 127, f0 = tid >> 7;    // f = f0 + 2j
  float acc[31];
  #pragma unroll
  for (int j = 0; j < 31; ++j) acc[j] = 0.f;
  for (int t = 0; t < SEED_; ++t){
    float v = pl[t*128 + d];
    #pragma unroll
    for (int j = 0; j < 31; ++j){
      int f = f0 + j*2;
      if (f < F_) acc[j] += cosT[f*SEED_ + t] * v;
    }
  }
  #pragma unroll
  for (int j = 0; j < 31; ++j){
    int f = f0 + j*2;
    if (f < F_) freqbf[((size_t)b*F_ + f)*128 + d] = __float2bfloat16(d < D_ ? acc[j] : 0.f);
  }
}

// pack poses into per-step 32x32 tiles
__global__ void c_poses(const float* __restrict__ poses, bf16* __restrict__ pk){
  int t = blockIdx.x, b = blockIdx.y, c = threadIdx.x;  // block 128
  float v = (c < D_) ? poses[((size_t)b*(SEED_+PRED_) + t)*D_ + c] : 0.f;
  pk[(size_t)t*32768 + ((b>>5)*4 + (c>>5))*1024 + (b&31)*32 + (c&31)] = __float2bfloat16(v);
}

__global__ void c_xinit(const float* __restrict__ poses, float* __restrict__ x, bf16* __restrict__ xpk){
  int b = blockIdx.x, c = threadIdx.x;  // block 128
  float v = (c < D_) ? poses[((size_t)b*(SEED_+PRED_) + (SEED_-1))*D_ + c] : 0.f;
  if (c < D_) x[b*D_ + c] = v;
  xpk[((b>>5)*4 + (c>>5))*1024 + (b&31)*32 + (c&31)] = __float2bfloat16(v);
}

__global__ void c_bf(const float* __restrict__ s, bf16* __restrict__ d, int n){
  int i = blockIdx.x*256 + threadIdx.x;
  if (i < n) d[i] = __float2bfloat16(s[i]);
}

__global__ void c_fpwt(const float* __restrict__ fpW, bf16* __restrict__ o){
  int dd = blockIdx.x;                       // 0..127
  for (int k = threadIdx.x; k < H_; k += 256)
    o[(size_t)dd*H_ + k] = __float2bfloat16(dd < D_ ? fpW[(size_t)k*D_ + dd] : 0.f);
}

// combined GRU weight rows (1152 wide: 128 x-cols | 1024 h-cols)
__global__ void c_wcat(const float* __restrict__ Wih, const float* __restrict__ Whh, bf16* __restrict__ o){
  int r = blockIdx.x;
  int jr; bool hasx, hash;
  if (r < 2048){ jr = r; hasx = true; hash = true; }
  else if (r < 3072){ jr = r; hasx = true; hash = false; }
  else { jr = r - 1024; hasx = false; hash = true; }
  bf16* row = o + (size_t)r*1152;
  for (int c = threadIdx.x; c < 1152; c += 256){
    float v = 0.f;
    if (c < D_) { if (hasx) v = Wih[(size_t)jr*D_ + c]; }
    else if (c >= 128){ if (hash) v = Whh[(size_t)jr*H_ + (c-128)]; }
    row[c] = __float2bfloat16(v);
  }
}

__global__ void c_bcat(const float* __restrict__ bih, const float* __restrict__ bhh, float* __restrict__ o){
  int r = blockIdx.x*256 + threadIdx.x;
  if (r >= 4096) return;
  float v;
  if (r < 2048) v = bih[r] + bhh[r];
  else if (r < 3072) v = bih[r];
  else v = bhh[r - 1024];
  o[r] = v;
}

// pack GRU weights into MFMA B-fragment order
__global__ __launch_bounds__(256) void c_wpk(const bf16* __restrict__ Wcat, bf16* __restrict__ Wpk){
  int chunk = blockIdx.x*4 + (threadIdx.x >> 6);
  int l = threadIdx.x & 63;
  int ks = chunk % 36; int t2 = chunk / 36; int g = t2 % 3; int ub = t2 / 3;
  int unit = ub*16 + (l & 15);
  bf16* dst = Wpk + (size_t)chunk*512 + l*8;
  #pragma unroll
  for (int e = 0; e < 8; ++e){
    int k = ks*32 + (l>>4)*8 + e;
    int row = (g==0) ? unit : (g==1) ? (1024+unit) : (k < 128 ? 2048+unit : 3072+unit);
    dst[e] = Wcat[(size_t)row*1152 + k];
  }
}

// pack preW into fragment order: chunk = ub*32+ks
__global__ __launch_bounds__(256) void c_ppk(const float* __restrict__ preW, bf16* __restrict__ prepk){
  int chunk = blockIdx.x*4 + (threadIdx.x >> 6);   // 2048 chunks
  int l = threadIdx.x & 63;
  int ks = chunk & 31, ub = chunk >> 5;
  int unit = ub*16 + (l & 15);
  bf16* dst = prepk + (size_t)chunk*512 + l*8;
  #pragma unroll
  for (int e = 0; e < 8; ++e)
    dst[e] = __float2bfloat16(preW[(size_t)unit*1024 + ks*32 + (l>>4)*8 + e]);
}

// pack W1-hid into fragment order: chunk = ng*32+ks, ng 0..111
__global__ __launch_bounds__(256) void c_w1pk(const float* __restrict__ sW1, bf16* __restrict__ w1pk){
  int chunk = blockIdx.x*4 + (threadIdx.x >> 6);   // 3584 chunks
  int l = threadIdx.x & 63;
  int ks = chunk & 31, ng = chunk >> 5;
  int unit = ng*16 + (l & 15);
  int j = unit >> 7, rr = unit & 127;
  bf16* dst = w1pk + (size_t)chunk*512 + l*8;
  #pragma unroll
  for (int e = 0; e < 8; ++e){
    int k = ks*32 + (l>>4)*8 + e;
    dst[e] = __float2bfloat16(sW1[((size_t)j*128 + rr)*1033 + k]);
  }
}

// bc = inproj @ fp_b + in_b
__global__ __launch_bounds__(256) void k_bc(const float* __restrict__ inW, const float* __restrict__ inb,
                     const float* __restrict__ fpb, float* __restrict__ bc){
  int wave = threadIdx.x >> 6, lane = threadIdx.x & 63;
  int r = blockIdx.x*4 + wave;
  const float4* row = (const float4*)(inW + (size_t)r*H_);
  const float4* fp4 = (const float4*)fpb;
  float s = 0.f;
  #pragma unroll
  for (int i = 0; i < 4; ++i){
    float4 a = row[lane + i*64];
    float4 b = fp4[lane + i*64];
    s += a.x*b.x + a.y*b.y + a.z*b.z + a.w*b.w;
  }
  #pragma unroll
  for (int off = 32; off; off >>= 1) s += __shfl_down(s, off);
  if (lane == 0) bc[r] = s + inb[r];
}

// ---------------- encoder: wave-autonomous GRU (R10, unchanged) ----------------
#define SLCP(QA, QB, KS, GACC) { \
  union { ull u[2]; v8bf v; } cc_; cc_.u[0]=(QA); cc_.u[1]=(QB); \
  v8bf a_ = cc_.v; \
  v8bf w0_ = *(const v8bf*)&Wl[(0*36+(KS))*512 + lane*8]; \
  v8bf w1_ = *(const v8bf*)&Wl[(1*36+(KS))*512 + lane*8]; \
  v8bf w2_ = *(const v8bf*)&Wl[(2*36+(KS))*512 + lane*8]; \
  aR = __builtin_amdgcn_mfma_f32_16x16x32_bf16(a_, w0_, aR, 0,0,0); \
  aZ = __builtin_amdgcn_mfma_f32_16x16x32_bf16(a_, w1_, aZ, 0,0,0); \
  GACC = __builtin_amdgcn_mfma_f32_16x16x32_bf16(a_, w2_, GACC, 0,0,0); }

#define LDHA(DA, DB, C) { \
  const ull* hp_ = (const ull*)(hs + hbase + (size_t)(C)*1024); \
  DA = AL(hp_); DB = AL(hp_+1); }

#define LDXP(DA, DB, TT, C) { \
  const ull* xp_ = (const ull*)(xpk + (size_t)(TT)*xstride + xbase + (size_t)(C)*1024); \
  DA = xp_[0]; DB = xp_[1]; }

__global__ __launch_bounds__(512) void gru_wave(
    const bf16* __restrict__ xpk, int xstride, int nsteps, int coop,
    const bf16* __restrict__ Wpk, const float* __restrict__ bcat,
    const float* __restrict__ hin_plain, float* __restrict__ hout_plain,
    bf16* __restrict__ hbplain,
    bf16* __restrict__ hpk0, bf16* __restrict__ hpk1,
    unsigned* __restrict__ prog)
{
  __shared__ bf16 Wl[3*36*512];       // 108 KB
  const int tid = threadIdx.x, wave = tid >> 6, lane = tid & 63;
  const int ub = blockIdx.x >> 1, bs = blockIdx.x & 1;
  const int u0 = ub*16;

  {
    const bf16* wsrc = Wpk + (size_t)ub*(3*36*512);
    #pragma unroll
    for (int i = 0; i < 14; ++i){
      int c = i*512 + tid;
      if (c < 6912) GLD16(&Wl[c*8], wsrc + (size_t)c*8);
    }
  }
  VMWAIT(0); BARRIER();

  const int la = lane & 15, lb = lane >> 4;
  const int r0 = bs*128 + wave*16;
  const int rb = r0 >> 5, y = wave & 1;
  const int ucol = u0 + la;
  const float bR = bcat[ucol], bZ = bcat[1024+ucol], bI = bcat[2048+ucol], bN = bcat[3072+ucol];
  const size_t hbase = (size_t)rb*32768 + (size_t)y*512 + la*32 + lb*8;
  const size_t xbase = (size_t)rb*4096  + (size_t)y*512 + la*32 + lb*8;
  const size_t pwb = (size_t)rb*32768 + (size_t)(u0>>5)*1024 + (size_t)y*512 + (u0&16) + la;

  float hr[4];
  if (nsteps == 1){
    #pragma unroll
    for (int r = 0; r < 4; ++r) hr[r] = hin_plain[(size_t)(r0 + lb*4 + r)*1024 + ucol];
  } else {
    #pragma unroll
    for (int r = 0; r < 4; ++r) hr[r] = 0.f;
  }

  ull a0,a1,a2,a3,a4,a5,a6,a7,a8,a9,a10,a11;
  ull b0,b1,b2,b3,b4,b5,b6,b7,b8,b9,b10,b11;
  LDXP(a0,b0,0,0); LDXP(a1,b1,0,1); LDXP(a2,b2,0,2); LDXP(a3,b3,0,3);

  for (int t = 0; t < nsteps; ++t){
    if (coop && t > 0){
      if (wave == 0){
        unsigned v = AL(&prog[bs*64 + lane]);
        while (__ballot(v >= (unsigned)t) != ~0ULL){
          __builtin_amdgcn_s_sleep(1);
          v = AL(&prog[bs*64 + lane]);
        }
      }
      __syncthreads();
      __builtin_amdgcn_sched_barrier(0);
    }
    const bf16* hs = (t & 1) ? hpk1 : hpk0;
    LDHA(a4,b4,0) LDHA(a5,b5,1) LDHA(a6,b6,2) LDHA(a7,b7,3)
    LDHA(a8,b8,4) LDHA(a9,b9,5) LDHA(a10,b10,6) LDHA(a11,b11,7)

    f32x4 z4 = {0.f,0.f,0.f,0.f};
    f32x4 aR = z4, aZ = z4, aI = z4, aN = z4;

    SLCP(a0,b0,0,aI)  LDHA(a0,b0,8)
    SLCP(a1,b1,1,aI)  LDHA(a1,b1,9)
    SLCP(a2,b2,2,aI)  LDHA(a2,b2,10)
    SLCP(a3,b3,3,aI)  LDHA(a3,b3,11)
    SLCP(a4,b4,4,aN)  LDHA(a4,b4,12)
    SLCP(a5,b5,5,aN)  LDHA(a5,b5,13)
    SLCP(a6,b6,6,aN)  LDHA(a6,b6,14)
    SLCP(a7,b7,7,aN)  LDHA(a7,b7,15)
    SLCP(a8,b8,8,aN)  LDHA(a8,b8,16)
    SLCP(a9,b9,9,aN)  LDHA(a9,b9,17)
    SLCP(a10,b10,10,aN) LDHA(a10,b10,18)
    SLCP(a11,b11,11,aN) LDHA(a11,b11,19)
    SLCP(a0,b0,12,aN) LDHA(a0,b0,20)
    SLCP(a1,b1,13,aN) LDHA(a1,b1,21)
    SLCP(a2,b2,14,aN) LDHA(a2,b2,22)
    SLCP(a3,b3,15,aN) LDHA(a3,b3,23)
    SLCP(a4,b4,16,aN) LDHA(a4,b4,24)
    SLCP(a5,b5,17,aN) LDHA(a5,b5,25)
    SLCP(a6,b6,18,aN) LDHA(a6,b6,26)
    SLCP(a7,b7,19,aN) LDHA(a7,b7,27)
    SLCP(a8,b8,20,aN) LDHA(a8,b8,28)
    SLCP(a9,b9,21,aN) LDHA(a9,b9,29)
    SLCP(a10,b10,22,aN) LDHA(a10,b10,30)
    SLCP(a11,b11,23,aN) LDHA(a11,b11,31)
    SLCP(a0,b0,24,aN) LDXP(a0,b0,t+1,0)
    SLCP(a1,b1,25,aN) LDXP(a1,b1,t+1,1)
    SLCP(a2,b2,26,aN) LDXP(a2,b2,t+1,2)
    SLCP(a3,b3,27,aN) LDXP(a3,b3,t+1,3)
    SLCP(a4,b4,28,aN)
    SLCP(a5,b5,29,aN)
    SLCP(a6,b6,30,aN)
    SLCP(a7,b7,31,aN)
    SLCP(a8,b8,32,aN)
    SLCP(a9,b9,33,aN)
    SLCP(a10,b10,34,aN)
    SLCP(a11,b11,35,aN)

    bf16* hd = (t & 1) ? hpk0 : hpk1;
    const bool last = (t == nsteps-1);
    #pragma unroll
    for (int r = 0; r < 4; ++r){
      float rg = 1.f/(1.f + __expf(-(aR[r] + bR)));
      float zg = 1.f/(1.f + __expf(-(aZ[r] + bZ)));
      float ng = tanhf((aI[r] + bI) + rg*(aN[r] + bN));
      float hv = (1.f - zg)*ng + zg*hr[r];
      hr[r] = hv;
      bf16 hv16 = __float2bfloat16(hv);
      unsigned short hbits = *(unsigned short*)&hv16;
      __hip_atomic_store((unsigned short*)(hd + pwb + (size_t)(lb*4 + r)*32), hbits,
                         __ATOMIC_RELAXED, __HIP_MEMORY_SCOPE_AGENT);
      if (last){
        hout_plain[(size_t)(r0 + lb*4 + r)*1024 + ucol] = hv;
        if (hbplain) hbplain[(size_t)(r0 + lb*4 + r)*1024 + ucol] = __float2bfloat16(hv);
      }
    }
    if (coop && t + 1 < nsteps){
      VMWAIT(0);
      __syncthreads();
      if (tid == 0)
        __hip_atomic_store(&prog[bs*64 + ub], (unsigned)(t+1), __ATOMIC_RELAXED, __HIP_MEMORY_SCOPE_AGENT);
    }
  }
}

// ---------------- persistent decoder: 24 steps x {GRU, pre, W1, SPL} ----------------
__constant__ int LVJ[14] = {0,1,6,8,9, 2,3,7,10,11, 4,5,12,13};
__constant__ int LVO[4]  = {0,5,10,14};
__constant__ int PAR_[14] = {-1,-1,0,1,2,3,-1,6,-1,-1,8,9,10,11};

// GRU-phase macros (source hs / xpk)
#define GRL(S,C) { const ull* p_=(const ull*)(hs + hbase + (size_t)(C)*1024); qa##S=AL(p_); qb##S=AL(p_+1); }
#define GXL(S,C) { const ull* p_=(const ull*)(xpk + xbase + (size_t)(C)*1024); qa##S=AL(p_); qb##S=AL(p_+1); }
#define GRC(S,KS,GACC) { union{ull u[2];v8bf v;}c_; c_.u[0]=qa##S;c_.u[1]=qb##S; v8bf a_=c_.v; \
  v8bf w0_=*(const v8bf*)&Wl[(KS)*512+lane*8]; \
  v8bf w1_=*(const v8bf*)&Wl[18432+(KS)*512+lane*8]; \
  v8bf w2_=*(const v8bf*)&Wl[36864+(KS)*512+lane*8]; \
  aR=__builtin_amdgcn_mfma_f32_16x16x32_bf16(a_,w0_,aR,0,0,0); \
  aZ=__builtin_amdgcn_mfma_f32_16x16x32_bf16(a_,w1_,aZ,0,0,0); \
  GACC=__builtin_amdgcn_mfma_f32_16x16x32_bf16(a_,w2_,GACC,0,0,0); }

// pre-phase macros (source = hd of this step, weights Wp LDS)
#define PRL(S,C) { const ull* p_=(const ull*)(hdp + hbase + (size_t)(C)*1024); qa##S=AL(p_); qb##S=AL(p_+1); }
#define PRC(S,KS) { union{ull u[2];v8bf v;}c_; c_.u[0]=qa##S;c_.u[1]=qb##S; \
  aP=__builtin_amdgcn_mfma_f32_16x16x32_bf16(c_.v, *(const v8bf*)&Wp[(KS)*512+lane*8], aP,0,0,0); }

// W1-phase macros (A = hidpk atomics, B = w1pk global)
#define W1L(S,C) { const ull* p0_=(const ull*)(hidpk + w1abase + (size_t)(C)*1024); \
  qa##S=AL(p0_); qb##S=AL(p0_+1); \
  const ull* p1_=(const ull*)(hidpk + w1abase + 512 + (size_t)(C)*1024); \
  qc##S=AL(p1_); qd##S=AL(p1_+1); \
  bq##S = *(const uint4*)(w1b + (size_t)(C)*512 + lane*8); }
#define W1C(S) { union{ull u[2];v8bf v;}x0_,x1_; x0_.u[0]=qa##S;x0_.u[1]=qb##S; x1_.u[0]=qc##S;x1_.u[1]=qd##S; \
  union{uint4 q; v8bf v;}bb_; bb_.q=bq##S; \
  c0=__builtin_amdgcn_mfma_f32_16x16x32_bf16(x0_.v,bb_.v,c0,0,0,0); \
  c1=__builtin_amdgcn_mfma_f32_16x16x32_bf16(x1_.v,bb_.v,c1,0,0,0); }

__global__ __launch_bounds__(512) void dec_all(
    const bf16* __restrict__ Wpk, const float* __restrict__ bcat,
    const float* __restrict__ hA,
    bf16* __restrict__ hpk0, bf16* __restrict__ hpk1,
    const bf16* __restrict__ prepk, const float* __restrict__ preb,
    const float* __restrict__ motion, bf16* __restrict__ hidpk,
    const bf16* __restrict__ w1pk, const float* __restrict__ sb1,
    float* __restrict__ hhpre,
    const float* __restrict__ sW1, const float* __restrict__ sW2,
    const float* __restrict__ sb2,
    float* __restrict__ xcur, bf16* __restrict__ xpk, float* __restrict__ out,
    unsigned* __restrict__ prog)
{
  __shared__ bf16 Wl[3*36*512];     // 108 KB GRU weights
  __shared__ bf16 Wp[32*512];       // 32 KB preW slice
  __shared__ float preds_s[4][128];
  __shared__ float hh_s[128][5];

  const int tid = threadIdx.x, wave = tid >> 6, lane = tid & 63;
  const int bid = blockIdx.x;
  const int ub = bid >> 1, bs = bid & 1, u0 = ub*16;
  const int la = lane & 15, lb = lane >> 4;

  {
    const bf16* wsrc = Wpk + (size_t)ub*(3*36*512);
    #pragma unroll
    for (int i = 0; i < 14; ++i){ int c = i*512 + tid; if (c < 6912) GLD16(&Wl[c*8], wsrc + (size_t)c*8); }
    const bf16* psrc = prepk + (size_t)ub*(32*512);
    #pragma unroll
    for (int i = 0; i < 4; ++i){ int c = i*512 + tid; GLD16(&Wp[c*8], psrc + (size_t)c*8); }
  }
  VMWAIT(0); BARRIER();

  const int r0 = bs*128 + wave*16;
  const int rb = r0 >> 5, y = wave & 1;
  const int ucol = u0 + la;
  const float bR = bcat[ucol], bZ = bcat[1024+ucol], bI = bcat[2048+ucol], bN = bcat[3072+ucol];
  const float pB = preb[ucol];
  const size_t hbase = (size_t)rb*32768 + (size_t)y*512 + la*32 + lb*8;
  const size_t xbase = (size_t)rb*4096  + (size_t)y*512 + la*32 + lb*8;
  const size_t pwb   = (size_t)rb*32768 + (size_t)(u0>>5)*1024 + (size_t)y*512 + (u0&16) + la;
  // W1 phase
  const int n0 = bid*16;
  const size_t w1abase = (size_t)wave*32768 + la*32 + lb*8;
  const bf16* w1b = w1pk + (size_t)bid*(32*512);
  const float sb1f = (bid < 112) ? sb1[n0 + la] : 0.f;
  // SPL phase
  const bool splact = (bid < 64) && (tid < 128);
  const int b0s = bid*4, th = tid;

  float hr[4];
  #pragma unroll
  for (int r = 0; r < 4; ++r) hr[r] = hA[(size_t)(r0 + lb*4 + r)*1024 + ucol];

  int ph = 0;
  auto PHSYNC = [&](void){
    ++ph;
    VMWAIT(0);
    __syncthreads();
    if (tid == 0) __hip_atomic_store(&prog[bid], (unsigned)ph, __ATOMIC_RELAXED, __HIP_MEMORY_SCOPE_AGENT);
    if (wave == 0){
      unsigned v1 = AL(&prog[lane]), v2 = AL(&prog[64 + lane]);
      while (__ballot((v1 >= (unsigned)ph) && (v2 >= (unsigned)ph)) != ~0ULL){
        __builtin_amdgcn_s_sleep(1);
        v1 = AL(&prog[lane]); v2 = AL(&prog[64 + lane]);
      }
    }
    __syncthreads();
    __builtin_amdgcn_sched_barrier(0);
  };

  ull qa0,qa1,qa2,qa3,qa4,qa5,qa6,qa7,qa8,qa9,qa10,qa11;
  ull qb0,qb1,qb2,qb3,qb4,qb5,qb6,qb7,qb8,qb9,qb10,qb11;
  ull qc0,qc1,qc2,qc3,qc4,qc5;
  ull qd0,qd1,qd2,qd3,qd4,qd5;
  uint4 bq0,bq1,bq2,bq3,bq4,bq5;

  for (int dt = 0; dt < PRED_; ++dt){
    // ---------- phase 1: GRU ----------
    const bf16* hs = (dt & 1) ? hpk1 : hpk0;
    bf16* hd = (dt & 1) ? hpk0 : hpk1;
    {
      GXL(0,0) GXL(1,1) GXL(2,2) GXL(3,3)
      GRL(4,0) GRL(5,1) GRL(6,2) GRL(7,3)
      GRL(8,4) GRL(9,5) GRL(10,6) GRL(11,7)
      f32x4 z4 = {0.f,0.f,0.f,0.f};
      f32x4 aR = z4, aZ = z4, aI = z4, aN = z4;
      GRC(0,0,aI)  GRL(0,8)
      GRC(1,1,aI)  GRL(1,9)
      GRC(2,2,aI)  GRL(2,10)
      GRC(3,3,aI)  GRL(3,11)
      GRC(4,4,aN)  GRL(4,12)
      GRC(5,5,aN)  GRL(5,13)
      GRC(6,6,aN)  GRL(6,14)
      GRC(7,7,aN)  GRL(7,15)
      GRC(8,8,aN)  GRL(8,16)
      GRC(9,9,aN)  GRL(9,17)
      GRC(10,10,aN) GRL(10,18)
      GRC(11,11,aN) GRL(11,19)
      GRC(0,12,aN) GRL(0,20)
      GRC(1,13,aN) GRL(1,21)
      GRC(2,14,aN) GRL(2,22)
      GRC(3,15,aN) GRL(3,23)
      GRC(4,16,aN) GRL(4,24)
      GRC(5,17,aN) GRL(5,25)
      GRC(6,18,aN) GRL(6,26)
      GRC(7,19,aN) GRL(7,27)
      GRC(8,20,aN) GRL(8,28)
      GRC(9,21,aN) GRL(9,29)
      GRC(10,22,aN) GRL(10,30)
      GRC(11,23,aN) GRL(11,31)
      GRC(0,24,aN)
      GRC(1,25,aN)
      GRC(2,26,aN)
      GRC(3,27,aN)
      GRC(4,28,aN)
      GRC(5,29,aN)
      GRC(6,30,aN)
      GRC(7,31,aN)
      GRC(8,32,aN)
      GRC(9,33,aN)
      GRC(10,34,aN)
      GRC(11,35,aN)
      #pragma unroll
      for (int r = 0; r < 4; ++r){
        float rg = 1.f/(1.f + __expf(-(aR[r] + bR)));
        float zg = 1.f/(1.f + __expf(-(aZ[r] + bZ)));
        float ng = tanhf((aI[r] + bI) + rg*(aN[r] + bN));
        float hv = (1.f - zg)*ng + zg*hr[r];
        hr[r] = hv;
        bf16 hv16 = __float2bfloat16(hv);
        __hip_atomic_store((unsigned short*)(hd + pwb + (size_t)(lb*4 + r)*32),
                           *(unsigned short*)&hv16, __ATOMIC_RELAXED, __HIP_MEMORY_SCOPE_AGENT);
      }
    }
    PHSYNC();

    // ---------- phase 2: pre (hid = relu(h@preW^T + preb) + motion) ----------
    {
      const bf16* hdp = hd;
      PRL(0,0) PRL(1,1) PRL(2,2) PRL(3,3) PRL(4,4) PRL(5,5)
      PRL(6,6) PRL(7,7) PRL(8,8) PRL(9,9) PRL(10,10) PRL(11,11)
      f32x4 aP = {0.f,0.f,0.f,0.f};
      PRC(0,0)  PRL(0,12)
      PRC(1,1)  PRL(1,13)
      PRC(2,2)  PRL(2,14)
      PRC(3,3)  PRL(3,15)
      PRC(4,4)  PRL(4,16)
      PRC(5,5)  PRL(5,17)
      PRC(6,6)  PRL(6,18)
      PRC(7,7)  PRL(7,19)
      PRC(8,8)  PRL(8,20)
      PRC(9,9)  PRL(9,21)
      PRC(10,10) PRL(10,22)
      PRC(11,11) PRL(11,23)
      PRC(0,12) PRL(0,24)
      PRC(1,13) PRL(1,25)
      PRC(2,14) PRL(2,26)
      PRC(3,15) PRL(3,27)
      PRC(4,16) PRL(4,28)
      PRC(5,17) PRL(5,29)
      PRC(6,18) PRL(6,30)
      PRC(7,19) PRL(7,31)
      PRC(8,20)
      PRC(9,21)
      PRC(10,22)
      PRC(11,23)
      PRC(0,24)
      PRC(1,25)
      PRC(2,26)
      PRC(3,27)
      PRC(4,28)
      PRC(5,29)
      PRC(6,30)
      PRC(7,31)
      #pragma unroll
      for (int r = 0; r < 4; ++r){
        int row = r0 + lb*4 + r;
        float v = fmaxf(aP[r] + pB, 0.f) + motion[(size_t)row*1024 + ucol];
        bf16 v16 = __float2bfloat16(v);
        __hip_atomic_store((unsigned short*)(hidpk + pwb + (size_t)(lb*4 + r)*32),
                           *(unsigned short*)&v16, __ATOMIC_RELAXED, __HIP_MEMORY_SCOPE_AGENT);
      }
    }
    PHSYNC();

    // ---------- phase 3: W1 (hhpre = hid @ W1^T + b1) ----------
    if (bid < 112){
      W1L(0,0) W1L(1,1) W1L(2,2) W1L(3,3) W1L(4,4) W1L(5,5)
      f32x4 c0 = {0.f,0.f,0.f,0.f}, c1 = c0;
      W1C(0) W1L(0,6)
      W1C(1) W1L(1,7)
      W1C(2) W1L(2,8)
      W1C(3) W1L(3,9)
      W1C(4) W1L(4,10)
      W1C(5) W1L(5,11)
      W1C(0) W1L(0,12)
      W1C(1) W1L(1,13)
      W1C(2) W1L(2,14)
      W1C(3) W1L(3,15)
      W1C(4) W1L(4,16)
      W1C(5) W1L(5,17)
      W1C(0) W1L(0,18)
      W1C(1) W1L(1,19)
      W1C(2) W1L(2,20)
      W1C(3) W1L(3,21)
      W1C(4) W1L(4,22)
      W1C(5) W1L(5,23)
      W1C(0) W1L(0,24)
      W1C(1) W1L(1,25)
      W1C(2) W1L(2,26)
      W1C(3) W1L(3,27)
      W1C(4) W1L(4,28)
      W1C(5) W1L(5,29)
      W1C(0) W1L(0,30)
      W1C(1) W1L(1,31)
      W1C(2)
      W1C(3)
      W1C(4)
      W1C(5)
      W1C(0)
      W1C(1)
      #pragma unroll
      for (int r = 0; r < 4; ++r){
        int row0 = wave*32 + lb*4 + r;
        int row1 = row0 + 16;
        __hip_atomic_store(&hhpre[(size_t)row0*1792 + n0 + la], c0[r] + sb1f,
                           __ATOMIC_RELAXED, __HIP_MEMORY_SCOPE_AGENT);
        __hip_atomic_store(&hhpre[(size_t)row1*1792 + n0 + la], c1[r] + sb1f,
                           __ATOMIC_RELAXED, __HIP_MEMORY_SCOPE_AGENT);
      }
    }
    PHSYNC();

    // ---------- phase 4: SPL chains + x/out update ----------
    for (int L = 0; L < 3; ++L){
      for (int ji = LVO[L]; ji < LVO[L+1]; ++ji){
        int j = LVJ[ji], p = PAR_[j];
        if (splact){
          float acc[4];
          #pragma unroll
          for (int bb = 0; bb < 4; ++bb)
            acc[bb] = AL(&hhpre[(size_t)(b0s+bb)*1792 + j*128 + th]);
          if (p >= 0){
            #pragma unroll
            for (int ii = 0; ii < 9; ++ii){
              float w = sW1[(size_t)(j*128 + th)*1033 + 1024 + ii];
              #pragma unroll
              for (int bb = 0; bb < 4; ++bb) acc[bb] += w * preds_s[bb][p*9 + ii];
            }
          }
          #pragma unroll
          for (int bb = 0; bb < 4; ++bb) hh_s[th][bb] = fmaxf(acc[bb], 0.f);
        }
        __syncthreads();
        if (splact && th < 72){
          int pp = th >> 1, half = th & 1;
          int bb = pp/9, oi = pp%9;
          const float* w2r = sW2 + (size_t)(j*9 + oi)*128 + half*64;
          float s = 0.f;
          #pragma unroll
          for (int ttt = 0; ttt < 64; ++ttt) s += hh_s[half*64 + ttt][bb] * w2r[ttt];
          s += __shfl_xor(s, 1);
          if (half == 0) preds_s[bb][j*9 + oi] = tanhf(s + sb2[j*9 + oi]);
        }
        __syncthreads();
      }
    }
    if (splact){
      for (int i = th; i < 4*D_; i += 128){
        int bb = i / D_, d = i % D_;
        int row = b0s + bb;
        size_t xi = (size_t)row*D_ + d;
        float v = xcur[xi] + preds_s[bb][d];
        xcur[xi] = v;
        bf16 v16 = __float2bfloat16(v);
        __hip_atomic_store((unsigned short*)(xpk + ((size_t)(row>>5)*4 + (d>>5))*1024 + (row&31)*32 + (d&31)),
                           *(unsigned short*)&v16, __ATOMIC_RELAXED, __HIP_MEMORY_SCOPE_AGENT);
        out[((size_t)row*PRED_ + dt)*D_ + d] = v;
      }
    }
    if (dt + 1 < PRED_) PHSYNC();
  }
}

// ---------------- pipelined generic GEMM (preamble only) ----------------
__global__ __launch_bounds__(256) void gemm64(
    const bf16* __restrict__ Am, const bf16* __restrict__ Bm, int K,
    const float* __restrict__ bias, const float* __restrict__ addmat,
    float* __restrict__ C, bf16* __restrict__ Cbf, int N, int MODE)
{
  __shared__ bf16 As[3][64*64];
  __shared__ bf16 Bs[3][64*64];
  const int tid = threadIdx.x;
  const int wave = tid >> 6, lane = tid & 63;
  const int m0 = blockIdx.x*64, n0 = blockIdx.y*64;
  const int fr = lane & 31, kh = lane >> 5;
  const int wm = (wave >> 1)*32, wn = (wave & 1)*32;
  const int KT = K >> 6;

  f32x16 acc = {0.f,0.f,0.f,0.f,0.f,0.f,0.f,0.f,0.f,0.f,0.f,0.f,0.f,0.f,0.f,0.f};

  auto STAGE = [&](int buf, int kt){
    #pragma unroll
    for (int q = 0; q < 2; ++q){
      int idx = q*256 + tid;
      int row = idx >> 3, cp = idx & 7, csw = cp ^ (row & 7);
      GLD16(&As[buf][idx*8], Am + (size_t)(m0+row)*K + kt*64 + csw*8);
    }
    #pragma unroll
    for (int q = 0; q < 2; ++q){
      int idx = q*256 + tid;
      int row = idx >> 3, cp = idx & 7, csw = cp ^ (row & 7);
      GLD16(&Bs[buf][idx*8], Bm + (size_t)(n0+row)*K + kt*64 + csw*8);
    }
  };
  auto COMPUTE = [&](int buf){
    const bf16* Ab = &As[buf][0];
    const bf16* Bb = &Bs[buf][0];
    #pragma unroll
    for (int ks = 0; ks < 4; ++ks){
      int ca = ks*2 + kh;
      v8bf av = *(const v8bf*)&Ab[(wm+fr)*64 + ((ca ^ ((wm+fr)&7))*8)];
      v8bf bv = *(const v8bf*)&Bb[(wn+fr)*64 + ((ca ^ ((wn+fr)&7))*8)];
      acc = __builtin_amdgcn_mfma_f32_32x32x16_bf16(av, bv, acc, 0, 0, 0);
    }
  };

  STAGE(0, 0);
  if (KT > 1){ STAGE(1, 1); VMWAIT(4); } else { VMWAIT(0); }
  BARRIER();
  for (int kt = 0; kt < KT; ++kt){
    if (kt + 2 < KT) STAGE((kt+2)%3, kt+2);
    COMPUTE(kt%3);
    if (kt + 2 < KT){ VMWAIT(4); BARRIER(); }
    else if (kt + 1 < KT){ VMWAIT(0); BARRIER(); }
  }

  const int col = n0 + wn + fr;
  float bb = bias ? bias[col] : 0.f;
  #pragma unroll
  for (int r = 0; r < 16; ++r){
    int row = m0 + wm + (r&3) + 8*(r>>2) + 4*kh;
    float v = acc[r] + bb;
    if (MODE == 1) v = fmaxf(v, 0.f) + addmat[(size_t)row*N + col];
    if (C)   C[(size_t)row*N + col] = v;
    if (Cbf) Cbf[(size_t)row*N + col] = __float2bfloat16(v);
  }
}

// ---------------- attention: one block per (b,h) ----------------
__global__ __launch_bounds__(256) void k_attn(const bf16* __restrict__ qkv,
                                              bf16* __restrict__ ctxbf){
  __shared__ char smem[65536];
  bf16* qs = (bf16*)smem;
  bf16* ks = qs + 64*256;
  float* sc = (float*)smem;
  float* cs = (float*)(smem + 32768);
  const int h = blockIdx.x, b = blockIdx.y;
  const int tid = threadIdx.x, wave = tid >> 6, lane = tid & 63;
  const int fr = lane & 31, kh = lane >> 5;
  const int wm = (wave >> 1)*32, wn = (wave & 1)*32;

  #pragma unroll
  for (int i = 0; i < 8; ++i){
    int idx = i*256 + tid;
    int row = idx >> 5, cp = idx & 31, csw = cp ^ (row & 7);
    GLD16(&qs[idx*8], qkv + (size_t)(b*F_ + row)*3072 + h*DH_ + csw*8);
  }
  #pragma unroll
  for (int i = 0; i < 8; ++i){
    int idx = i*256 + tid;
    int row = idx >> 5, cp = idx & 31, csw = cp ^ (row & 7);
    GLD16(&ks[idx*8], qkv + (size_t)(b*F_ + row)*3072 + H_ + h*DH_ + csw*8);
  }
  __syncthreads();

  f32x16 acc = {0.f,0.f,0.f,0.f,0.f,0.f,0.f,0.f,0.f,0.f,0.f,0.f,0.f,0.f,0.f,0.f};
  #pragma unroll
  for (int i = 0; i < 16; ++i){
    int ca = i*2 + kh;
    v8bf av = *(const v8bf*)&qs[((wm+fr)*32 + (ca ^ ((wm+fr)&7)))*8];
    v8bf bv = *(const v8bf*)&ks[((wn+fr)*32 + (ca ^ ((wn+fr)&7)))*8];
    acc = __builtin_amdgcn_mfma_f32_32x32x16_bf16(av, bv, acc, 0, 0, 0);
  }
  __syncthreads();
  #pragma unroll
  for (int r = 0; r < 16; ++r){
    int row = wm + (r&3) + 8*(r>>2) + 4*kh;
    sc[row*65 + (wn+fr)] = acc[r]*0.0625f;
  }
  __syncthreads();
  if (tid < F_){
    float m = -1e30f;
    for (int k2 = 0; k2 < F_; ++k2) m = fmaxf(m, sc[tid*65+k2]);
    float s = 0.f;
    for (int k2 = 0; k2 < F_; ++k2){ float e = __expf(sc[tid*65+k2]-m); sc[tid*65+k2] = e; s += e; }
    float is = 1.f/s;
    for (int k2 = 0; k2 < F_; ++k2) sc[tid*65+k2] *= is;
  }
  __syncthreads();
  if (tid < F_){
    float s = 0.f;
    for (int r = 0; r < F_; ++r) s += sc[r*65+tid];
    cs[tid] = s;
  }
  __syncthreads();
  float a = 0.f;
  for (int k2 = 0; k2 < F_; ++k2){
    float v = __bfloat162float(qkv[(size_t)(b*F_+k2)*3072 + 2*H_ + h*DH_ + tid]);
    a += cs[k2]*v;
  }
  ctxbf[(size_t)b*H_ + h*DH_ + tid] = __float2bfloat16(a * (1.f/61.f));
}

// ---------------- launch ----------------
extern "C" void kernel_launch(void* const* d_in, const int* in_sizes, int n_in,
                              void* d_out, int out_size, void* d_ws, size_t ws_size,
                              hipStream_t stream){
  (void)in_sizes; (void)n_in; (void)out_size; (void)ws_size;
  const float* poses = (const float*)d_in[0];
  const float* gWih  = (const float*)d_in[1];
  const float* gWhh  = (const float*)d_in[2];
  const float* gbih  = (const float*)d_in[3];
  const float* gbhh  = (const float*)d_in[4];
  const float* preW  = (const float*)d_in[5];
  const float* preb  = (const float*)d_in[6];
  const float* fpW   = (const float*)d_in[7];
  const float* fpb   = (const float*)d_in[8];
  const float* inW   = (const float*)d_in[9];
  const float* inb   = (const float*)d_in[10];
  const float* outW  = (const float*)d_in[11];
  const float* outb  = (const float*)d_in[12];
  const float* sW1   = (const float*)d_in[13];
  const float* sb1   = (const float*)d_in[14];
  const float* sW2   = (const float*)d_in[15];
  const float* sb2   = (const float*)d_in[16];
  float* out = (float*)d_out;

  char* w = (char*)d_ws;
  size_t off = 0;
  auto alloc = [&](size_t bytes)->char*{ char* p = w + off; off += (bytes + 255) & ~(size_t)255; return p; };
  float* cosT   = (float*)alloc(7320*4);
  float* bc     = (float*)alloc(3072*4);
  float* motion = (float*)alloc((size_t)256*1024*4);
  float* hA     = (float*)alloc((size_t)256*1024*4);
  float* xcur   = (float*)alloc((size_t)256*126*4);
  float* hhpre  = (float*)alloc((size_t)256*1792*4);
  float* bcat   = (float*)alloc(4096*4);
  unsigned* prog= (unsigned*)alloc(1024);
  bf16* posespk = (bf16*)alloc((size_t)121*32768*2);
  bf16* Wcat    = (bf16*)alloc((size_t)4096*1152*2);
  bf16* Wpk     = (bf16*)alloc((size_t)64*108*512*2);
  bf16* prepk   = (bf16*)alloc((size_t)64*32*512*2);
  bf16* w1pk    = (bf16*)alloc((size_t)112*32*512*2);
  bf16* outbf   = (bf16*)alloc((size_t)1024*1024*2);
  bf16* inbf    = (bf16*)alloc((size_t)3072*1024*2);
  bf16* fpwt    = (bf16*)alloc((size_t)128*1024*2);
  bf16* ctxbf   = (bf16*)alloc((size_t)256*1024*2);
  bf16* hpkA    = (bf16*)alloc((size_t)256*1024*2);
  bf16* hpkB    = (bf16*)alloc((size_t)256*1024*2);
  bf16* hidpk   = (bf16*)alloc((size_t)256*1024*2);
  bf16* xpk     = (bf16*)alloc((size_t)32768*2);
  bf16* Wcbf    = (bf16*)alloc((size_t)3072*128*2);
  bf16* freqbf  = (bf16*)alloc((size_t)B_*F_*128*2);
  bf16* qkvbf   = (bf16*)alloc((size_t)15680*3072*2);

  hipMemsetAsync(hpkA, 0, (size_t)256*1024*2, stream);
  hipMemsetAsync(prog, 0, 1024, stream);

  k_cos<<<29, 256, 0, stream>>>(cosT);
  k_dft2<<<B_, 256, 0, stream>>>(poses, cosT, freqbf);
  c_poses<<<dim3(SEED_, B_), 128, 0, stream>>>(poses, posespk);
  c_xinit<<<B_, 128, 0, stream>>>(poses, xcur, xpk);
  c_wcat<<<4096, 256, 0, stream>>>(gWih, gWhh, Wcat);
  c_bcat<<<16, 256, 0, stream>>>(gbih, gbhh, bcat);
  c_wpk<<<1728, 256, 0, stream>>>(Wcat, Wpk);
  c_ppk<<<512, 256, 0, stream>>>(preW, prepk);
  c_w1pk<<<896, 256, 0, stream>>>(sW1, w1pk);
  c_bf<<<4096, 256, 0, stream>>>(outW, outbf, 1024*1024);
  c_bf<<<12288, 256, 0, stream>>>(inW, inbf, 3072*1024);
  c_fpwt<<<128, 256, 0, stream>>>(fpW, fpwt);
  k_bc<<<768, 256, 0, stream>>>(inW, inb, fpb, bc);

  // Wc = inproj @ fp_W  (3072 x 128, bf16)
  gemm64<<<dim3(48, 2), 256, 0, stream>>>(inbf, fpwt, 1024, nullptr, nullptr, nullptr, Wcbf, 128, 0);
  // qkv = freq @ Wc^T + bc  (15616 x 3072, bf16)
  gemm64<<<dim3(244, 48), 256, 0, stream>>>(freqbf, Wcbf, 128, bc, nullptr, nullptr, qkvbf, 3072, 0);
  k_attn<<<dim3(HEADS_, B_), 256, 0, stream>>>(qkvbf, ctxbf);
  // motion_ctx = ctx_mean @ outproj^T + outb
  gemm64<<<dim3(4, 16), 256, 0, stream>>>(ctxbf, outbf, 1024, outb, nullptr, motion, nullptr, 1024, 0);

  // encoder: cooperative, fence-free coherent h, 120 steps; final h -> hA, packed -> hpkA
  {
    const bf16* a0 = posespk; int a1 = 32768; int a2 = SEED_; int a3 = 1;
    const bf16* a4 = Wpk; const float* a5 = bcat;
    const float* a6 = hA; float* a7 = hA; bf16* a8 = nullptr;
    bf16* a9 = hpkA; bf16* a10 = hpkB; unsigned* a11 = prog;
    void* args[] = { &a0, &a1, &a2, &a3, &a4, &a5, &a6, &a7, &a8, &a9, &a10, &a11 };
    hipLaunchCooperativeKernel(reinterpret_cast<void*>(gru_wave), dim3(128), dim3(512),
                               args, 0, stream);
  }

  // persistent decoder: 24 steps x {GRU, pre, W1, SPL}, flag-synced
  {
    const bf16* a0 = Wpk; const float* a1 = bcat; const float* a2 = hA;
    bf16* a3 = hpkA; bf16* a4 = hpkB;
    const bf16* a5 = prepk; const float* a6 = preb; const float* a7 = motion;
    bf16* a8 = hidpk; const bf16* a9 = w1pk; const float* a10 = sb1;
    float* a11 = hhpre;
    const float* a12 = sW1; const float* a13 = sW2; const float* a14 = sb2;
    float* a15 = xcur; bf16* a16 = xpk; float* a17 = out;
    unsigned* a18 = prog + 128;
    void* args[] = { &a0, &a1, &a2, &a3, &a4, &a5, &a6, &a7, &a8, &a9, &a10,
                     &a11, &a12, &a13, &a14, &a15, &a16, &a17, &a18 };
    hipLaunchCooperativeKernel(reinterpret_cast<void*>(dec_all), dim3(128), dim3(512),
                               args, 0, stream);
  }
}

// Round 12
// 4330.701 us; speedup vs baseline: 1.0158x; 1.0158x over previous
//
#include <hip/hip_runtime.h>
#include <hip/hip_bf16.h>

typedef __hip_bfloat16 bf16;
typedef __attribute__((ext_vector_type(8))) short v8bf;     // 8 bf16 (4 VGPR)
typedef __attribute__((ext_vector_type(16))) float f32x16;
typedef __attribute__((ext_vector_type(4))) float f32x4;
typedef unsigned long long ull;

#define B_    256
#define SEED_ 120
#define PRED_ 24
#define D_    126
#define H_    1024
#define F_    61
#define HEADS_ 4
#define DH_   256

#define GLD16(lds, g) __builtin_amdgcn_global_load_lds( \
    (const __attribute__((address_space(1))) unsigned int*)(g), \
    (__attribute__((address_space(3))) unsigned int*)(lds), 16, 0, 0)
#define VMWAIT(n) asm volatile("s_waitcnt vmcnt(" #n ")" ::: "memory")
#define BARRIER() do { __builtin_amdgcn_s_barrier(); __builtin_amdgcn_sched_barrier(0); } while(0)
#define AL(P) __hip_atomic_load((P), __ATOMIC_RELAXED, __HIP_MEMORY_SCOPE_AGENT)

// ---------------- small precompute kernels ----------------
__global__ void k_cos(float* cosT){
  int i = blockIdx.x*256 + threadIdx.x;
  if (i < F_*SEED_){
    int f = i / SEED_, t = i % SEED_;
    int ph = (f*t) % SEED_;
    cosT[i] = cosf(6.283185307179586f * (float)ph / (float)SEED_);
  }
}

__global__ __launch_bounds__(256) void k_dft2(const float* __restrict__ poses,
                      const float* __restrict__ cosT, bf16* __restrict__ freqbf){
  __shared__ float pl[SEED_*128];      // 60 KB
  int b = blockIdx.x, tid = threadIdx.x;
  for (int i = tid; i < SEED_*D_; i += 256){
    int t = i / D_, d = i - t*D_;
    pl[t*128 + d] = poses[((size_t)b*(SEED_+PRED_) + t)*D_ + d];
  }
  __syncthreads();
  int d = tid & 127, f0 = tid >> 7;    // f = f0 + 2j
  float acc[31];
  #pragma unroll
  for (int j = 0; j < 31; ++j) acc[j] = 0.f;
  for (int t = 0; t < SEED_; ++t){
    float v = pl[t*128 + d];
    #pragma unroll
    for (int j = 0; j < 31; ++j){
      int f = f0 + j*2;
      if (f < F_) acc[j] += cosT[f*SEED_ + t] * v;
    }
  }
  #pragma unroll
  for (int j = 0; j < 31; ++j){
    int f = f0 + j*2;
    if (f < F_) freqbf[((size_t)b*F_ + f)*128 + d] = __float2bfloat16(d < D_ ? acc[j] : 0.f);
  }
}

// pack poses into per-step 32x32 tiles
__global__ void c_poses(const float* __restrict__ poses, bf16* __restrict__ pk){
  int t = blockIdx.x, b = blockIdx.y, c = threadIdx.x;  // block 128
  float v = (c < D_) ? poses[((size_t)b*(SEED_+PRED_) + t)*D_ + c] : 0.f;
  pk[(size_t)t*32768 + ((b>>5)*4 + (c>>5))*1024 + (b&31)*32 + (c&31)] = __float2bfloat16(v);
}

__global__ void c_xinit(const float* __restrict__ poses, float* __restrict__ x, bf16* __restrict__ xpk){
  int b = blockIdx.x, c = threadIdx.x;  // block 128
  float v = (c < D_) ? poses[((size_t)b*(SEED_+PRED_) + (SEED_-1))*D_ + c] : 0.f;
  if (c < D_) x[b*D_ + c] = v;
  xpk[((b>>5)*4 + (c>>5))*1024 + (b&31)*32 + (c&31)] = __float2bfloat16(v);
}

__global__ void c_bf(const float* __restrict__ s, bf16* __restrict__ d, int n){
  int i = blockIdx.x*256 + threadIdx.x;
  if (i < n) d[i] = __float2bfloat16(s[i]);
}

__global__ void c_fpwt(const float* __restrict__ fpW, bf16* __restrict__ o){
  int dd = blockIdx.x;                       // 0..127
  for (int k = threadIdx.x; k < H_; k += 256)
    o[(size_t)dd*H_ + k] = __float2bfloat16(dd < D_ ? fpW[(size_t)k*D_ + dd] : 0.f);
}

// combined GRU weight rows (1152 wide: 128 x-cols | 1024 h-cols)
__global__ void c_wcat(const float* __restrict__ Wih, const float* __restrict__ Whh, bf16* __restrict__ o){
  int r = blockIdx.x;
  int jr; bool hasx, hash;
  if (r < 2048){ jr = r; hasx = true; hash = true; }
  else if (r < 3072){ jr = r; hasx = true; hash = false; }
  else { jr = r - 1024; hasx = false; hash = true; }
  bf16* row = o + (size_t)r*1152;
  for (int c = threadIdx.x; c < 1152; c += 256){
    float v = 0.f;
    if (c < D_) { if (hasx) v = Wih[(size_t)jr*D_ + c]; }
    else if (c >= 128){ if (hash) v = Whh[(size_t)jr*H_ + (c-128)]; }
    row[c] = __float2bfloat16(v);
  }
}

__global__ void c_bcat(const float* __restrict__ bih, const float* __restrict__ bhh, float* __restrict__ o){
  int r = blockIdx.x*256 + threadIdx.x;
  if (r >= 4096) return;
  float v;
  if (r < 2048) v = bih[r] + bhh[r];
  else if (r < 3072) v = bih[r];
  else v = bhh[r - 1024];
  o[r] = v;
}

// pack GRU weights into MFMA B-fragment order
__global__ __launch_bounds__(256) void c_wpk(const bf16* __restrict__ Wcat, bf16* __restrict__ Wpk){
  int chunk = blockIdx.x*4 + (threadIdx.x >> 6);
  int l = threadIdx.x & 63;
  int ks = chunk % 36; int t2 = chunk / 36; int g = t2 % 3; int ub = t2 / 3;
  int unit = ub*16 + (l & 15);
  bf16* dst = Wpk + (size_t)chunk*512 + l*8;
  #pragma unroll
  for (int e = 0; e < 8; ++e){
    int k = ks*32 + (l>>4)*8 + e;
    int row = (g==0) ? unit : (g==1) ? (1024+unit) : (k < 128 ? 2048+unit : 3072+unit);
    dst[e] = Wcat[(size_t)row*1152 + k];
  }
}

// pack preW into fragment order: chunk = ub*32+ks
__global__ __launch_bounds__(256) void c_ppk(const float* __restrict__ preW, bf16* __restrict__ prepk){
  int chunk = blockIdx.x*4 + (threadIdx.x >> 6);   // 2048 chunks
  int l = threadIdx.x & 63;
  int ks = chunk & 31, ub = chunk >> 5;
  int unit = ub*16 + (l & 15);
  bf16* dst = prepk + (size_t)chunk*512 + l*8;
  #pragma unroll
  for (int e = 0; e < 8; ++e)
    dst[e] = __float2bfloat16(preW[(size_t)unit*1024 + ks*32 + (l>>4)*8 + e]);
}

// pack W1-hid into fragment order: chunk = ug*32+ks, ug 0..111
__global__ __launch_bounds__(256) void c_w1pk(const float* __restrict__ sW1, bf16* __restrict__ w1pk){
  int chunk = blockIdx.x*4 + (threadIdx.x >> 6);   // 3584 chunks
  int l = threadIdx.x & 63;
  int ks = chunk & 31, ng = chunk >> 5;
  int unit = ng*16 + (l & 15);
  int j = unit >> 7, rr = unit & 127;
  bf16* dst = w1pk + (size_t)chunk*512 + l*8;
  #pragma unroll
  for (int e = 0; e < 8; ++e){
    int k = ks*32 + (l>>4)*8 + e;
    dst[e] = __float2bfloat16(sW1[((size_t)j*128 + rr)*1033 + k]);
  }
}

// pack SPL parent weights: w1par[(j*9+ii)*128 + t] = sW1[(j*128+t)*1033 + 1024 + ii]
__global__ void c_w1par(const float* __restrict__ sW1, float* __restrict__ w1par){
  int i = blockIdx.x*256 + threadIdx.x;
  if (i < 14*9*128){
    int j = i / (9*128); int rem = i % (9*128); int ii = rem / 128; int th = rem % 128;
    w1par[i] = sW1[((size_t)(j*128 + th))*1033 + 1024 + ii];
  }
}

// bc = inproj @ fp_b + in_b
__global__ __launch_bounds__(256) void k_bc(const float* __restrict__ inW, const float* __restrict__ inb,
                     const float* __restrict__ fpb, float* __restrict__ bc){
  int wave = threadIdx.x >> 6, lane = threadIdx.x & 63;
  int r = blockIdx.x*4 + wave;
  const float4* row = (const float4*)(inW + (size_t)r*H_);
  const float4* fp4 = (const float4*)fpb;
  float s = 0.f;
  #pragma unroll
  for (int i = 0; i < 4; ++i){
    float4 a = row[lane + i*64];
    float4 b = fp4[lane + i*64];
    s += a.x*b.x + a.y*b.y + a.z*b.z + a.w*b.w;
  }
  #pragma unroll
  for (int off = 32; off; off >>= 1) s += __shfl_down(s, off);
  if (lane == 0) bc[r] = s + inb[r];
}

// ---------------- encoder: wave-autonomous GRU (R10, unchanged) ----------------
#define SLCP(QA, QB, KS, GACC) { \
  union { ull u[2]; v8bf v; } cc_; cc_.u[0]=(QA); cc_.u[1]=(QB); \
  v8bf a_ = cc_.v; \
  v8bf w0_ = *(const v8bf*)&Wl[(0*36+(KS))*512 + lane*8]; \
  v8bf w1_ = *(const v8bf*)&Wl[(1*36+(KS))*512 + lane*8]; \
  v8bf w2_ = *(const v8bf*)&Wl[(2*36+(KS))*512 + lane*8]; \
  aR = __builtin_amdgcn_mfma_f32_16x16x32_bf16(a_, w0_, aR, 0,0,0); \
  aZ = __builtin_amdgcn_mfma_f32_16x16x32_bf16(a_, w1_, aZ, 0,0,0); \
  GACC = __builtin_amdgcn_mfma_f32_16x16x32_bf16(a_, w2_, GACC, 0,0,0); }

#define LDHA(DA, DB, C) { \
  const ull* hp_ = (const ull*)(hs + hbase + (size_t)(C)*1024); \
  DA = AL(hp_); DB = AL(hp_+1); }

#define LDXP(DA, DB, TT, C) { \
  const ull* xp_ = (const ull*)(xpk + (size_t)(TT)*xstride + xbase + (size_t)(C)*1024); \
  DA = xp_[0]; DB = xp_[1]; }

__global__ __launch_bounds__(512) void gru_wave(
    const bf16* __restrict__ xpk, int xstride, int nsteps, int coop,
    const bf16* __restrict__ Wpk, const float* __restrict__ bcat,
    const float* __restrict__ hin_plain, float* __restrict__ hout_plain,
    bf16* __restrict__ hbplain,
    bf16* __restrict__ hpk0, bf16* __restrict__ hpk1,
    unsigned* __restrict__ prog)
{
  __shared__ bf16 Wl[3*36*512];       // 108 KB
  const int tid = threadIdx.x, wave = tid >> 6, lane = tid & 63;
  const int ub = blockIdx.x >> 1, bs = blockIdx.x & 1;
  const int u0 = ub*16;

  {
    const bf16* wsrc = Wpk + (size_t)ub*(3*36*512);
    #pragma unroll
    for (int i = 0; i < 14; ++i){
      int c = i*512 + tid;
      if (c < 6912) GLD16(&Wl[c*8], wsrc + (size_t)c*8);
    }
  }
  VMWAIT(0); BARRIER();

  const int la = lane & 15, lb = lane >> 4;
  const int r0 = bs*128 + wave*16;
  const int rb = r0 >> 5, y = wave & 1;
  const int ucol = u0 + la;
  const float bR = bcat[ucol], bZ = bcat[1024+ucol], bI = bcat[2048+ucol], bN = bcat[3072+ucol];
  const size_t hbase = (size_t)rb*32768 + (size_t)y*512 + la*32 + lb*8;
  const size_t xbase = (size_t)rb*4096  + (size_t)y*512 + la*32 + lb*8;
  const size_t pwb = (size_t)rb*32768 + (size_t)(u0>>5)*1024 + (size_t)y*512 + (u0&16) + la;

  float hr[4];
  if (nsteps == 1){
    #pragma unroll
    for (int r = 0; r < 4; ++r) hr[r] = hin_plain[(size_t)(r0 + lb*4 + r)*1024 + ucol];
  } else {
    #pragma unroll
    for (int r = 0; r < 4; ++r) hr[r] = 0.f;
  }

  ull a0,a1,a2,a3,a4,a5,a6,a7,a8,a9,a10,a11;
  ull b0,b1,b2,b3,b4,b5,b6,b7,b8,b9,b10,b11;
  LDXP(a0,b0,0,0); LDXP(a1,b1,0,1); LDXP(a2,b2,0,2); LDXP(a3,b3,0,3);

  for (int t = 0; t < nsteps; ++t){
    if (coop && t > 0){
      if (wave == 0){
        unsigned v = AL(&prog[bs*64 + lane]);
        while (__ballot(v >= (unsigned)t) != ~0ULL){
          __builtin_amdgcn_s_sleep(1);
          v = AL(&prog[bs*64 + lane]);
        }
      }
      __syncthreads();
      __builtin_amdgcn_sched_barrier(0);
    }
    const bf16* hs = (t & 1) ? hpk1 : hpk0;
    LDHA(a4,b4,0) LDHA(a5,b5,1) LDHA(a6,b6,2) LDHA(a7,b7,3)
    LDHA(a8,b8,4) LDHA(a9,b9,5) LDHA(a10,b10,6) LDHA(a11,b11,7)

    f32x4 z4 = {0.f,0.f,0.f,0.f};
    f32x4 aR = z4, aZ = z4, aI = z4, aN = z4;

    SLCP(a0,b0,0,aI)  LDHA(a0,b0,8)
    SLCP(a1,b1,1,aI)  LDHA(a1,b1,9)
    SLCP(a2,b2,2,aI)  LDHA(a2,b2,10)
    SLCP(a3,b3,3,aI)  LDHA(a3,b3,11)
    SLCP(a4,b4,4,aN)  LDHA(a4,b4,12)
    SLCP(a5,b5,5,aN)  LDHA(a5,b5,13)
    SLCP(a6,b6,6,aN)  LDHA(a6,b6,14)
    SLCP(a7,b7,7,aN)  LDHA(a7,b7,15)
    SLCP(a8,b8,8,aN)  LDHA(a8,b8,16)
    SLCP(a9,b9,9,aN)  LDHA(a9,b9,17)
    SLCP(a10,b10,10,aN) LDHA(a10,b10,18)
    SLCP(a11,b11,11,aN) LDHA(a11,b11,19)
    SLCP(a0,b0,12,aN) LDHA(a0,b0,20)
    SLCP(a1,b1,13,aN) LDHA(a1,b1,21)
    SLCP(a2,b2,14,aN) LDHA(a2,b2,22)
    SLCP(a3,b3,15,aN) LDHA(a3,b3,23)
    SLCP(a4,b4,16,aN) LDHA(a4,b4,24)
    SLCP(a5,b5,17,aN) LDHA(a5,b5,25)
    SLCP(a6,b6,18,aN) LDHA(a6,b6,26)
    SLCP(a7,b7,19,aN) LDHA(a7,b7,27)
    SLCP(a8,b8,20,aN) LDHA(a8,b8,28)
    SLCP(a9,b9,21,aN) LDHA(a9,b9,29)
    SLCP(a10,b10,22,aN) LDHA(a10,b10,30)
    SLCP(a11,b11,23,aN) LDHA(a11,b11,31)
    SLCP(a0,b0,24,aN) LDXP(a0,b0,t+1,0)
    SLCP(a1,b1,25,aN) LDXP(a1,b1,t+1,1)
    SLCP(a2,b2,26,aN) LDXP(a2,b2,t+1,2)
    SLCP(a3,b3,27,aN) LDXP(a3,b3,t+1,3)
    SLCP(a4,b4,28,aN)
    SLCP(a5,b5,29,aN)
    SLCP(a6,b6,30,aN)
    SLCP(a7,b7,31,aN)
    SLCP(a8,b8,32,aN)
    SLCP(a9,b9,33,aN)
    SLCP(a10,b10,34,aN)
    SLCP(a11,b11,35,aN)

    bf16* hd = (t & 1) ? hpk0 : hpk1;
    const bool last = (t == nsteps-1);
    #pragma unroll
    for (int r = 0; r < 4; ++r){
      float rg = 1.f/(1.f + __expf(-(aR[r] + bR)));
      float zg = 1.f/(1.f + __expf(-(aZ[r] + bZ)));
      float ng = tanhf((aI[r] + bI) + rg*(aN[r] + bN));
      float hv = (1.f - zg)*ng + zg*hr[r];
      hr[r] = hv;
      bf16 hv16 = __float2bfloat16(hv);
      unsigned short hbits = *(unsigned short*)&hv16;
      __hip_atomic_store((unsigned short*)(hd + pwb + (size_t)(lb*4 + r)*32), hbits,
                         __ATOMIC_RELAXED, __HIP_MEMORY_SCOPE_AGENT);
      if (last){
        hout_plain[(size_t)(r0 + lb*4 + r)*1024 + ucol] = hv;
        if (hbplain) hbplain[(size_t)(r0 + lb*4 + r)*1024 + ucol] = __float2bfloat16(hv);
      }
    }
    if (coop && t + 1 < nsteps){
      VMWAIT(0);
      __syncthreads();
      if (tid == 0)
        __hip_atomic_store(&prog[bs*64 + ub], (unsigned)(t+1), __ATOMIC_RELAXED, __HIP_MEMORY_SCOPE_AGENT);
    }
  }
}

// ---------------- persistent decoder: 24 steps x {GRU, pre, W1, SPL} ----------------
__constant__ int LVJ[14] = {0,1,6,8,9, 2,3,7,10,11, 4,5,12,13};
__constant__ int LVO[4]  = {0,5,10,14};
__constant__ int PAR_[14] = {-1,-1,0,1,2,3,-1,6,-1,-1,8,9,10,11};

#define GRL(S,C) { const ull* p_=(const ull*)(hs + hbase + (size_t)(C)*1024); qa##S=AL(p_); qb##S=AL(p_+1); }
#define GXL(S,C) { const ull* p_=(const ull*)(xpk + xbase + (size_t)(C)*1024); qa##S=AL(p_); qb##S=AL(p_+1); }
#define GRC(S,KS,GACC) { union{ull u[2];v8bf v;}c_; c_.u[0]=qa##S;c_.u[1]=qb##S; v8bf a_=c_.v; \
  v8bf w0_=*(const v8bf*)&Wl[(KS)*512+lane*8]; \
  v8bf w1_=*(const v8bf*)&Wl[18432+(KS)*512+lane*8]; \
  v8bf w2_=*(const v8bf*)&Wl[36864+(KS)*512+lane*8]; \
  aR=__builtin_amdgcn_mfma_f32_16x16x32_bf16(a_,w0_,aR,0,0,0); \
  aZ=__builtin_amdgcn_mfma_f32_16x16x32_bf16(a_,w1_,aZ,0,0,0); \
  GACC=__builtin_amdgcn_mfma_f32_16x16x32_bf16(a_,w2_,GACC,0,0,0); }

#define PRL(S,C) { const ull* p_=(const ull*)(hdp + hbase + (size_t)(C)*1024); qa##S=AL(p_); qb##S=AL(p_+1); }
#define PRC(S,KS) { union{ull u[2];v8bf v;}c_; c_.u[0]=qa##S;c_.u[1]=qb##S; \
  aP=__builtin_amdgcn_mfma_f32_16x16x32_bf16(c_.v, *(const v8bf*)&Wp[(KS)*512+lane*8], aP,0,0,0); }

// W1: M=64 x N=64 per block (mq=bid/28, ng=bid%28); wave = 16 rows x 32 cols
#define W1L(S,C) { const ull* p_=(const ull*)(hidpk + w1abase + (size_t)(C)*1024); \
  qa##S=AL(p_); qb##S=AL(p_+1); \
  bq##S = *(const uint4*)(w1b0 + (size_t)(C)*512 + lane*8); \
  br##S = *(const uint4*)(w1b1 + (size_t)(C)*512 + lane*8); }
#define W1C(S) { union{ull u[2];v8bf v;}x_; x_.u[0]=qa##S;x_.u[1]=qb##S; \
  union{uint4 q; v8bf v;}b0_,b1_; b0_.q=bq##S; b1_.q=br##S; \
  c0=__builtin_amdgcn_mfma_f32_16x16x32_bf16(x_.v,b0_.v,c0,0,0,0); \
  c1=__builtin_amdgcn_mfma_f32_16x16x32_bf16(x_.v,b1_.v,c1,0,0,0); }

__global__ __launch_bounds__(512) void dec_all(
    const bf16* __restrict__ Wpk, const float* __restrict__ bcat,
    const float* __restrict__ hA,
    bf16* __restrict__ hpk0, bf16* __restrict__ hpk1,
    const bf16* __restrict__ prepk, const float* __restrict__ preb,
    const float* __restrict__ motion, bf16* __restrict__ hidpk,
    const bf16* __restrict__ w1pk, const float* __restrict__ sb1,
    float* __restrict__ hhpre,
    const float* __restrict__ w1par, const float* __restrict__ sW2,
    const float* __restrict__ sb2,
    float* __restrict__ xcur, bf16* __restrict__ xpk, float* __restrict__ out,
    unsigned* __restrict__ prog)
{
  __shared__ bf16 Wl[3*36*512];     // 108 KB GRU weights
  __shared__ bf16 Wp[32*512];       // 32 KB preW slice
  __shared__ float preds_s[2][128];
  __shared__ float hh_s[128][3];

  const int tid = threadIdx.x, wave = tid >> 6, lane = tid & 63;
  const int bid = blockIdx.x;
  const int ub = bid >> 1, bs = bid & 1, u0 = ub*16;
  const int la = lane & 15, lb = lane >> 4;

  {
    const bf16* wsrc = Wpk + (size_t)ub*(3*36*512);
    #pragma unroll
    for (int i = 0; i < 14; ++i){ int c = i*512 + tid; if (c < 6912) GLD16(&Wl[c*8], wsrc + (size_t)c*8); }
    const bf16* psrc = prepk + (size_t)ub*(32*512);
    #pragma unroll
    for (int i = 0; i < 4; ++i){ int c = i*512 + tid; GLD16(&Wp[c*8], psrc + (size_t)c*8); }
  }
  VMWAIT(0); BARRIER();

  const int r0 = bs*128 + wave*16;
  const int rb = r0 >> 5, y = wave & 1;
  const int ucol = u0 + la;
  const float bR = bcat[ucol], bZ = bcat[1024+ucol], bI = bcat[2048+ucol], bN = bcat[3072+ucol];
  const float pB = preb[ucol];
  const size_t hbase = (size_t)rb*32768 + (size_t)y*512 + la*32 + lb*8;
  const size_t xbase = (size_t)rb*4096  + (size_t)y*512 + la*32 + lb*8;
  const size_t pwb   = (size_t)rb*32768 + (size_t)(u0>>5)*1024 + (size_t)y*512 + (u0&16) + la;
  // W1 phase: M=64 x N=64 per block
  const bool w1act = (bid < 112);
  const int mq = bid / 28, ng = bid % 28;
  const int mg = wave >> 1, nc = wave & 1;
  const int r0w = mq*64 + mg*16;
  const int w1rb = r0w >> 5, w1y = mg & 1;
  const size_t w1abase = (size_t)w1rb*32768 + (size_t)w1y*512 + la*32 + lb*8;
  const int ug0 = ng*4 + nc*2, ug1 = ug0 + 1;
  const bf16* w1b0 = w1pk + (size_t)ug0*(32*512);
  const bf16* w1b1 = w1pk + (size_t)ug1*(32*512);
  const float sb1a = w1act ? sb1[ug0*16 + la] : 0.f;
  const float sb1b = w1act ? sb1[ug1*16 + la] : 0.f;
  // SPL phase: 128 blocks x 2 batches
  const bool splact = (tid < 128);
  const int b0s = bid*2, th = tid;

  float hr[4];
  #pragma unroll
  for (int r = 0; r < 4; ++r) hr[r] = hA[(size_t)(r0 + lb*4 + r)*1024 + ucol];

  int ph = 0;
  auto PHSYNC = [&](void){
    ++ph;
    VMWAIT(0);
    __syncthreads();
    if (tid == 0) __hip_atomic_store(&prog[bid], (unsigned)ph, __ATOMIC_RELAXED, __HIP_MEMORY_SCOPE_AGENT);
    if (wave == 0){
      unsigned v1 = AL(&prog[lane]), v2 = AL(&prog[64 + lane]);
      while (__ballot((v1 >= (unsigned)ph) && (v2 >= (unsigned)ph)) != ~0ULL){
        __builtin_amdgcn_s_sleep(1);
        v1 = AL(&prog[lane]); v2 = AL(&prog[64 + lane]);
      }
    }
    __syncthreads();
    __builtin_amdgcn_sched_barrier(0);
  };

  ull qa0,qa1,qa2,qa3,qa4,qa5,qa6,qa7,qa8,qa9,qa10,qa11;
  ull qb0,qb1,qb2,qb3,qb4,qb5,qb6,qb7,qb8,qb9,qb10,qb11;
  uint4 bq0,bq1,bq2,bq3,bq4,bq5;
  uint4 br0,br1,br2,br3,br4,br5;

  for (int dt = 0; dt < PRED_; ++dt){
    // ---------- phase 1: GRU ----------
    const bf16* hs = (dt & 1) ? hpk1 : hpk0;
    bf16* hd = (dt & 1) ? hpk0 : hpk1;
    {
      GXL(0,0) GXL(1,1) GXL(2,2) GXL(3,3)
      GRL(4,0) GRL(5,1) GRL(6,2) GRL(7,3)
      GRL(8,4) GRL(9,5) GRL(10,6) GRL(11,7)
      f32x4 z4 = {0.f,0.f,0.f,0.f};
      f32x4 aR = z4, aZ = z4, aI = z4, aN = z4;
      GRC(0,0,aI)  GRL(0,8)
      GRC(1,1,aI)  GRL(1,9)
      GRC(2,2,aI)  GRL(2,10)
      GRC(3,3,aI)  GRL(3,11)
      GRC(4,4,aN)  GRL(4,12)
      GRC(5,5,aN)  GRL(5,13)
      GRC(6,6,aN)  GRL(6,14)
      GRC(7,7,aN)  GRL(7,15)
      GRC(8,8,aN)  GRL(8,16)
      GRC(9,9,aN)  GRL(9,17)
      GRC(10,10,aN) GRL(10,18)
      GRC(11,11,aN) GRL(11,19)
      GRC(0,12,aN) GRL(0,20)
      GRC(1,13,aN) GRL(1,21)
      GRC(2,14,aN) GRL(2,22)
      GRC(3,15,aN) GRL(3,23)
      GRC(4,16,aN) GRL(4,24)
      GRC(5,17,aN) GRL(5,25)
      GRC(6,18,aN) GRL(6,26)
      GRC(7,19,aN) GRL(7,27)
      GRC(8,20,aN) GRL(8,28)
      GRC(9,21,aN) GRL(9,29)
      GRC(10,22,aN) GRL(10,30)
      GRC(11,23,aN) GRL(11,31)
      GRC(0,24,aN)
      GRC(1,25,aN)
      GRC(2,26,aN)
      GRC(3,27,aN)
      GRC(4,28,aN)
      GRC(5,29,aN)
      GRC(6,30,aN)
      GRC(7,31,aN)
      GRC(8,32,aN)
      GRC(9,33,aN)
      GRC(10,34,aN)
      GRC(11,35,aN)
      #pragma unroll
      for (int r = 0; r < 4; ++r){
        float rg = 1.f/(1.f + __expf(-(aR[r] + bR)));
        float zg = 1.f/(1.f + __expf(-(aZ[r] + bZ)));
        float ng2 = tanhf((aI[r] + bI) + rg*(aN[r] + bN));
        float hv = (1.f - zg)*ng2 + zg*hr[r];
        hr[r] = hv;
        bf16 hv16 = __float2bfloat16(hv);
        __hip_atomic_store((unsigned short*)(hd + pwb + (size_t)(lb*4 + r)*32),
                           *(unsigned short*)&hv16, __ATOMIC_RELAXED, __HIP_MEMORY_SCOPE_AGENT);
      }
    }
    PHSYNC();

    // ---------- phase 2: pre (hid = relu(h@preW^T + preb) + motion) ----------
    {
      const bf16* hdp = hd;
      PRL(0,0) PRL(1,1) PRL(2,2) PRL(3,3) PRL(4,4) PRL(5,5)
      PRL(6,6) PRL(7,7) PRL(8,8) PRL(9,9) PRL(10,10) PRL(11,11)
      f32x4 aP = {0.f,0.f,0.f,0.f};
      PRC(0,0)  PRL(0,12)
      PRC(1,1)  PRL(1,13)
      PRC(2,2)  PRL(2,14)
      PRC(3,3)  PRL(3,15)
      PRC(4,4)  PRL(4,16)
      PRC(5,5)  PRL(5,17)
      PRC(6,6)  PRL(6,18)
      PRC(7,7)  PRL(7,19)
      PRC(8,8)  PRL(8,20)
      PRC(9,9)  PRL(9,21)
      PRC(10,10) PRL(10,22)
      PRC(11,11) PRL(11,23)
      PRC(0,12) PRL(0,24)
      PRC(1,13) PRL(1,25)
      PRC(2,14) PRL(2,26)
      PRC(3,15) PRL(3,27)
      PRC(4,16) PRL(4,28)
      PRC(5,17) PRL(5,29)
      PRC(6,18) PRL(6,30)
      PRC(7,19) PRL(7,31)
      PRC(8,20)
      PRC(9,21)
      PRC(10,22)
      PRC(11,23)
      PRC(0,24)
      PRC(1,25)
      PRC(2,26)
      PRC(3,27)
      PRC(4,28)
      PRC(5,29)
      PRC(6,30)
      PRC(7,31)
      #pragma unroll
      for (int r = 0; r < 4; ++r){
        int row = r0 + lb*4 + r;
        float v = fmaxf(aP[r] + pB, 0.f) + motion[(size_t)row*1024 + ucol];
        bf16 v16 = __float2bfloat16(v);
        __hip_atomic_store((unsigned short*)(hidpk + pwb + (size_t)(lb*4 + r)*32),
                           *(unsigned short*)&v16, __ATOMIC_RELAXED, __HIP_MEMORY_SCOPE_AGENT);
      }
    }
    PHSYNC();

    // ---------- phase 3: W1 (hhpre = hid @ W1^T + b1) ----------
    if (w1act){
      W1L(0,0) W1L(1,1) W1L(2,2) W1L(3,3) W1L(4,4) W1L(5,5)
      f32x4 c0 = {0.f,0.f,0.f,0.f}, c1 = c0;
      W1C(0) W1L(0,6)
      W1C(1) W1L(1,7)
      W1C(2) W1L(2,8)
      W1C(3) W1L(3,9)
      W1C(4) W1L(4,10)
      W1C(5) W1L(5,11)
      W1C(0) W1L(0,12)
      W1C(1) W1L(1,13)
      W1C(2) W1L(2,14)
      W1C(3) W1L(3,15)
      W1C(4) W1L(4,16)
      W1C(5) W1L(5,17)
      W1C(0) W1L(0,18)
      W1C(1) W1L(1,19)
      W1C(2) W1L(2,20)
      W1C(3) W1L(3,21)
      W1C(4) W1L(4,22)
      W1C(5) W1L(5,23)
      W1C(0) W1L(0,24)
      W1C(1) W1L(1,25)
      W1C(2) W1L(2,26)
      W1C(3) W1L(3,27)
      W1C(4) W1L(4,28)
      W1C(5) W1L(5,29)
      W1C(0) W1L(0,30)
      W1C(1) W1L(1,31)
      W1C(2)
      W1C(3)
      W1C(4)
      W1C(5)
      W1C(0)
      W1C(1)
      #pragma unroll
      for (int r = 0; r < 4; ++r){
        int row = r0w + lb*4 + r;
        __hip_atomic_store(&hhpre[(size_t)row*1792 + ug0*16 + la], c0[r] + sb1a,
                           __ATOMIC_RELAXED, __HIP_MEMORY_SCOPE_AGENT);
        __hip_atomic_store(&hhpre[(size_t)row*1792 + ug1*16 + la], c1[r] + sb1b,
                           __ATOMIC_RELAXED, __HIP_MEMORY_SCOPE_AGENT);
      }
    }
    PHSYNC();

    // ---------- phase 4: SPL chains + x/out update (128 blocks x 2 batches) ----------
    for (int L = 0; L < 3; ++L){
      for (int ji = LVO[L]; ji < LVO[L+1]; ++ji){
        int j = LVJ[ji], p = PAR_[j];
        if (splact){
          float acc[2];
          #pragma unroll
          for (int bb = 0; bb < 2; ++bb)
            acc[bb] = AL(&hhpre[(size_t)(b0s+bb)*1792 + j*128 + th]);
          if (p >= 0){
            #pragma unroll
            for (int ii = 0; ii < 9; ++ii){
              float w = w1par[(j*9 + ii)*128 + th];
              #pragma unroll
              for (int bb = 0; bb < 2; ++bb) acc[bb] += w * preds_s[bb][p*9 + ii];
            }
          }
          #pragma unroll
          for (int bb = 0; bb < 2; ++bb) hh_s[th][bb] = fmaxf(acc[bb], 0.f);
        }
        __syncthreads();
        if (splact && th < 36){
          int pp = th >> 1, half = th & 1;
          int bb = pp/9, oi = pp%9;
          const float* w2r = sW2 + (size_t)(j*9 + oi)*128 + half*64;
          float s = 0.f;
          #pragma unroll
          for (int ttt = 0; ttt < 64; ++ttt) s += hh_s[half*64 + ttt][bb] * w2r[ttt];
          s += __shfl_xor(s, 1);
          if (half == 0) preds_s[bb][j*9 + oi] = tanhf(s + sb2[j*9 + oi]);
        }
        __syncthreads();
      }
    }
    if (splact){
      for (int i = th; i < 2*D_; i += 128){
        int bb = i / D_, d = i % D_;
        int row = b0s + bb;
        size_t xi = (size_t)row*D_ + d;
        float v = xcur[xi] + preds_s[bb][d];
        xcur[xi] = v;
        bf16 v16 = __float2bfloat16(v);
        __hip_atomic_store((unsigned short*)(xpk + ((size_t)(row>>5)*4 + (d>>5))*1024 + (row&31)*32 + (d&31)),
                           *(unsigned short*)&v16, __ATOMIC_RELAXED, __HIP_MEMORY_SCOPE_AGENT);
        out[((size_t)row*PRED_ + dt)*D_ + d] = v;
      }
    }
    if (dt + 1 < PRED_) PHSYNC();
  }
}

// ---------------- pipelined generic GEMM (preamble only) ----------------
__global__ __launch_bounds__(256) void gemm64(
    const bf16* __restrict__ Am, const bf16* __restrict__ Bm, int K,
    const float* __restrict__ bias, const float* __restrict__ addmat,
    float* __restrict__ C, bf16* __restrict__ Cbf, int N, int MODE)
{
  __shared__ bf16 As[3][64*64];
  __shared__ bf16 Bs[3][64*64];
  const int tid = threadIdx.x;
  const int wave = tid >> 6, lane = tid & 63;
  const int m0 = blockIdx.x*64, n0 = blockIdx.y*64;
  const int fr = lane & 31, kh = lane >> 5;
  const int wm = (wave >> 1)*32, wn = (wave & 1)*32;
  const int KT = K >> 6;

  f32x16 acc = {0.f,0.f,0.f,0.f,0.f,0.f,0.f,0.f,0.f,0.f,0.f,0.f,0.f,0.f,0.f,0.f};

  auto STAGE = [&](int buf, int kt){
    #pragma unroll
    for (int q = 0; q < 2; ++q){
      int idx = q*256 + tid;
      int row = idx >> 3, cp = idx & 7, csw = cp ^ (row & 7);
      GLD16(&As[buf][idx*8], Am + (size_t)(m0+row)*K + kt*64 + csw*8);
    }
    #pragma unroll
    for (int q = 0; q < 2; ++q){
      int idx = q*256 + tid;
      int row = idx >> 3, cp = idx & 7, csw = cp ^ (row & 7);
      GLD16(&Bs[buf][idx*8], Bm + (size_t)(n0+row)*K + kt*64 + csw*8);
    }
  };
  auto COMPUTE = [&](int buf){
    const bf16* Ab = &As[buf][0];
    const bf16* Bb = &Bs[buf][0];
    #pragma unroll
    for (int ks = 0; ks < 4; ++ks){
      int ca = ks*2 + kh;
      v8bf av = *(const v8bf*)&Ab[(wm+fr)*64 + ((ca ^ ((wm+fr)&7))*8)];
      v8bf bv = *(const v8bf*)&Bb[(wn+fr)*64 + ((ca ^ ((wn+fr)&7))*8)];
      acc = __builtin_amdgcn_mfma_f32_32x32x16_bf16(av, bv, acc, 0, 0, 0);
    }
  };

  STAGE(0, 0);
  if (KT > 1){ STAGE(1, 1); VMWAIT(4); } else { VMWAIT(0); }
  BARRIER();
  for (int kt = 0; kt < KT; ++kt){
    if (kt + 2 < KT) STAGE((kt+2)%3, kt+2);
    COMPUTE(kt%3);
    if (kt + 2 < KT){ VMWAIT(4); BARRIER(); }
    else if (kt + 1 < KT){ VMWAIT(0); BARRIER(); }
  }

  const int col = n0 + wn + fr;
  float bb = bias ? bias[col] : 0.f;
  #pragma unroll
  for (int r = 0; r < 16; ++r){
    int row = m0 + wm + (r&3) + 8*(r>>2) + 4*kh;
    float v = acc[r] + bb;
    if (MODE == 1) v = fmaxf(v, 0.f) + addmat[(size_t)row*N + col];
    if (C)   C[(size_t)row*N + col] = v;
    if (Cbf) Cbf[(size_t)row*N + col] = __float2bfloat16(v);
  }
}

// ---------------- attention: one block per (b,h) ----------------
__global__ __launch_bounds__(256) void k_attn(const bf16* __restrict__ qkv,
                                              bf16* __restrict__ ctxbf){
  __shared__ char smem[65536];
  bf16* qs = (bf16*)smem;
  bf16* ks = qs + 64*256;
  float* sc = (float*)smem;
  float* cs = (float*)(smem + 32768);
  const int h = blockIdx.x, b = blockIdx.y;
  const int tid = threadIdx.x, wave = tid >> 6, lane = tid & 63;
  const int fr = lane & 31, kh = lane >> 5;
  const int wm = (wave >> 1)*32, wn = (wave & 1)*32;

  #pragma unroll
  for (int i = 0; i < 8; ++i){
    int idx = i*256 + tid;
    int row = idx >> 5, cp = idx & 31, csw = cp ^ (row & 7);
    GLD16(&qs[idx*8], qkv + (size_t)(b*F_ + row)*3072 + h*DH_ + csw*8);
  }
  #pragma unroll
  for (int i = 0; i < 8; ++i){
    int idx = i*256 + tid;
    int row = idx >> 5, cp = idx & 31, csw = cp ^ (row & 7);
    GLD16(&ks[idx*8], qkv + (size_t)(b*F_ + row)*3072 + H_ + h*DH_ + csw*8);
  }
  __syncthreads();

  f32x16 acc = {0.f,0.f,0.f,0.f,0.f,0.f,0.f,0.f,0.f,0.f,0.f,0.f,0.f,0.f,0.f,0.f};
  #pragma unroll
  for (int i = 0; i < 16; ++i){
    int ca = i*2 + kh;
    v8bf av = *(const v8bf*)&qs[((wm+fr)*32 + (ca ^ ((wm+fr)&7)))*8];
    v8bf bv = *(const v8bf*)&ks[((wn+fr)*32 + (ca ^ ((wn+fr)&7)))*8];
    acc = __builtin_amdgcn_mfma_f32_32x32x16_bf16(av, bv, acc, 0, 0, 0);
  }
  __syncthreads();
  #pragma unroll
  for (int r = 0; r < 16; ++r){
    int row = wm + (r&3) + 8*(r>>2) + 4*kh;
    sc[row*65 + (wn+fr)] = acc[r]*0.0625f;
  }
  __syncthreads();
  if (tid < F_){
    float m = -1e30f;
    for (int k2 = 0; k2 < F_; ++k2) m = fmaxf(m, sc[tid*65+k2]);
    float s = 0.f;
    for (int k2 = 0; k2 < F_; ++k2){ float e = __expf(sc[tid*65+k2]-m); sc[tid*65+k2] = e; s += e; }
    float is = 1.f/s;
    for (int k2 = 0; k2 < F_; ++k2) sc[tid*65+k2] *= is;
  }
  __syncthreads();
  if (tid < F_){
    float s = 0.f;
    for (int r = 0; r < F_; ++r) s += sc[r*65+tid];
    cs[tid] = s;
  }
  __syncthreads();
  float a = 0.f;
  for (int k2 = 0; k2 < F_; ++k2){
    float v = __bfloat162float(qkv[(size_t)(b*F_+k2)*3072 + 2*H_ + h*DH_ + tid]);
    a += cs[k2]*v;
  }
  ctxbf[(size_t)b*H_ + h*DH_ + tid] = __float2bfloat16(a * (1.f/61.f));
}

// ---------------- launch ----------------
extern "C" void kernel_launch(void* const* d_in, const int* in_sizes, int n_in,
                              void* d_out, int out_size, void* d_ws, size_t ws_size,
                              hipStream_t stream){
  (void)in_sizes; (void)n_in; (void)out_size; (void)ws_size;
  const float* poses = (const float*)d_in[0];
  const float* gWih  = (const float*)d_in[1];
  const float* gWhh  = (const float*)d_in[2];
  const float* gbih  = (const float*)d_in[3];
  const float* gbhh  = (const float*)d_in[4];
  const float* preW  = (const float*)d_in[5];
  const float* preb  = (const float*)d_in[6];
  const float* fpW   = (const float*)d_in[7];
  const float* fpb   = (const float*)d_in[8];
  const float* inW   = (const float*)d_in[9];
  const float* inb   = (const float*)d_in[10];
  const float* outW  = (const float*)d_in[11];
  const float* outb  = (const float*)d_in[12];
  const float* sW1   = (const float*)d_in[13];
  const float* sb1   = (const float*)d_in[14];
  const float* sW2   = (const float*)d_in[15];
  const float* sb2   = (const float*)d_in[16];
  float* out = (float*)d_out;

  char* w = (char*)d_ws;
  size_t off = 0;
  auto alloc = [&](size_t bytes)->char*{ char* p = w + off; off += (bytes + 255) & ~(size_t)255; return p; };
  float* cosT   = (float*)alloc(7320*4);
  float* bc     = (float*)alloc(3072*4);
  float* motion = (float*)alloc((size_t)256*1024*4);
  float* hA     = (float*)alloc((size_t)256*1024*4);
  float* xcur   = (float*)alloc((size_t)256*126*4);
  float* hhpre  = (float*)alloc((size_t)256*1792*4);
  float* bcat   = (float*)alloc(4096*4);
  float* w1par  = (float*)alloc(14*9*128*4);
  unsigned* prog= (unsigned*)alloc(1024);
  bf16* posespk = (bf16*)alloc((size_t)121*32768*2);
  bf16* Wcat    = (bf16*)alloc((size_t)4096*1152*2);
  bf16* Wpk     = (bf16*)alloc((size_t)64*108*512*2);
  bf16* prepk   = (bf16*)alloc((size_t)64*32*512*2);
  bf16* w1pk    = (bf16*)alloc((size_t)112*32*512*2);
  bf16* outbf   = (bf16*)alloc((size_t)1024*1024*2);
  bf16* inbf    = (bf16*)alloc((size_t)3072*1024*2);
  bf16* fpwt    = (bf16*)alloc((size_t)128*1024*2);
  bf16* ctxbf   = (bf16*)alloc((size_t)256*1024*2);
  bf16* hpkA    = (bf16*)alloc((size_t)256*1024*2);
  bf16* hpkB    = (bf16*)alloc((size_t)256*1024*2);
  bf16* hidpk   = (bf16*)alloc((size_t)256*1024*2);
  bf16* xpk     = (bf16*)alloc((size_t)32768*2);
  bf16* Wcbf    = (bf16*)alloc((size_t)3072*128*2);
  bf16* freqbf  = (bf16*)alloc((size_t)B_*F_*128*2);
  bf16* qkvbf   = (bf16*)alloc((size_t)15680*3072*2);

  hipMemsetAsync(hpkA, 0, (size_t)256*1024*2, stream);
  hipMemsetAsync(prog, 0, 1024, stream);

  k_cos<<<29, 256, 0, stream>>>(cosT);
  k_dft2<<<B_, 256, 0, stream>>>(poses, cosT, freqbf);
  c_poses<<<dim3(SEED_, B_), 128, 0, stream>>>(poses, posespk);
  c_xinit<<<B_, 128, 0, stream>>>(poses, xcur, xpk);
  c_wcat<<<4096, 256, 0, stream>>>(gWih, gWhh, Wcat);
  c_bcat<<<16, 256, 0, stream>>>(gbih, gbhh, bcat);
  c_wpk<<<1728, 256, 0, stream>>>(Wcat, Wpk);
  c_ppk<<<512, 256, 0, stream>>>(preW, prepk);
  c_w1pk<<<896, 256, 0, stream>>>(sW1, w1pk);
  c_w1par<<<63, 256, 0, stream>>>(sW1, w1par);
  c_bf<<<4096, 256, 0, stream>>>(outW, outbf, 1024*1024);
  c_bf<<<12288, 256, 0, stream>>>(inW, inbf, 3072*1024);
  c_fpwt<<<128, 256, 0, stream>>>(fpW, fpwt);
  k_bc<<<768, 256, 0, stream>>>(inW, inb, fpb, bc);

  // Wc = inproj @ fp_W  (3072 x 128, bf16)
  gemm64<<<dim3(48, 2), 256, 0, stream>>>(inbf, fpwt, 1024, nullptr, nullptr, nullptr, Wcbf, 128, 0);
  // qkv = freq @ Wc^T + bc  (15616 x 3072, bf16)
  gemm64<<<dim3(244, 48), 256, 0, stream>>>(freqbf, Wcbf, 128, bc, nullptr, nullptr, qkvbf, 3072, 0);
  k_attn<<<dim3(HEADS_, B_), 256, 0, stream>>>(qkvbf, ctxbf);
  // motion_ctx = ctx_mean @ outproj^T + outb
  gemm64<<<dim3(4, 16), 256, 0, stream>>>(ctxbf, outbf, 1024, outb, nullptr, motion, nullptr, 1024, 0);

  // encoder: cooperative, fence-free coherent h, 120 steps; final h -> hA, packed -> hpkA
  {
    const bf16* a0 = posespk; int a1 = 32768; int a2 = SEED_; int a3 = 1;
    const bf16* a4 = Wpk; const float* a5 = bcat;
    const float* a6 = hA; float* a7 = hA; bf16* a8 = nullptr;
    bf16* a9 = hpkA; bf16* a10 = hpkB; unsigned* a11 = prog;
    void* args[] = { &a0, &a1, &a2, &a3, &a4, &a5, &a6, &a7, &a8, &a9, &a10, &a11 };
    hipLaunchCooperativeKernel(reinterpret_cast<void*>(gru_wave), dim3(128), dim3(512),
                               args, 0, stream);
  }

  // persistent decoder: 24 steps x {GRU, pre, W1, SPL}, flag-synced
  {
    const bf16* a0 = Wpk; const float* a1 = bcat; const float* a2 = hA;
    bf16* a3 = hpkA; bf16* a4 = hpkB;
    const bf16* a5 = prepk; const float* a6 = preb; const float* a7 = motion;
    bf16* a8 = hidpk; const bf16* a9 = w1pk; const float* a10 = sb1;
    float* a11 = hhpre;
    const float* a12 = w1par; const float* a13 = sW2; const float* a14 = sb2;
    float* a15 = xcur; bf16* a16 = xpk; float* a17 = out;
    unsigned* a18 = prog + 128;
    void* args[] = { &a0, &a1, &a2, &a3, &a4, &a5, &a6, &a7, &a8, &a9, &a10,
                     &a11, &a12, &a13, &a14, &a15, &a16, &a17, &a18 };
    hipLaunchCooperativeKernel(reinterpret_cast<void*>(dec_all), dim3(128), dim3(512),
                               args, 0, stream);
  }
}

// Round 13
// 4124.789 us; speedup vs baseline: 1.0665x; 1.0499x over previous
//
#include <hip/hip_runtime.h>
#include <hip/hip_bf16.h>

typedef __hip_bfloat16 bf16;
typedef __attribute__((ext_vector_type(8))) short v8bf;     // 8 bf16 (4 VGPR)
typedef __attribute__((ext_vector_type(16))) float f32x16;
typedef __attribute__((ext_vector_type(4))) float f32x4;
typedef unsigned long long ull;

#define B_    256
#define SEED_ 120
#define PRED_ 24
#define D_    126
#define H_    1024
#define F_    61
#define HEADS_ 4
#define DH_   256

#define GLD16(lds, g) __builtin_amdgcn_global_load_lds( \
    (const __attribute__((address_space(1))) unsigned int*)(g), \
    (__attribute__((address_space(3))) unsigned int*)(lds), 16, 0, 0)
#define VMWAIT(n) asm volatile("s_waitcnt vmcnt(" #n ")" ::: "memory")
#define BARRIER() do { __builtin_amdgcn_s_barrier(); __builtin_amdgcn_sched_barrier(0); } while(0)
#define AL(P) __hip_atomic_load((P), __ATOMIC_RELAXED, __HIP_MEMORY_SCOPE_AGENT)

// ---------------- small precompute kernels ----------------
__global__ void k_cos(float* cosT){
  int i = blockIdx.x*256 + threadIdx.x;
  if (i < F_*SEED_){
    int f = i / SEED_, t = i % SEED_;
    int ph = (f*t) % SEED_;
    cosT[i] = cosf(6.283185307179586f * (float)ph / (float)SEED_);
  }
}

__global__ __launch_bounds__(256) void k_dft2(const float* __restrict__ poses,
                      const float* __restrict__ cosT, bf16* __restrict__ freqbf){
  __shared__ float pl[SEED_*128];      // 60 KB
  int b = blockIdx.x, tid = threadIdx.x;
  for (int i = tid; i < SEED_*D_; i += 256){
    int t = i / D_, d = i - t*D_;
    pl[t*128 + d] = poses[((size_t)b*(SEED_+PRED_) + t)*D_ + d];
  }
  __syncthreads();
  int d = tid & 127, f0 = tid >> 7;    // f = f0 + 2j
  float acc[31];
  #pragma unroll
  for (int j = 0; j < 31; ++j) acc[j] = 0.f;
  for (int t = 0; t < SEED_; ++t){
    float v = pl[t*128 + d];
    #pragma unroll
    for (int j = 0; j < 31; ++j){
      int f = f0 + j*2;
      if (f < F_) acc[j] += cosT[f*SEED_ + t] * v;
    }
  }
  #pragma unroll
  for (int j = 0; j < 31; ++j){
    int f = f0 + j*2;
    if (f < F_) freqbf[((size_t)b*F_ + f)*128 + d] = __float2bfloat16(d < D_ ? acc[j] : 0.f);
  }
}

// pack poses into per-step 32x32 tiles
__global__ void c_poses(const float* __restrict__ poses, bf16* __restrict__ pk){
  int t = blockIdx.x, b = blockIdx.y, c = threadIdx.x;  // block 128
  float v = (c < D_) ? poses[((size_t)b*(SEED_+PRED_) + t)*D_ + c] : 0.f;
  pk[(size_t)t*32768 + ((b>>5)*4 + (c>>5))*1024 + (b&31)*32 + (c&31)] = __float2bfloat16(v);
}

__global__ void c_xinit(const float* __restrict__ poses, float* __restrict__ x, bf16* __restrict__ xpk){
  int b = blockIdx.x, c = threadIdx.x;  // block 128
  float v = (c < D_) ? poses[((size_t)b*(SEED_+PRED_) + (SEED_-1))*D_ + c] : 0.f;
  if (c < D_) x[b*D_ + c] = v;
  xpk[((b>>5)*4 + (c>>5))*1024 + (b&31)*32 + (c&31)] = __float2bfloat16(v);
}

__global__ void c_bf(const float* __restrict__ s, bf16* __restrict__ d, int n){
  int i = blockIdx.x*256 + threadIdx.x;
  if (i < n) d[i] = __float2bfloat16(s[i]);
}

__global__ void c_fpwt(const float* __restrict__ fpW, bf16* __restrict__ o){
  int dd = blockIdx.x;                       // 0..127
  for (int k = threadIdx.x; k < H_; k += 256)
    o[(size_t)dd*H_ + k] = __float2bfloat16(dd < D_ ? fpW[(size_t)k*D_ + dd] : 0.f);
}

// combined GRU weight rows (1152 wide: 128 x-cols | 1024 h-cols)
__global__ void c_wcat(const float* __restrict__ Wih, const float* __restrict__ Whh, bf16* __restrict__ o){
  int r = blockIdx.x;
  int jr; bool hasx, hash;
  if (r < 2048){ jr = r; hasx = true; hash = true; }
  else if (r < 3072){ jr = r; hasx = true; hash = false; }
  else { jr = r - 1024; hasx = false; hash = true; }
  bf16* row = o + (size_t)r*1152;
  for (int c = threadIdx.x; c < 1152; c += 256){
    float v = 0.f;
    if (c < D_) { if (hasx) v = Wih[(size_t)jr*D_ + c]; }
    else if (c >= 128){ if (hash) v = Whh[(size_t)jr*H_ + (c-128)]; }
    row[c] = __float2bfloat16(v);
  }
}

__global__ void c_bcat(const float* __restrict__ bih, const float* __restrict__ bhh, float* __restrict__ o){
  int r = blockIdx.x*256 + threadIdx.x;
  if (r >= 4096) return;
  float v;
  if (r < 2048) v = bih[r] + bhh[r];
  else if (r < 3072) v = bih[r];
  else v = bhh[r - 1024];
  o[r] = v;
}

// pack GRU weights into MFMA B-fragment order
__global__ __launch_bounds__(256) void c_wpk(const bf16* __restrict__ Wcat, bf16* __restrict__ Wpk){
  int chunk = blockIdx.x*4 + (threadIdx.x >> 6);
  int l = threadIdx.x & 63;
  int ks = chunk % 36; int t2 = chunk / 36; int g = t2 % 3; int ub = t2 / 3;
  int unit = ub*16 + (l & 15);
  bf16* dst = Wpk + (size_t)chunk*512 + l*8;
  #pragma unroll
  for (int e = 0; e < 8; ++e){
    int k = ks*32 + (l>>4)*8 + e;
    int row = (g==0) ? unit : (g==1) ? (1024+unit) : (k < 128 ? 2048+unit : 3072+unit);
    dst[e] = Wcat[(size_t)row*1152 + k];
  }
}

// pack preW into fragment order: chunk = ub*32+ks
__global__ __launch_bounds__(256) void c_ppk(const float* __restrict__ preW, bf16* __restrict__ prepk){
  int chunk = blockIdx.x*4 + (threadIdx.x >> 6);   // 2048 chunks
  int l = threadIdx.x & 63;
  int ks = chunk & 31, ub = chunk >> 5;
  int unit = ub*16 + (l & 15);
  bf16* dst = prepk + (size_t)chunk*512 + l*8;
  #pragma unroll
  for (int e = 0; e < 8; ++e)
    dst[e] = __float2bfloat16(preW[(size_t)unit*1024 + ks*32 + (l>>4)*8 + e]);
}

// pack W1-hid into fragment order: chunk = ug*32+ks, ug 0..111
__global__ __launch_bounds__(256) void c_w1pk(const float* __restrict__ sW1, bf16* __restrict__ w1pk){
  int chunk = blockIdx.x*4 + (threadIdx.x >> 6);   // 3584 chunks
  int l = threadIdx.x & 63;
  int ks = chunk & 31, ng = chunk >> 5;
  int unit = ng*16 + (l & 15);
  int j = unit >> 7, rr = unit & 127;
  bf16* dst = w1pk + (size_t)chunk*512 + l*8;
  #pragma unroll
  for (int e = 0; e < 8; ++e){
    int k = ks*32 + (l>>4)*8 + e;
    dst[e] = __float2bfloat16(sW1[((size_t)j*128 + rr)*1033 + k]);
  }
}

// pack SPL parent weights: w1par[(j*9+ii)*128 + t] = sW1[(j*128+t)*1033 + 1024 + ii]
__global__ void c_w1par(const float* __restrict__ sW1, float* __restrict__ w1par){
  int i = blockIdx.x*256 + threadIdx.x;
  if (i < 14*9*128){
    int j = i / (9*128); int rem = i % (9*128); int ii = rem / 128; int th = rem % 128;
    w1par[i] = sW1[((size_t)(j*128 + th))*1033 + 1024 + ii];
  }
}

// bc = inproj @ fp_b + in_b
__global__ __launch_bounds__(256) void k_bc(const float* __restrict__ inW, const float* __restrict__ inb,
                     const float* __restrict__ fpb, float* __restrict__ bc){
  int wave = threadIdx.x >> 6, lane = threadIdx.x & 63;
  int r = blockIdx.x*4 + wave;
  const float4* row = (const float4*)(inW + (size_t)r*H_);
  const float4* fp4 = (const float4*)fpb;
  float s = 0.f;
  #pragma unroll
  for (int i = 0; i < 4; ++i){
    float4 a = row[lane + i*64];
    float4 b = fp4[lane + i*64];
    s += a.x*b.x + a.y*b.y + a.z*b.z + a.w*b.w;
  }
  #pragma unroll
  for (int off = 32; off; off >>= 1) s += __shfl_down(s, off);
  if (lane == 0) bc[r] = s + inb[r];
}

// ---------------- encoder: wave-autonomous GRU (R10, unchanged) ----------------
#define SLCP(QA, QB, KS, GACC) { \
  union { ull u[2]; v8bf v; } cc_; cc_.u[0]=(QA); cc_.u[1]=(QB); \
  v8bf a_ = cc_.v; \
  v8bf w0_ = *(const v8bf*)&Wl[(0*36+(KS))*512 + lane*8]; \
  v8bf w1_ = *(const v8bf*)&Wl[(1*36+(KS))*512 + lane*8]; \
  v8bf w2_ = *(const v8bf*)&Wl[(2*36+(KS))*512 + lane*8]; \
  aR = __builtin_amdgcn_mfma_f32_16x16x32_bf16(a_, w0_, aR, 0,0,0); \
  aZ = __builtin_amdgcn_mfma_f32_16x16x32_bf16(a_, w1_, aZ, 0,0,0); \
  GACC = __builtin_amdgcn_mfma_f32_16x16x32_bf16(a_, w2_, GACC, 0,0,0); }

#define LDHA(DA, DB, C) { \
  const ull* hp_ = (const ull*)(hs + hbase + (size_t)(C)*1024); \
  DA = AL(hp_); DB = AL(hp_+1); }

#define LDXP(DA, DB, TT, C) { \
  const ull* xp_ = (const ull*)(xpk + (size_t)(TT)*xstride + xbase + (size_t)(C)*1024); \
  DA = xp_[0]; DB = xp_[1]; }

__global__ __launch_bounds__(512) void gru_wave(
    const bf16* __restrict__ xpk, int xstride, int nsteps, int coop,
    const bf16* __restrict__ Wpk, const float* __restrict__ bcat,
    const float* __restrict__ hin_plain, float* __restrict__ hout_plain,
    bf16* __restrict__ hbplain,
    bf16* __restrict__ hpk0, bf16* __restrict__ hpk1,
    unsigned* __restrict__ prog)
{
  __shared__ bf16 Wl[3*36*512];       // 108 KB
  const int tid = threadIdx.x, wave = tid >> 6, lane = tid & 63;
  const int ub = blockIdx.x >> 1, bs = blockIdx.x & 1;
  const int u0 = ub*16;

  {
    const bf16* wsrc = Wpk + (size_t)ub*(3*36*512);
    #pragma unroll
    for (int i = 0; i < 14; ++i){
      int c = i*512 + tid;
      if (c < 6912) GLD16(&Wl[c*8], wsrc + (size_t)c*8);
    }
  }
  VMWAIT(0); BARRIER();

  const int la = lane & 15, lb = lane >> 4;
  const int r0 = bs*128 + wave*16;
  const int rb = r0 >> 5, y = wave & 1;
  const int ucol = u0 + la;
  const float bR = bcat[ucol], bZ = bcat[1024+ucol], bI = bcat[2048+ucol], bN = bcat[3072+ucol];
  const size_t hbase = (size_t)rb*32768 + (size_t)y*512 + la*32 + lb*8;
  const size_t xbase = (size_t)rb*4096  + (size_t)y*512 + la*32 + lb*8;
  const size_t pwb = (size_t)rb*32768 + (size_t)(u0>>5)*1024 + (size_t)y*512 + (u0&16) + la;

  float hr[4];
  if (nsteps == 1){
    #pragma unroll
    for (int r = 0; r < 4; ++r) hr[r] = hin_plain[(size_t)(r0 + lb*4 + r)*1024 + ucol];
  } else {
    #pragma unroll
    for (int r = 0; r < 4; ++r) hr[r] = 0.f;
  }

  ull a0,a1,a2,a3,a4,a5,a6,a7,a8,a9,a10,a11;
  ull b0,b1,b2,b3,b4,b5,b6,b7,b8,b9,b10,b11;
  LDXP(a0,b0,0,0); LDXP(a1,b1,0,1); LDXP(a2,b2,0,2); LDXP(a3,b3,0,3);

  for (int t = 0; t < nsteps; ++t){
    if (coop && t > 0){
      if (wave == 0){
        unsigned v = AL(&prog[bs*64 + lane]);
        while (__ballot(v >= (unsigned)t) != ~0ULL){
          __builtin_amdgcn_s_sleep(1);
          v = AL(&prog[bs*64 + lane]);
        }
      }
      __syncthreads();
      __builtin_amdgcn_sched_barrier(0);
    }
    const bf16* hs = (t & 1) ? hpk1 : hpk0;
    LDHA(a4,b4,0) LDHA(a5,b5,1) LDHA(a6,b6,2) LDHA(a7,b7,3)
    LDHA(a8,b8,4) LDHA(a9,b9,5) LDHA(a10,b10,6) LDHA(a11,b11,7)

    f32x4 z4 = {0.f,0.f,0.f,0.f};
    f32x4 aR = z4, aZ = z4, aI = z4, aN = z4;

    SLCP(a0,b0,0,aI)  LDHA(a0,b0,8)
    SLCP(a1,b1,1,aI)  LDHA(a1,b1,9)
    SLCP(a2,b2,2,aI)  LDHA(a2,b2,10)
    SLCP(a3,b3,3,aI)  LDHA(a3,b3,11)
    SLCP(a4,b4,4,aN)  LDHA(a4,b4,12)
    SLCP(a5,b5,5,aN)  LDHA(a5,b5,13)
    SLCP(a6,b6,6,aN)  LDHA(a6,b6,14)
    SLCP(a7,b7,7,aN)  LDHA(a7,b7,15)
    SLCP(a8,b8,8,aN)  LDHA(a8,b8,16)
    SLCP(a9,b9,9,aN)  LDHA(a9,b9,17)
    SLCP(a10,b10,10,aN) LDHA(a10,b10,18)
    SLCP(a11,b11,11,aN) LDHA(a11,b11,19)
    SLCP(a0,b0,12,aN) LDHA(a0,b0,20)
    SLCP(a1,b1,13,aN) LDHA(a1,b1,21)
    SLCP(a2,b2,14,aN) LDHA(a2,b2,22)
    SLCP(a3,b3,15,aN) LDHA(a3,b3,23)
    SLCP(a4,b4,16,aN) LDHA(a4,b4,24)
    SLCP(a5,b5,17,aN) LDHA(a5,b5,25)
    SLCP(a6,b6,18,aN) LDHA(a6,b6,26)
    SLCP(a7,b7,19,aN) LDHA(a7,b7,27)
    SLCP(a8,b8,20,aN) LDHA(a8,b8,28)
    SLCP(a9,b9,21,aN) LDHA(a9,b9,29)
    SLCP(a10,b10,22,aN) LDHA(a10,b10,30)
    SLCP(a11,b11,23,aN) LDHA(a11,b11,31)
    SLCP(a0,b0,24,aN) LDXP(a0,b0,t+1,0)
    SLCP(a1,b1,25,aN) LDXP(a1,b1,t+1,1)
    SLCP(a2,b2,26,aN) LDXP(a2,b2,t+1,2)
    SLCP(a3,b3,27,aN) LDXP(a3,b3,t+1,3)
    SLCP(a4,b4,28,aN)
    SLCP(a5,b5,29,aN)
    SLCP(a6,b6,30,aN)
    SLCP(a7,b7,31,aN)
    SLCP(a8,b8,32,aN)
    SLCP(a9,b9,33,aN)
    SLCP(a10,b10,34,aN)
    SLCP(a11,b11,35,aN)

    bf16* hd = (t & 1) ? hpk0 : hpk1;
    const bool last = (t == nsteps-1);
    #pragma unroll
    for (int r = 0; r < 4; ++r){
      float rg = 1.f/(1.f + __expf(-(aR[r] + bR)));
      float zg = 1.f/(1.f + __expf(-(aZ[r] + bZ)));
      float ng = tanhf((aI[r] + bI) + rg*(aN[r] + bN));
      float hv = (1.f - zg)*ng + zg*hr[r];
      hr[r] = hv;
      bf16 hv16 = __float2bfloat16(hv);
      unsigned short hbits = *(unsigned short*)&hv16;
      __hip_atomic_store((unsigned short*)(hd + pwb + (size_t)(lb*4 + r)*32), hbits,
                         __ATOMIC_RELAXED, __HIP_MEMORY_SCOPE_AGENT);
      if (last){
        hout_plain[(size_t)(r0 + lb*4 + r)*1024 + ucol] = hv;
        if (hbplain) hbplain[(size_t)(r0 + lb*4 + r)*1024 + ucol] = __float2bfloat16(hv);
      }
    }
    if (coop && t + 1 < nsteps){
      VMWAIT(0);
      __syncthreads();
      if (tid == 0)
        __hip_atomic_store(&prog[bs*64 + ub], (unsigned)(t+1), __ATOMIC_RELAXED, __HIP_MEMORY_SCOPE_AGENT);
    }
  }
}

// ---------------- persistent decoder: 24 steps x {GRU, pre, W1, SPL} ----------------
__constant__ int LVJ[14] = {0,1,6,8,9, 2,3,7,10,11, 4,5,12,13};
__constant__ int LVO[4]  = {0,5,10,14};
__constant__ int PAR_[14] = {-1,-1,0,1,2,3,-1,6,-1,-1,8,9,10,11};

#define GRL(S,C) { const ull* p_=(const ull*)(hs + hbase + (size_t)(C)*1024); qa##S=AL(p_); qb##S=AL(p_+1); }
#define GXL(S,C) { const ull* p_=(const ull*)(xpk + xbase + (size_t)(C)*1024); qa##S=AL(p_); qb##S=AL(p_+1); }
#define GRC(S,KS,GACC) { union{ull u[2];v8bf v;}c_; c_.u[0]=qa##S;c_.u[1]=qb##S; v8bf a_=c_.v; \
  v8bf w0_=*(const v8bf*)&Wl[(KS)*512+lane*8]; \
  v8bf w1_=*(const v8bf*)&Wl[18432+(KS)*512+lane*8]; \
  v8bf w2_=*(const v8bf*)&Wl[36864+(KS)*512+lane*8]; \
  aR=__builtin_amdgcn_mfma_f32_16x16x32_bf16(a_,w0_,aR,0,0,0); \
  aZ=__builtin_amdgcn_mfma_f32_16x16x32_bf16(a_,w1_,aZ,0,0,0); \
  GACC=__builtin_amdgcn_mfma_f32_16x16x32_bf16(a_,w2_,GACC,0,0,0); }

#define PRL(S,C) { const ull* p_=(const ull*)(hdp + hbase + (size_t)(C)*1024); qa##S=AL(p_); qb##S=AL(p_+1); }
#define PRC(S,KS) { union{ull u[2];v8bf v;}c_; c_.u[0]=qa##S;c_.u[1]=qb##S; \
  aP=__builtin_amdgcn_mfma_f32_16x16x32_bf16(c_.v, *(const v8bf*)&Wp[(KS)*512+lane*8], aP,0,0,0); }

// W1: M=64 x N=64 per block (mq=bid/28, ng=bid%28); wave = 16 rows x 32 cols
#define W1L(S,C) { const ull* p_=(const ull*)(hidpk + w1abase + (size_t)(C)*1024); \
  qa##S=AL(p_); qb##S=AL(p_+1); \
  bq##S = *(const uint4*)(w1b0 + (size_t)(C)*512 + lane*8); \
  br##S = *(const uint4*)(w1b1 + (size_t)(C)*512 + lane*8); }
#define W1C(S) { union{ull u[2];v8bf v;}x_; x_.u[0]=qa##S;x_.u[1]=qb##S; \
  union{uint4 q; v8bf v;}b0_,b1_; b0_.q=bq##S; b1_.q=br##S; \
  c0=__builtin_amdgcn_mfma_f32_16x16x32_bf16(x_.v,b0_.v,c0,0,0,0); \
  c1=__builtin_amdgcn_mfma_f32_16x16x32_bf16(x_.v,b1_.v,c1,0,0,0); }

__global__ __launch_bounds__(512) void dec_all(
    const bf16* __restrict__ Wpk, const float* __restrict__ bcat,
    const float* __restrict__ hA,
    bf16* __restrict__ hpk0, bf16* __restrict__ hpk1,
    const bf16* __restrict__ prepk, const float* __restrict__ preb,
    const float* __restrict__ motion, bf16* __restrict__ hidpk,
    const bf16* __restrict__ w1pk, const float* __restrict__ sb1,
    float* __restrict__ hhpre,
    const float* __restrict__ w1par, const float* __restrict__ sW2,
    const float* __restrict__ sb2,
    float* __restrict__ xcur, bf16* __restrict__ xpk, float* __restrict__ out,
    unsigned* __restrict__ prog, unsigned* __restrict__ progS)
{
  __shared__ bf16 Wl[3*36*512];     // 108 KB GRU weights
  __shared__ bf16 Wp[32*512];       // 32 KB preW slice
  __shared__ float hhl[2][1792];    // 14 KB SPL input stage
  __shared__ float preds_s[2][128];
  __shared__ float hh_s[128][2];

  const int tid = threadIdx.x, wave = tid >> 6, lane = tid & 63;
  const int bid = blockIdx.x;
  const int ub = bid >> 1, bs = bid & 1, u0 = ub*16;
  const int la = lane & 15, lb = lane >> 4;

  {
    const bf16* wsrc = Wpk + (size_t)ub*(3*36*512);
    #pragma unroll
    for (int i = 0; i < 14; ++i){ int c = i*512 + tid; if (c < 6912) GLD16(&Wl[c*8], wsrc + (size_t)c*8); }
    const bf16* psrc = prepk + (size_t)ub*(32*512);
    #pragma unroll
    for (int i = 0; i < 4; ++i){ int c = i*512 + tid; GLD16(&Wp[c*8], psrc + (size_t)c*8); }
  }
  VMWAIT(0); BARRIER();

  const int r0 = bs*128 + wave*16;
  const int rb = r0 >> 5, y = wave & 1;
  const int ucol = u0 + la;
  const float bR = bcat[ucol], bZ = bcat[1024+ucol], bI = bcat[2048+ucol], bN = bcat[3072+ucol];
  const float pB = preb[ucol];
  const size_t hbase = (size_t)rb*32768 + (size_t)y*512 + la*32 + lb*8;
  const size_t xbase = (size_t)rb*4096  + (size_t)y*512 + la*32 + lb*8;
  const size_t pwb   = (size_t)rb*32768 + (size_t)(u0>>5)*1024 + (size_t)y*512 + (u0&16) + la;
  // W1 phase: M=64 x N=64 per block
  const bool w1act = (bid < 112);
  const int mq = bid / 28, ng = bid % 28;
  const int mg = wave >> 1, nc = wave & 1;
  const int r0w = mq*64 + mg*16;
  const int w1rb = r0w >> 5, w1y = mg & 1;
  const size_t w1abase = (size_t)w1rb*32768 + (size_t)w1y*512 + la*32 + lb*8;
  const int ug0 = ng*4 + nc*2, ug1 = ug0 + 1;
  const bf16* w1b0 = w1pk + (size_t)ug0*(32*512);
  const bf16* w1b1 = w1pk + (size_t)ug1*(32*512);
  const float sb1a = w1act ? sb1[ug0*16 + la] : 0.f;
  const float sb1b = w1act ? sb1[ug1*16 + la] : 0.f;
  // SPL phase: 128 blocks x 2 batches
  const int b0s = bid*2, th = tid;

  float hr[4];
  #pragma unroll
  for (int r = 0; r < 4; ++r) hr[r] = hA[(size_t)(r0 + lb*4 + r)*1024 + ucol];

  int ph = 0;
  auto PHSYNC = [&](void){
    ++ph;
    VMWAIT(0);
    __syncthreads();
    if (tid == 0) __hip_atomic_store(&prog[bid], (unsigned)ph, __ATOMIC_RELAXED, __HIP_MEMORY_SCOPE_AGENT);
    if (wave == 0){
      unsigned v1 = AL(&prog[lane]), v2 = AL(&prog[64 + lane]);
      while (__ballot((v1 >= (unsigned)ph) && (v2 >= (unsigned)ph)) != ~0ULL){
        __builtin_amdgcn_s_sleep(2);
        v1 = AL(&prog[lane]); v2 = AL(&prog[64 + lane]);
      }
    }
    __syncthreads();
    __builtin_amdgcn_sched_barrier(0);
  };

  ull qa0,qa1,qa2,qa3,qa4,qa5,qa6,qa7,qa8,qa9,qa10,qa11;
  ull qb0,qb1,qb2,qb3,qb4,qb5,qb6,qb7,qb8,qb9,qb10,qb11;
  uint4 bq0,bq1,bq2,bq3,bq4,bq5;
  uint4 br0,br1,br2,br3,br4,br5;

  for (int dt = 0; dt < PRED_; ++dt){
    // ---------- phase 1: GRU (h-slices first; x-slices after SPL flag) ----------
    const bf16* hs = (dt & 1) ? hpk1 : hpk0;
    bf16* hd = (dt & 1) ? hpk0 : hpk1;
    {
      GRL(0,0) GRL(1,1) GRL(2,2) GRL(3,3) GRL(4,4) GRL(5,5)
      GRL(6,6) GRL(7,7) GRL(8,8) GRL(9,9) GRL(10,10) GRL(11,11)
      f32x4 z4 = {0.f,0.f,0.f,0.f};
      f32x4 aR = z4, aZ = z4, aI = z4, aN = z4;
      GRC(0,4,aN)  GRL(0,12)
      GRC(1,5,aN)  GRL(1,13)
      GRC(2,6,aN)  GRL(2,14)
      GRC(3,7,aN)  GRL(3,15)
      GRC(4,8,aN)  GRL(4,16)
      GRC(5,9,aN)  GRL(5,17)
      GRC(6,10,aN) GRL(6,18)
      GRC(7,11,aN) GRL(7,19)
      GRC(8,12,aN) GRL(8,20)
      GRC(9,13,aN) GRL(9,21)
      GRC(10,14,aN) GRL(10,22)
      GRC(11,15,aN) GRL(11,23)
      GRC(0,16,aN) GRL(0,24)
      GRC(1,17,aN) GRL(1,25)
      GRC(2,18,aN) GRL(2,26)
      GRC(3,19,aN) GRL(3,27)
      GRC(4,20,aN) GRL(4,28)
      GRC(5,21,aN) GRL(5,29)
      GRC(6,22,aN) GRL(6,30)
      GRC(7,23,aN) GRL(7,31)
      GRC(8,24,aN)
      GRC(9,25,aN)
      GRC(10,26,aN)
      GRC(11,27,aN)
      GRC(0,28,aN)
      GRC(1,29,aN)
      GRC(2,30,aN)
      GRC(3,31,aN)
      GRC(4,32,aN)
      GRC(5,33,aN)
      GRC(6,34,aN)
      GRC(7,35,aN)
      // wait for previous step's SPL (x ready), hidden behind the 32 h-slices
      if (dt > 0){
        if (wave == 0){
          unsigned v1 = AL(&progS[lane]), v2 = AL(&progS[64 + lane]);
          while (__ballot((v1 >= (unsigned)dt) && (v2 >= (unsigned)dt)) != ~0ULL){
            __builtin_amdgcn_s_sleep(2);
            v1 = AL(&progS[lane]); v2 = AL(&progS[64 + lane]);
          }
        }
        __syncthreads();
        __builtin_amdgcn_sched_barrier(0);
      }
      GXL(8,0) GXL(9,1) GXL(10,2) GXL(11,3)
      GRC(8,0,aI)
      GRC(9,1,aI)
      GRC(10,2,aI)
      GRC(11,3,aI)
      #pragma unroll
      for (int r = 0; r < 4; ++r){
        float rg = 1.f/(1.f + __expf(-(aR[r] + bR)));
        float zg = 1.f/(1.f + __expf(-(aZ[r] + bZ)));
        float ng2 = tanhf((aI[r] + bI) + rg*(aN[r] + bN));
        float hv = (1.f - zg)*ng2 + zg*hr[r];
        hr[r] = hv;
        bf16 hv16 = __float2bfloat16(hv);
        __hip_atomic_store((unsigned short*)(hd + pwb + (size_t)(lb*4 + r)*32),
                           *(unsigned short*)&hv16, __ATOMIC_RELAXED, __HIP_MEMORY_SCOPE_AGENT);
      }
    }
    PHSYNC();

    // ---------- phase 2: pre (hid = relu(h@preW^T + preb) + motion) ----------
    {
      const bf16* hdp = hd;
      PRL(0,0) PRL(1,1) PRL(2,2) PRL(3,3) PRL(4,4) PRL(5,5)
      PRL(6,6) PRL(7,7) PRL(8,8) PRL(9,9) PRL(10,10) PRL(11,11)
      f32x4 aP = {0.f,0.f,0.f,0.f};
      PRC(0,0)  PRL(0,12)
      PRC(1,1)  PRL(1,13)
      PRC(2,2)  PRL(2,14)
      PRC(3,3)  PRL(3,15)
      PRC(4,4)  PRL(4,16)
      PRC(5,5)  PRL(5,17)
      PRC(6,6)  PRL(6,18)
      PRC(7,7)  PRL(7,19)
      PRC(8,8)  PRL(8,20)
      PRC(9,9)  PRL(9,21)
      PRC(10,10) PRL(10,22)
      PRC(11,11) PRL(11,23)
      PRC(0,12) PRL(0,24)
      PRC(1,13) PRL(1,25)
      PRC(2,14) PRL(2,26)
      PRC(3,15) PRL(3,27)
      PRC(4,16) PRL(4,28)
      PRC(5,17) PRL(5,29)
      PRC(6,18) PRL(6,30)
      PRC(7,19) PRL(7,31)
      PRC(8,20)
      PRC(9,21)
      PRC(10,22)
      PRC(11,23)
      PRC(0,24)
      PRC(1,25)
      PRC(2,26)
      PRC(3,27)
      PRC(4,28)
      PRC(5,29)
      PRC(6,30)
      PRC(7,31)
      #pragma unroll
      for (int r = 0; r < 4; ++r){
        int row = r0 + lb*4 + r;
        float v = fmaxf(aP[r] + pB, 0.f) + motion[(size_t)row*1024 + ucol];
        bf16 v16 = __float2bfloat16(v);
        __hip_atomic_store((unsigned short*)(hidpk + pwb + (size_t)(lb*4 + r)*32),
                           *(unsigned short*)&v16, __ATOMIC_RELAXED, __HIP_MEMORY_SCOPE_AGENT);
      }
    }
    PHSYNC();

    // ---------- phase 3: W1 (hhpre = hid @ W1^T + b1) ----------
    if (w1act){
      W1L(0,0) W1L(1,1) W1L(2,2) W1L(3,3) W1L(4,4) W1L(5,5)
      f32x4 c0 = {0.f,0.f,0.f,0.f}, c1 = c0;
      W1C(0) W1L(0,6)
      W1C(1) W1L(1,7)
      W1C(2) W1L(2,8)
      W1C(3) W1L(3,9)
      W1C(4) W1L(4,10)
      W1C(5) W1L(5,11)
      W1C(0) W1L(0,12)
      W1C(1) W1L(1,13)
      W1C(2) W1L(2,14)
      W1C(3) W1L(3,15)
      W1C(4) W1L(4,16)
      W1C(5) W1L(5,17)
      W1C(0) W1L(0,18)
      W1C(1) W1L(1,19)
      W1C(2) W1L(2,20)
      W1C(3) W1L(3,21)
      W1C(4) W1L(4,22)
      W1C(5) W1L(5,23)
      W1C(0) W1L(0,24)
      W1C(1) W1L(1,25)
      W1C(2) W1L(2,26)
      W1C(3) W1L(3,27)
      W1C(4) W1L(4,28)
      W1C(5) W1L(5,29)
      W1C(0) W1L(0,30)
      W1C(1) W1L(1,31)
      W1C(2)
      W1C(3)
      W1C(4)
      W1C(5)
      W1C(0)
      W1C(1)
      #pragma unroll
      for (int r = 0; r < 4; ++r){
        int row = r0w + lb*4 + r;
        __hip_atomic_store(&hhpre[(size_t)row*1792 + ug0*16 + la], c0[r] + sb1a,
                           __ATOMIC_RELAXED, __HIP_MEMORY_SCOPE_AGENT);
        __hip_atomic_store(&hhpre[(size_t)row*1792 + ug1*16 + la], c1[r] + sb1b,
                           __ATOMIC_RELAXED, __HIP_MEMORY_SCOPE_AGENT);
      }
    }
    PHSYNC();

    // ---------- phase 4: SPL (preload hhpre -> LDS, chain from LDS) ----------
    for (int i = tid; i < 2*1792; i += 512){
      int bb = i / 1792, col = i - bb*1792;
      hhl[bb][col] = AL(&hhpre[(size_t)(b0s+bb)*1792 + col]);
    }
    __syncthreads();
    for (int L = 0; L < 3; ++L){
      for (int ji = LVO[L]; ji < LVO[L+1]; ++ji){
        int j = LVJ[ji], p = PAR_[j];
        if (tid < 128){
          float acc[2] = { hhl[0][j*128 + th], hhl[1][j*128 + th] };
          if (p >= 0){
            #pragma unroll
            for (int ii = 0; ii < 9; ++ii){
              float w = w1par[(j*9 + ii)*128 + th];
              acc[0] += w * preds_s[0][p*9 + ii];
              acc[1] += w * preds_s[1][p*9 + ii];
            }
          }
          hh_s[th][0] = fmaxf(acc[0], 0.f);
          hh_s[th][1] = fmaxf(acc[1], 0.f);
        }
        __syncthreads();
        if (tid < 36){
          int pp = th >> 1, half = th & 1;
          int bb = pp/9, oi = pp%9;
          const float4* w4 = (const float4*)(sW2 + (size_t)(j*9 + oi)*128 + half*64);
          float s = 0.f;
          #pragma unroll
          for (int q = 0; q < 16; ++q){
            float4 wv = w4[q];
            s += hh_s[half*64 + q*4 + 0][bb]*wv.x + hh_s[half*64 + q*4 + 1][bb]*wv.y
               + hh_s[half*64 + q*4 + 2][bb]*wv.z + hh_s[half*64 + q*4 + 3][bb]*wv.w;
          }
          s += __shfl_xor(s, 1);
          if (half == 0) preds_s[bb][j*9 + oi] = tanhf(s + sb2[j*9 + oi]);
        }
        __syncthreads();
      }
    }
    if (tid < 128){
      for (int i = th; i < 2*D_; i += 128){
        int bb = i / D_, d = i % D_;
        int row = b0s + bb;
        size_t xi = (size_t)row*D_ + d;
        float v = xcur[xi] + preds_s[bb][d];
        xcur[xi] = v;
        bf16 v16 = __float2bfloat16(v);
        __hip_atomic_store((unsigned short*)(xpk + ((size_t)(row>>5)*4 + (d>>5))*1024 + (row&31)*32 + (d&31)),
                           *(unsigned short*)&v16, __ATOMIC_RELAXED, __HIP_MEMORY_SCOPE_AGENT);
        out[((size_t)row*PRED_ + dt)*D_ + d] = v;
      }
    }
    VMWAIT(0);
    __syncthreads();
    if (tid == 0)
      __hip_atomic_store(&progS[bid], (unsigned)(dt+1), __ATOMIC_RELAXED, __HIP_MEMORY_SCOPE_AGENT);
    // no global sync here: next GRU's h-slices depend only on already-synced data;
    // its x-slices wait on progS.
  }
}

// ---------------- pipelined generic GEMM (preamble only) ----------------
__global__ __launch_bounds__(256) void gemm64(
    const bf16* __restrict__ Am, const bf16* __restrict__ Bm, int K,
    const float* __restrict__ bias, const float* __restrict__ addmat,
    float* __restrict__ C, bf16* __restrict__ Cbf, int N, int MODE)
{
  __shared__ bf16 As[3][64*64];
  __shared__ bf16 Bs[3][64*64];
  const int tid = threadIdx.x;
  const int wave = tid >> 6, lane = tid & 63;
  const int m0 = blockIdx.x*64, n0 = blockIdx.y*64;
  const int fr = lane & 31, kh = lane >> 5;
  const int wm = (wave >> 1)*32, wn = (wave & 1)*32;
  const int KT = K >> 6;

  f32x16 acc = {0.f,0.f,0.f,0.f,0.f,0.f,0.f,0.f,0.f,0.f,0.f,0.f,0.f,0.f,0.f,0.f};

  auto STAGE = [&](int buf, int kt){
    #pragma unroll
    for (int q = 0; q < 2; ++q){
      int idx = q*256 + tid;
      int row = idx >> 3, cp = idx & 7, csw = cp ^ (row & 7);
      GLD16(&As[buf][idx*8], Am + (size_t)(m0+row)*K + kt*64 + csw*8);
    }
    #pragma unroll
    for (int q = 0; q < 2; ++q){
      int idx = q*256 + tid;
      int row = idx >> 3, cp = idx & 7, csw = cp ^ (row & 7);
      GLD16(&Bs[buf][idx*8], Bm + (size_t)(n0+row)*K + kt*64 + csw*8);
    }
  };
  auto COMPUTE = [&](int buf){
    const bf16* Ab = &As[buf][0];
    const bf16* Bb = &Bs[buf][0];
    #pragma unroll
    for (int ks = 0; ks < 4; ++ks){
      int ca = ks*2 + kh;
      v8bf av = *(const v8bf*)&Ab[(wm+fr)*64 + ((ca ^ ((wm+fr)&7))*8)];
      v8bf bv = *(const v8bf*)&Bb[(wn+fr)*64 + ((ca ^ ((wn+fr)&7))*8)];
      acc = __builtin_amdgcn_mfma_f32_32x32x16_bf16(av, bv, acc, 0, 0, 0);
    }
  };

  STAGE(0, 0);
  if (KT > 1){ STAGE(1, 1); VMWAIT(4); } else { VMWAIT(0); }
  BARRIER();
  for (int kt = 0; kt < KT; ++kt){
    if (kt + 2 < KT) STAGE((kt+2)%3, kt+2);
    COMPUTE(kt%3);
    if (kt + 2 < KT){ VMWAIT(4); BARRIER(); }
    else if (kt + 1 < KT){ VMWAIT(0); BARRIER(); }
  }

  const int col = n0 + wn + fr;
  float bb = bias ? bias[col] : 0.f;
  #pragma unroll
  for (int r = 0; r < 16; ++r){
    int row = m0 + wm + (r&3) + 8*(r>>2) + 4*kh;
    float v = acc[r] + bb;
    if (MODE == 1) v = fmaxf(v, 0.f) + addmat[(size_t)row*N + col];
    if (C)   C[(size_t)row*N + col] = v;
    if (Cbf) Cbf[(size_t)row*N + col] = __float2bfloat16(v);
  }
}

// ---------------- attention: one block per (b,h) ----------------
__global__ __launch_bounds__(256) void k_attn(const bf16* __restrict__ qkv,
                                              bf16* __restrict__ ctxbf){
  __shared__ char smem[65536];
  bf16* qs = (bf16*)smem;
  bf16* ks = qs + 64*256;
  float* sc = (float*)smem;
  float* cs = (float*)(smem + 32768);
  const int h = blockIdx.x, b = blockIdx.y;
  const int tid = threadIdx.x, wave = tid >> 6, lane = tid & 63;
  const int fr = lane & 31, kh = lane >> 5;
  const int wm = (wave >> 1)*32, wn = (wave & 1)*32;

  #pragma unroll
  for (int i = 0; i < 8; ++i){
    int idx = i*256 + tid;
    int row = idx >> 5, cp = idx & 31, csw = cp ^ (row & 7);
    GLD16(&qs[idx*8], qkv + (size_t)(b*F_ + row)*3072 + h*DH_ + csw*8);
  }
  #pragma unroll
  for (int i = 0; i < 8; ++i){
    int idx = i*256 + tid;
    int row = idx >> 5, cp = idx & 31, csw = cp ^ (row & 7);
    GLD16(&ks[idx*8], qkv + (size_t)(b*F_ + row)*3072 + H_ + h*DH_ + csw*8);
  }
  __syncthreads();

  f32x16 acc = {0.f,0.f,0.f,0.f,0.f,0.f,0.f,0.f,0.f,0.f,0.f,0.f,0.f,0.f,0.f,0.f};
  #pragma unroll
  for (int i = 0; i < 16; ++i){
    int ca = i*2 + kh;
    v8bf av = *(const v8bf*)&qs[((wm+fr)*32 + (ca ^ ((wm+fr)&7)))*8];
    v8bf bv = *(const v8bf*)&ks[((wn+fr)*32 + (ca ^ ((wn+fr)&7)))*8];
    acc = __builtin_amdgcn_mfma_f32_32x32x16_bf16(av, bv, acc, 0, 0, 0);
  }
  __syncthreads();
  #pragma unroll
  for (int r = 0; r < 16; ++r){
    int row = wm + (r&3) + 8*(r>>2) + 4*kh;
    sc[row*65 + (wn+fr)] = acc[r]*0.0625f;
  }
  __syncthreads();
  if (tid < F_){
    float m = -1e30f;
    for (int k2 = 0; k2 < F_; ++k2) m = fmaxf(m, sc[tid*65+k2]);
    float s = 0.f;
    for (int k2 = 0; k2 < F_; ++k2){ float e = __expf(sc[tid*65+k2]-m); sc[tid*65+k2] = e; s += e; }
    float is = 1.f/s;
    for (int k2 = 0; k2 < F_; ++k2) sc[tid*65+k2] *= is;
  }
  __syncthreads();
  if (tid < F_){
    float s = 0.f;
    for (int r = 0; r < F_; ++r) s += sc[r*65+tid];
    cs[tid] = s;
  }
  __syncthreads();
  float a = 0.f;
  for (int k2 = 0; k2 < F_; ++k2){
    float v = __bfloat162float(qkv[(size_t)(b*F_+k2)*3072 + 2*H_ + h*DH_ + tid]);
    a += cs[k2]*v;
  }
  ctxbf[(size_t)b*H_ + h*DH_ + tid] = __float2bfloat16(a * (1.f/61.f));
}

// ---------------- launch ----------------
extern "C" void kernel_launch(void* const* d_in, const int* in_sizes, int n_in,
                              void* d_out, int out_size, void* d_ws, size_t ws_size,
                              hipStream_t stream){
  (void)in_sizes; (void)n_in; (void)out_size; (void)ws_size;
  const float* poses = (const float*)d_in[0];
  const float* gWih  = (const float*)d_in[1];
  const float* gWhh  = (const float*)d_in[2];
  const float* gbih  = (const float*)d_in[3];
  const float* gbhh  = (const float*)d_in[4];
  const float* preW  = (const float*)d_in[5];
  const float* preb  = (const float*)d_in[6];
  const float* fpW   = (const float*)d_in[7];
  const float* fpb   = (const float*)d_in[8];
  const float* inW   = (const float*)d_in[9];
  const float* inb   = (const float*)d_in[10];
  const float* outW  = (const float*)d_in[11];
  const float* outb  = (const float*)d_in[12];
  const float* sW1   = (const float*)d_in[13];
  const float* sb1   = (const float*)d_in[14];
  const float* sW2   = (const float*)d_in[15];
  const float* sb2   = (const float*)d_in[16];
  float* out = (float*)d_out;

  char* w = (char*)d_ws;
  size_t off = 0;
  auto alloc = [&](size_t bytes)->char*{ char* p = w + off; off += (bytes + 255) & ~(size_t)255; return p; };
  float* cosT   = (float*)alloc(7320*4);
  float* bc     = (float*)alloc(3072*4);
  float* motion = (float*)alloc((size_t)256*1024*4);
  float* hA     = (float*)alloc((size_t)256*1024*4);
  float* xcur   = (float*)alloc((size_t)256*126*4);
  float* hhpre  = (float*)alloc((size_t)256*1792*4);
  float* bcat   = (float*)alloc(4096*4);
  float* w1par  = (float*)alloc(14*9*128*4);
  unsigned* prog= (unsigned*)alloc(2048);
  bf16* posespk = (bf16*)alloc((size_t)121*32768*2);
  bf16* Wcat    = (bf16*)alloc((size_t)4096*1152*2);
  bf16* Wpk     = (bf16*)alloc((size_t)64*108*512*2);
  bf16* prepk   = (bf16*)alloc((size_t)64*32*512*2);
  bf16* w1pk    = (bf16*)alloc((size_t)112*32*512*2);
  bf16* outbf   = (bf16*)alloc((size_t)1024*1024*2);
  bf16* inbf    = (bf16*)alloc((size_t)3072*1024*2);
  bf16* fpwt    = (bf16*)alloc((size_t)128*1024*2);
  bf16* ctxbf   = (bf16*)alloc((size_t)256*1024*2);
  bf16* hpkA    = (bf16*)alloc((size_t)256*1024*2);
  bf16* hpkB    = (bf16*)alloc((size_t)256*1024*2);
  bf16* hidpk   = (bf16*)alloc((size_t)256*1024*2);
  bf16* xpk     = (bf16*)alloc((size_t)32768*2);
  bf16* Wcbf    = (bf16*)alloc((size_t)3072*128*2);
  bf16* freqbf  = (bf16*)alloc((size_t)B_*F_*128*2);
  bf16* qkvbf   = (bf16*)alloc((size_t)15680*3072*2);

  hipMemsetAsync(hpkA, 0, (size_t)256*1024*2, stream);
  hipMemsetAsync(prog, 0, 2048, stream);

  k_cos<<<29, 256, 0, stream>>>(cosT);
  k_dft2<<<B_, 256, 0, stream>>>(poses, cosT, freqbf);
  c_poses<<<dim3(SEED_, B_), 128, 0, stream>>>(poses, posespk);
  c_xinit<<<B_, 128, 0, stream>>>(poses, xcur, xpk);
  c_wcat<<<4096, 256, 0, stream>>>(gWih, gWhh, Wcat);
  c_bcat<<<16, 256, 0, stream>>>(gbih, gbhh, bcat);
  c_wpk<<<1728, 256, 0, stream>>>(Wcat, Wpk);
  c_ppk<<<512, 256, 0, stream>>>(preW, prepk);
  c_w1pk<<<896, 256, 0, stream>>>(sW1, w1pk);
  c_w1par<<<63, 256, 0, stream>>>(sW1, w1par);
  c_bf<<<4096, 256, 0, stream>>>(outW, outbf, 1024*1024);
  c_bf<<<12288, 256, 0, stream>>>(inW, inbf, 3072*1024);
  c_fpwt<<<128, 256, 0, stream>>>(fpW, fpwt);
  k_bc<<<768, 256, 0, stream>>>(inW, inb, fpb, bc);

  // Wc = inproj @ fp_W  (3072 x 128, bf16)
  gemm64<<<dim3(48, 2), 256, 0, stream>>>(inbf, fpwt, 1024, nullptr, nullptr, nullptr, Wcbf, 128, 0);
  // qkv = freq @ Wc^T + bc  (15616 x 3072, bf16)
  gemm64<<<dim3(244, 48), 256, 0, stream>>>(freqbf, Wcbf, 128, bc, nullptr, nullptr, qkvbf, 3072, 0);
  k_attn<<<dim3(HEADS_, B_), 256, 0, stream>>>(qkvbf, ctxbf);
  // motion_ctx = ctx_mean @ outproj^T + outb
  gemm64<<<dim3(4, 16), 256, 0, stream>>>(ctxbf, outbf, 1024, outb, nullptr, motion, nullptr, 1024, 0);

  // encoder: cooperative, fence-free coherent h, 120 steps; final h -> hA, packed -> hpkA
  {
    const bf16* a0 = posespk; int a1 = 32768; int a2 = SEED_; int a3 = 1;
    const bf16* a4 = Wpk; const float* a5 = bcat;
    const float* a6 = hA; float* a7 = hA; bf16* a8 = nullptr;
    bf16* a9 = hpkA; bf16* a10 = hpkB; unsigned* a11 = prog;
    void* args[] = { &a0, &a1, &a2, &a3, &a4, &a5, &a6, &a7, &a8, &a9, &a10, &a11 };
    hipLaunchCooperativeKernel(reinterpret_cast<void*>(gru_wave), dim3(128), dim3(512),
                               args, 0, stream);
  }

  // persistent decoder: 24 steps x {GRU, pre, W1, SPL}, flag-synced (3 syncs + hidden SPL flag)
  {
    const bf16* a0 = Wpk; const float* a1 = bcat; const float* a2 = hA;
    bf16* a3 = hpkA; bf16* a4 = hpkB;
    const bf16* a5 = prepk; const float* a6 = preb; const float* a7 = motion;
    bf16* a8 = hidpk; const bf16* a9 = w1pk; const float* a10 = sb1;
    float* a11 = hhpre;
    const float* a12 = w1par; const float* a13 = sW2; const float* a14 = sb2;
    float* a15 = xcur; bf16* a16 = xpk; float* a17 = out;
    unsigned* a18 = prog + 128;
    unsigned* a19 = prog + 256;
    void* args[] = { &a0, &a1, &a2, &a3, &a4, &a5, &a6, &a7, &a8, &a9, &a10,
                     &a11, &a12, &a13, &a14, &a15, &a16, &a17, &a18, &a19 };
    hipLaunchCooperativeKernel(reinterpret_cast<void*>(dec_all), dim3(128), dim3(512),
                               args, 0, stream);
  }
}

// Round 14
// 3204.281 us; speedup vs baseline: 1.3729x; 1.2873x over previous
//
#include <hip/hip_runtime.h>
#include <hip/hip_bf16.h>

typedef __hip_bfloat16 bf16;
typedef __attribute__((ext_vector_type(8))) short v8bf;     // 8 bf16 (4 VGPR)
typedef __attribute__((ext_vector_type(16))) float f32x16;
typedef __attribute__((ext_vector_type(4))) float f32x4;
typedef unsigned long long ull;

#define B_    256
#define SEED_ 120
#define PRED_ 24
#define D_    126
#define H_    1024
#define F_    61
#define HEADS_ 4
#define DH_   256

#define GLD16(lds, g) __builtin_amdgcn_global_load_lds( \
    (const __attribute__((address_space(1))) unsigned int*)(g), \
    (__attribute__((address_space(3))) unsigned int*)(lds), 16, 0, 0)
#define VMWAIT(n) asm volatile("s_waitcnt vmcnt(" #n ")" ::: "memory")
#define BARRIER() do { __builtin_amdgcn_s_barrier(); __builtin_amdgcn_sched_barrier(0); } while(0)
#define AL(P) __hip_atomic_load((P), __ATOMIC_RELAXED, __HIP_MEMORY_SCOPE_AGENT)

// ---------------- small precompute kernels ----------------
__global__ void k_cos(float* cosT){
  int i = blockIdx.x*256 + threadIdx.x;
  if (i < F_*SEED_){
    int f = i / SEED_, t = i % SEED_;
    int ph = (f*t) % SEED_;
    cosT[i] = cosf(6.283185307179586f * (float)ph / (float)SEED_);
  }
}

__global__ __launch_bounds__(256) void k_dft2(const float* __restrict__ poses,
                      const float* __restrict__ cosT, bf16* __restrict__ freqbf){
  __shared__ float pl[SEED_*128];      // 60 KB
  int b = blockIdx.x, tid = threadIdx.x;
  for (int i = tid; i < SEED_*D_; i += 256){
    int t = i / D_, d = i - t*D_;
    pl[t*128 + d] = poses[((size_t)b*(SEED_+PRED_) + t)*D_ + d];
  }
  __syncthreads();
  int d = tid & 127, f0 = tid >> 7;    // f = f0 + 2j
  float acc[31];
  #pragma unroll
  for (int j = 0; j < 31; ++j) acc[j] = 0.f;
  for (int t = 0; t < SEED_; ++t){
    float v = pl[t*128 + d];
    #pragma unroll
    for (int j = 0; j < 31; ++j){
      int f = f0 + j*2;
      if (f < F_) acc[j] += cosT[f*SEED_ + t] * v;
    }
  }
  #pragma unroll
  for (int j = 0; j < 31; ++j){
    int f = f0 + j*2;
    if (f < F_) freqbf[((size_t)b*F_ + f)*128 + d] = __float2bfloat16(d < D_ ? acc[j] : 0.f);
  }
}

// pack poses into per-step 32x32 tiles
__global__ void c_poses(const float* __restrict__ poses, bf16* __restrict__ pk){
  int t = blockIdx.x, b = blockIdx.y, c = threadIdx.x;  // block 128
  float v = (c < D_) ? poses[((size_t)b*(SEED_+PRED_) + t)*D_ + c] : 0.f;
  pk[(size_t)t*32768 + ((b>>5)*4 + (c>>5))*1024 + (b&31)*32 + (c&31)] = __float2bfloat16(v);
}

__global__ void c_xinit(const float* __restrict__ poses, float* __restrict__ x, bf16* __restrict__ xpk){
  int b = blockIdx.x, c = threadIdx.x;  // block 128
  float v = (c < D_) ? poses[((size_t)b*(SEED_+PRED_) + (SEED_-1))*D_ + c] : 0.f;
  if (c < D_) x[b*D_ + c] = v;
  xpk[((b>>5)*4 + (c>>5))*1024 + (b&31)*32 + (c&31)] = __float2bfloat16(v);
}

__global__ void c_bf(const float* __restrict__ s, bf16* __restrict__ d, int n){
  int i = blockIdx.x*256 + threadIdx.x;
  if (i < n) d[i] = __float2bfloat16(s[i]);
}

__global__ void c_fpwt(const float* __restrict__ fpW, bf16* __restrict__ o){
  int dd = blockIdx.x;                       // 0..127
  for (int k = threadIdx.x; k < H_; k += 256)
    o[(size_t)dd*H_ + k] = __float2bfloat16(dd < D_ ? fpW[(size_t)k*D_ + dd] : 0.f);
}

__global__ void c_w1hid(const float* __restrict__ W1, bf16* __restrict__ o){
  int i = blockIdx.x*256 + threadIdx.x;      // 1792*1024
  if (i < 1792*1024){ int r = i >> 10, c = i & 1023; o[i] = __float2bfloat16(W1[(size_t)r*1033 + c]); }
}

// combined GRU weight rows (1152 wide: 128 x-cols | 1024 h-cols)
__global__ void c_wcat(const float* __restrict__ Wih, const float* __restrict__ Whh, bf16* __restrict__ o){
  int r = blockIdx.x;
  int jr; bool hasx, hash;
  if (r < 2048){ jr = r; hasx = true; hash = true; }
  else if (r < 3072){ jr = r; hasx = true; hash = false; }
  else { jr = r - 1024; hasx = false; hash = true; }
  bf16* row = o + (size_t)r*1152;
  for (int c = threadIdx.x; c < 1152; c += 256){
    float v = 0.f;
    if (c < D_) { if (hasx) v = Wih[(size_t)jr*D_ + c]; }
    else if (c >= 128){ if (hash) v = Whh[(size_t)jr*H_ + (c-128)]; }
    row[c] = __float2bfloat16(v);
  }
}

__global__ void c_bcat(const float* __restrict__ bih, const float* __restrict__ bhh, float* __restrict__ o){
  int r = blockIdx.x*256 + threadIdx.x;
  if (r >= 4096) return;
  float v;
  if (r < 2048) v = bih[r] + bhh[r];
  else if (r < 3072) v = bih[r];
  else v = bhh[r - 1024];
  o[r] = v;
}

// pack GRU weights into MFMA B-fragment order
__global__ __launch_bounds__(256) void c_wpk(const bf16* __restrict__ Wcat, bf16* __restrict__ Wpk){
  int chunk = blockIdx.x*4 + (threadIdx.x >> 6);
  int l = threadIdx.x & 63;
  int ks = chunk % 36; int t2 = chunk / 36; int g = t2 % 3; int ub = t2 / 3;
  int unit = ub*16 + (l & 15);
  bf16* dst = Wpk + (size_t)chunk*512 + l*8;
  #pragma unroll
  for (int e = 0; e < 8; ++e){
    int k = ks*32 + (l>>4)*8 + e;
    int row = (g==0) ? unit : (g==1) ? (1024+unit) : (k < 128 ? 2048+unit : 3072+unit);
    dst[e] = Wcat[(size_t)row*1152 + k];
  }
}

// pack SPL parent weights: w1par[(j*9+ii)*128 + t] = sW1[(j*128+t)*1033 + 1024 + ii]
__global__ void c_w1par(const float* __restrict__ sW1, float* __restrict__ w1par){
  int i = blockIdx.x*256 + threadIdx.x;
  if (i < 14*9*128){
    int j = i / (9*128); int rem = i % (9*128); int ii = rem / 128; int th = rem % 128;
    w1par[i] = sW1[((size_t)(j*128 + th))*1033 + 1024 + ii];
  }
}

// bc = inproj @ fp_b + in_b
__global__ __launch_bounds__(256) void k_bc(const float* __restrict__ inW, const float* __restrict__ inb,
                     const float* __restrict__ fpb, float* __restrict__ bc){
  int wave = threadIdx.x >> 6, lane = threadIdx.x & 63;
  int r = blockIdx.x*4 + wave;
  const float4* row = (const float4*)(inW + (size_t)r*H_);
  const float4* fp4 = (const float4*)fpb;
  float s = 0.f;
  #pragma unroll
  for (int i = 0; i < 4; ++i){
    float4 a = row[lane + i*64];
    float4 b = fp4[lane + i*64];
    s += a.x*b.x + a.y*b.y + a.z*b.z + a.w*b.w;
  }
  #pragma unroll
  for (int off = 32; off; off >>= 1) s += __shfl_down(s, off);
  if (lane == 0) bc[r] = s + inb[r];
}

// ---------------- encoder: wave-autonomous GRU (R10, unchanged) ----------------
#define SLCP(QA, QB, KS, GACC) { \
  union { ull u[2]; v8bf v; } cc_; cc_.u[0]=(QA); cc_.u[1]=(QB); \
  v8bf a_ = cc_.v; \
  v8bf w0_ = *(const v8bf*)&Wl[(0*36+(KS))*512 + lane*8]; \
  v8bf w1_ = *(const v8bf*)&Wl[(1*36+(KS))*512 + lane*8]; \
  v8bf w2_ = *(const v8bf*)&Wl[(2*36+(KS))*512 + lane*8]; \
  aR = __builtin_amdgcn_mfma_f32_16x16x32_bf16(a_, w0_, aR, 0,0,0); \
  aZ = __builtin_amdgcn_mfma_f32_16x16x32_bf16(a_, w1_, aZ, 0,0,0); \
  GACC = __builtin_amdgcn_mfma_f32_16x16x32_bf16(a_, w2_, GACC, 0,0,0); }

#define LDHA(DA, DB, C) { \
  const ull* hp_ = (const ull*)(hs + hbase + (size_t)(C)*1024); \
  DA = AL(hp_); DB = AL(hp_+1); }

#define LDXP(DA, DB, TT, C) { \
  const ull* xp_ = (const ull*)(xpk + (size_t)(TT)*xstride + xbase + (size_t)(C)*1024); \
  DA = xp_[0]; DB = xp_[1]; }

__global__ __launch_bounds__(512) void gru_wave(
    const bf16* __restrict__ xpk, int xstride, int nsteps, int coop,
    const bf16* __restrict__ Wpk, const float* __restrict__ bcat,
    const float* __restrict__ hin_plain, float* __restrict__ hout_plain,
    bf16* __restrict__ hbplain,
    bf16* __restrict__ hpk0, bf16* __restrict__ hpk1,
    unsigned* __restrict__ prog)
{
  __shared__ bf16 Wl[3*36*512];       // 108 KB
  const int tid = threadIdx.x, wave = tid >> 6, lane = tid & 63;
  const int ub = blockIdx.x >> 1, bs = blockIdx.x & 1;
  const int u0 = ub*16;

  {
    const bf16* wsrc = Wpk + (size_t)ub*(3*36*512);
    #pragma unroll
    for (int i = 0; i < 14; ++i){
      int c = i*512 + tid;
      if (c < 6912) GLD16(&Wl[c*8], wsrc + (size_t)c*8);
    }
  }
  VMWAIT(0); BARRIER();

  const int la = lane & 15, lb = lane >> 4;
  const int r0 = bs*128 + wave*16;
  const int rb = r0 >> 5, y = wave & 1;
  const int ucol = u0 + la;
  const float bR = bcat[ucol], bZ = bcat[1024+ucol], bI = bcat[2048+ucol], bN = bcat[3072+ucol];
  const size_t hbase = (size_t)rb*32768 + (size_t)y*512 + la*32 + lb*8;
  const size_t xbase = (size_t)rb*4096  + (size_t)y*512 + la*32 + lb*8;
  const size_t pwb = (size_t)rb*32768 + (size_t)(u0>>5)*1024 + (size_t)y*512 + (u0&16) + la;

  float hr[4];
  if (nsteps == 1){
    #pragma unroll
    for (int r = 0; r < 4; ++r) hr[r] = hin_plain[(size_t)(r0 + lb*4 + r)*1024 + ucol];
  } else {
    #pragma unroll
    for (int r = 0; r < 4; ++r) hr[r] = 0.f;
  }

  ull a0,a1,a2,a3,a4,a5,a6,a7,a8,a9,a10,a11;
  ull b0,b1,b2,b3,b4,b5,b6,b7,b8,b9,b10,b11;
  LDXP(a0,b0,0,0); LDXP(a1,b1,0,1); LDXP(a2,b2,0,2); LDXP(a3,b3,0,3);

  for (int t = 0; t < nsteps; ++t){
    if (coop && t > 0){
      if (wave == 0){
        unsigned v = AL(&prog[bs*64 + lane]);
        while (__ballot(v >= (unsigned)t) != ~0ULL){
          __builtin_amdgcn_s_sleep(1);
          v = AL(&prog[bs*64 + lane]);
        }
      }
      __syncthreads();
      __builtin_amdgcn_sched_barrier(0);
    }
    const bf16* hs = (t & 1) ? hpk1 : hpk0;
    LDHA(a4,b4,0) LDHA(a5,b5,1) LDHA(a6,b6,2) LDHA(a7,b7,3)
    LDHA(a8,b8,4) LDHA(a9,b9,5) LDHA(a10,b10,6) LDHA(a11,b11,7)

    f32x4 z4 = {0.f,0.f,0.f,0.f};
    f32x4 aR = z4, aZ = z4, aI = z4, aN = z4;

    SLCP(a0,b0,0,aI)  LDHA(a0,b0,8)
    SLCP(a1,b1,1,aI)  LDHA(a1,b1,9)
    SLCP(a2,b2,2,aI)  LDHA(a2,b2,10)
    SLCP(a3,b3,3,aI)  LDHA(a3,b3,11)
    SLCP(a4,b4,4,aN)  LDHA(a4,b4,12)
    SLCP(a5,b5,5,aN)  LDHA(a5,b5,13)
    SLCP(a6,b6,6,aN)  LDHA(a6,b6,14)
    SLCP(a7,b7,7,aN)  LDHA(a7,b7,15)
    SLCP(a8,b8,8,aN)  LDHA(a8,b8,16)
    SLCP(a9,b9,9,aN)  LDHA(a9,b9,17)
    SLCP(a10,b10,10,aN) LDHA(a10,b10,18)
    SLCP(a11,b11,11,aN) LDHA(a11,b11,19)
    SLCP(a0,b0,12,aN) LDHA(a0,b0,20)
    SLCP(a1,b1,13,aN) LDHA(a1,b1,21)
    SLCP(a2,b2,14,aN) LDHA(a2,b2,22)
    SLCP(a3,b3,15,aN) LDHA(a3,b3,23)
    SLCP(a4,b4,16,aN) LDHA(a4,b4,24)
    SLCP(a5,b5,17,aN) LDHA(a5,b5,25)
    SLCP(a6,b6,18,aN) LDHA(a6,b6,26)
    SLCP(a7,b7,19,aN) LDHA(a7,b7,27)
    SLCP(a8,b8,20,aN) LDHA(a8,b8,28)
    SLCP(a9,b9,21,aN) LDHA(a9,b9,29)
    SLCP(a10,b10,22,aN) LDHA(a10,b10,30)
    SLCP(a11,b11,23,aN) LDHA(a11,b11,31)
    SLCP(a0,b0,24,aN) LDXP(a0,b0,t+1,0)
    SLCP(a1,b1,25,aN) LDXP(a1,b1,t+1,1)
    SLCP(a2,b2,26,aN) LDXP(a2,b2,t+1,2)
    SLCP(a3,b3,27,aN) LDXP(a3,b3,t+1,3)
    SLCP(a4,b4,28,aN)
    SLCP(a5,b5,29,aN)
    SLCP(a6,b6,30,aN)
    SLCP(a7,b7,31,aN)
    SLCP(a8,b8,32,aN)
    SLCP(a9,b9,33,aN)
    SLCP(a10,b10,34,aN)
    SLCP(a11,b11,35,aN)

    bf16* hd = (t & 1) ? hpk0 : hpk1;
    const bool last = (t == nsteps-1);
    #pragma unroll
    for (int r = 0; r < 4; ++r){
      float rg = 1.f/(1.f + __expf(-(aR[r] + bR)));
      float zg = 1.f/(1.f + __expf(-(aZ[r] + bZ)));
      float ng = tanhf((aI[r] + bI) + rg*(aN[r] + bN));
      float hv = (1.f - zg)*ng + zg*hr[r];
      hr[r] = hv;
      bf16 hv16 = __float2bfloat16(hv);
      unsigned short hbits = *(unsigned short*)&hv16;
      __hip_atomic_store((unsigned short*)(hd + pwb + (size_t)(lb*4 + r)*32), hbits,
                         __ATOMIC_RELAXED, __HIP_MEMORY_SCOPE_AGENT);
      if (last){
        hout_plain[(size_t)(r0 + lb*4 + r)*1024 + ucol] = hv;
        if (hbplain) hbplain[(size_t)(r0 + lb*4 + r)*1024 + ucol] = __float2bfloat16(hv);
      }
    }
    if (coop && t + 1 < nsteps){
      VMWAIT(0);
      __syncthreads();
      if (tid == 0)
        __hip_atomic_store(&prog[bs*64 + ub], (unsigned)(t+1), __ATOMIC_RELAXED, __HIP_MEMORY_SCOPE_AGENT);
    }
  }
}

// ---------------- decoder GRU with fused SPL(t-1) prologue ----------------
__constant__ int LVJ[14] = {0,1,6,8,9, 2,3,7,10,11, 4,5,12,13};
__constant__ int LVO[4]  = {0,5,10,14};
__constant__ int PAR_[14] = {-1,-1,0,1,2,3,-1,6,-1,-1,8,9,10,11};

#define DGRL(S,C) { const ull* p_=(const ull*)(hspk + hbase + (size_t)(C)*1024); qa##S=AL(p_); qb##S=AL(p_+1); }
#define DGXL(S,C) { const ull* p_=(const ull*)(xpk + xbase + (size_t)(C)*1024); qa##S=AL(p_); qb##S=AL(p_+1); }
#define DGRC(S,KS,GACC) { union{ull u[2];v8bf v;}c_; c_.u[0]=qa##S;c_.u[1]=qb##S; v8bf a_=c_.v; \
  v8bf w0_=*(const v8bf*)&Wl[(KS)*512+lane*8]; \
  v8bf w1_=*(const v8bf*)&Wl[18432+(KS)*512+lane*8]; \
  v8bf w2_=*(const v8bf*)&Wl[36864+(KS)*512+lane*8]; \
  aR=__builtin_amdgcn_mfma_f32_16x16x32_bf16(a_,w0_,aR,0,0,0); \
  aZ=__builtin_amdgcn_mfma_f32_16x16x32_bf16(a_,w1_,aZ,0,0,0); \
  GACC=__builtin_amdgcn_mfma_f32_16x16x32_bf16(a_,w2_,GACC,0,0,0); }

__global__ __launch_bounds__(512) void gru_spl(
    const bf16* __restrict__ xpk, const bf16* __restrict__ Wpk,
    const float* __restrict__ bcat,
    const float* __restrict__ hin_plain, float* __restrict__ hout_plain,
    bf16* __restrict__ hbplain,
    const bf16* __restrict__ hspk, bf16* __restrict__ hdpk,
    const float* __restrict__ hhpre, const float* __restrict__ w1par,
    const float* __restrict__ sW2, const float* __restrict__ sb2,
    float* __restrict__ xcur, bf16* __restrict__ xpkw, float* __restrict__ out,
    int dt, unsigned* __restrict__ progS)
{
  __shared__ bf16 Wl[3*36*512];     // 108 KB
  __shared__ float hhl[2][1792];    // 14 KB
  __shared__ float preds_s[2][128];
  __shared__ float hh_s[128][2];
  const int tid = threadIdx.x, wave = tid >> 6, lane = tid & 63;
  const int bid = blockIdx.x;
  const int ub = bid >> 1, bs = bid & 1, u0 = ub*16;

  {  // weights -> LDS (async, overlaps SPL)
    const bf16* wsrc = Wpk + (size_t)ub*(3*36*512);
    #pragma unroll
    for (int i = 0; i < 14; ++i){ int c = i*512 + tid; if (c < 6912) GLD16(&Wl[c*8], wsrc + (size_t)c*8); }
  }

  // ---- SPL of previous step (regular loads; coherent via launch boundary) ----
  const int b0s = bid*2, th = tid;
  if (dt > 0){
    for (int i = tid; i < 2*1792; i += 512){
      int bb = i / 1792, col = i - bb*1792;
      hhl[bb][col] = hhpre[(size_t)(b0s+bb)*1792 + col];
    }
    __syncthreads();
    for (int L = 0; L < 3; ++L){
      for (int ji = LVO[L]; ji < LVO[L+1]; ++ji){
        int j = LVJ[ji], p = PAR_[j];
        if (tid < 128){
          float a0s = hhl[0][j*128 + th], a1s = hhl[1][j*128 + th];
          if (p >= 0){
            #pragma unroll
            for (int ii = 0; ii < 9; ++ii){
              float w = w1par[(j*9 + ii)*128 + th];
              a0s += w * preds_s[0][p*9 + ii];
              a1s += w * preds_s[1][p*9 + ii];
            }
          }
          hh_s[th][0] = fmaxf(a0s, 0.f);
          hh_s[th][1] = fmaxf(a1s, 0.f);
        }
        __syncthreads();
        if (tid < 36){
          int pp = th >> 1, half = th & 1;
          int bb = pp/9, oi = pp%9;
          const float4* w4 = (const float4*)(sW2 + (size_t)(j*9 + oi)*128 + half*64);
          float s = 0.f;
          #pragma unroll
          for (int q = 0; q < 16; ++q){
            float4 wv = w4[q];
            s += hh_s[half*64 + q*4 + 0][bb]*wv.x + hh_s[half*64 + q*4 + 1][bb]*wv.y
               + hh_s[half*64 + q*4 + 2][bb]*wv.z + hh_s[half*64 + q*4 + 3][bb]*wv.w;
          }
          s += __shfl_xor(s, 1);
          if (half == 0) preds_s[bb][j*9 + oi] = tanhf(s + sb2[j*9 + oi]);
        }
        __syncthreads();
      }
    }
    if (tid < 128){
      for (int i = th; i < 2*D_; i += 128){
        int bb = i / D_, d = i % D_;
        int row = b0s + bb;
        size_t xi = (size_t)row*D_ + d;
        float v = xcur[xi] + preds_s[bb][d];
        xcur[xi] = v;
        bf16 v16 = __float2bfloat16(v);
        __hip_atomic_store((unsigned short*)(xpkw + ((size_t)(row>>5)*4 + (d>>5))*1024 + (row&31)*32 + (d&31)),
                           *(unsigned short*)&v16, __ATOMIC_RELAXED, __HIP_MEMORY_SCOPE_AGENT);
        out[((size_t)row*PRED_ + (dt-1))*D_ + d] = v;
      }
    }
    VMWAIT(0);              // xpk atomic stores (and weights) drained
    __syncthreads();
    if (tid == 0)
      __hip_atomic_store(&progS[bid], (unsigned)dt, __ATOMIC_RELAXED, __HIP_MEMORY_SCOPE_AGENT);
  }

  VMWAIT(0); BARRIER();     // weights resident

  const int la = lane & 15, lb = lane >> 4;
  const int r0 = bs*128 + wave*16;
  const int rb = r0 >> 5, y = wave & 1;
  const int ucol = u0 + la;
  const float bR = bcat[ucol], bZ = bcat[1024+ucol], bI = bcat[2048+ucol], bN = bcat[3072+ucol];
  const size_t hbase = (size_t)rb*32768 + (size_t)y*512 + la*32 + lb*8;
  const size_t xbase = (size_t)rb*4096  + (size_t)y*512 + la*32 + lb*8;
  const size_t pwb = (size_t)rb*32768 + (size_t)(u0>>5)*1024 + (size_t)y*512 + (u0&16) + la;

  float hr[4];
  #pragma unroll
  for (int r = 0; r < 4; ++r) hr[r] = hin_plain[(size_t)(r0 + lb*4 + r)*1024 + ucol];

  ull qa0,qa1,qa2,qa3,qa4,qa5,qa6,qa7,qa8,qa9,qa10,qa11;
  ull qb0,qb1,qb2,qb3,qb4,qb5,qb6,qb7,qb8,qb9,qb10,qb11;

  // h-slices first (depend only on h^t)
  DGRL(0,0) DGRL(1,1) DGRL(2,2) DGRL(3,3) DGRL(4,4) DGRL(5,5)
  DGRL(6,6) DGRL(7,7) DGRL(8,8) DGRL(9,9) DGRL(10,10) DGRL(11,11)
  f32x4 z4 = {0.f,0.f,0.f,0.f};
  f32x4 aR = z4, aZ = z4, aI = z4, aN = z4;
  DGRC(0,4,aN)  DGRL(0,12)
  DGRC(1,5,aN)  DGRL(1,13)
  DGRC(2,6,aN)  DGRL(2,14)
  DGRC(3,7,aN)  DGRL(3,15)
  DGRC(4,8,aN)  DGRL(4,16)
  DGRC(5,9,aN)  DGRL(5,17)
  DGRC(6,10,aN) DGRL(6,18)
  DGRC(7,11,aN) DGRL(7,19)
  DGRC(8,12,aN) DGRL(8,20)
  DGRC(9,13,aN) DGRL(9,21)
  DGRC(10,14,aN) DGRL(10,22)
  DGRC(11,15,aN) DGRL(11,23)
  DGRC(0,16,aN) DGRL(0,24)
  DGRC(1,17,aN) DGRL(1,25)
  DGRC(2,18,aN) DGRL(2,26)
  DGRC(3,19,aN) DGRL(3,27)
  DGRC(4,20,aN) DGRL(4,28)
  DGRC(5,21,aN) DGRL(5,29)
  DGRC(6,22,aN) DGRL(6,30)
  DGRC(7,23,aN) DGRL(7,31)
  DGRC(8,24,aN)
  DGRC(9,25,aN)
  DGRC(10,26,aN)
  DGRC(11,27,aN)
  DGRC(0,28,aN)
  DGRC(1,29,aN)
  DGRC(2,30,aN)
  DGRC(3,31,aN)
  DGRC(4,32,aN)
  DGRC(5,33,aN)
  DGRC(6,34,aN)
  DGRC(7,35,aN)
  // wait for all blocks' SPL (x^t ready); usually already satisfied
  if (dt > 0){
    if (wave == 0){
      unsigned v1 = AL(&progS[lane]), v2 = AL(&progS[64 + lane]);
      while (__ballot((v1 >= (unsigned)dt) && (v2 >= (unsigned)dt)) != ~0ULL){
        __builtin_amdgcn_s_sleep(2);
        v1 = AL(&progS[lane]); v2 = AL(&progS[64 + lane]);
      }
    }
    __syncthreads();
    __builtin_amdgcn_sched_barrier(0);
  }
  DGXL(8,0) DGXL(9,1) DGXL(10,2) DGXL(11,3)
  DGRC(8,0,aI)
  DGRC(9,1,aI)
  DGRC(10,2,aI)
  DGRC(11,3,aI)
  #pragma unroll
  for (int r = 0; r < 4; ++r){
    float rg = 1.f/(1.f + __expf(-(aR[r] + bR)));
    float zg = 1.f/(1.f + __expf(-(aZ[r] + bZ)));
    float ng = tanhf((aI[r] + bI) + rg*(aN[r] + bN));
    float hv = (1.f - zg)*ng + zg*hr[r];
    bf16 hv16 = __float2bfloat16(hv);
    __hip_atomic_store((unsigned short*)(hdpk + pwb + (size_t)(lb*4 + r)*32),
                       *(unsigned short*)&hv16, __ATOMIC_RELAXED, __HIP_MEMORY_SCOPE_AGENT);
    hout_plain[(size_t)(r0 + lb*4 + r)*1024 + ucol] = hv;
    hbplain[(size_t)(r0 + lb*4 + r)*1024 + ucol] = hv16;
  }
}

// ---------------- pipelined generic GEMM: C[M,N] = A @ B^T (+bias/epilogue) ----------------
__global__ __launch_bounds__(256) void gemm64(
    const bf16* __restrict__ Am, const bf16* __restrict__ Bm, int K,
    const float* __restrict__ bias, const float* __restrict__ addmat,
    float* __restrict__ C, bf16* __restrict__ Cbf, int N, int MODE)
{
  __shared__ bf16 As[3][64*64];
  __shared__ bf16 Bs[3][64*64];
  const int tid = threadIdx.x;
  const int wave = tid >> 6, lane = tid & 63;
  const int m0 = blockIdx.x*64, n0 = blockIdx.y*64;
  const int fr = lane & 31, kh = lane >> 5;
  const int wm = (wave >> 1)*32, wn = (wave & 1)*32;
  const int KT = K >> 6;

  f32x16 acc = {0.f,0.f,0.f,0.f,0.f,0.f,0.f,0.f,0.f,0.f,0.f,0.f,0.f,0.f,0.f,0.f};

  auto STAGE = [&](int buf, int kt){
    #pragma unroll
    for (int q = 0; q < 2; ++q){
      int idx = q*256 + tid;
      int row = idx >> 3, cp = idx & 7, csw = cp ^ (row & 7);
      GLD16(&As[buf][idx*8], Am + (size_t)(m0+row)*K + kt*64 + csw*8);
    }
    #pragma unroll
    for (int q = 0; q < 2; ++q){
      int idx = q*256 + tid;
      int row = idx >> 3, cp = idx & 7, csw = cp ^ (row & 7);
      GLD16(&Bs[buf][idx*8], Bm + (size_t)(n0+row)*K + kt*64 + csw*8);
    }
  };
  auto COMPUTE = [&](int buf){
    const bf16* Ab = &As[buf][0];
    const bf16* Bb = &Bs[buf][0];
    #pragma unroll
    for (int ks = 0; ks < 4; ++ks){
      int ca = ks*2 + kh;
      v8bf av = *(const v8bf*)&Ab[(wm+fr)*64 + ((ca ^ ((wm+fr)&7))*8)];
      v8bf bv = *(const v8bf*)&Bb[(wn+fr)*64 + ((ca ^ ((wn+fr)&7))*8)];
      acc = __builtin_amdgcn_mfma_f32_32x32x16_bf16(av, bv, acc, 0, 0, 0);
    }
  };

  STAGE(0, 0);
  if (KT > 1){ STAGE(1, 1); VMWAIT(4); } else { VMWAIT(0); }
  BARRIER();
  for (int kt = 0; kt < KT; ++kt){
    if (kt + 2 < KT) STAGE((kt+2)%3, kt+2);
    COMPUTE(kt%3);
    if (kt + 2 < KT){ VMWAIT(4); BARRIER(); }
    else if (kt + 1 < KT){ VMWAIT(0); BARRIER(); }
  }

  const int col = n0 + wn + fr;
  float bb = bias ? bias[col] : 0.f;
  #pragma unroll
  for (int r = 0; r < 16; ++r){
    int row = m0 + wm + (r&3) + 8*(r>>2) + 4*kh;
    float v = acc[r] + bb;
    if (MODE == 1) v = fmaxf(v, 0.f) + addmat[(size_t)row*N + col];
    if (C)   C[(size_t)row*N + col] = v;
    if (Cbf) Cbf[(size_t)row*N + col] = __float2bfloat16(v);
  }
}

// ---------------- attention: one block per (b,h) ----------------
__global__ __launch_bounds__(256) void k_attn(const bf16* __restrict__ qkv,
                                              bf16* __restrict__ ctxbf){
  __shared__ char smem[65536];
  bf16* qs = (bf16*)smem;
  bf16* ks = qs + 64*256;
  float* sc = (float*)smem;
  float* cs = (float*)(smem + 32768);
  const int h = blockIdx.x, b = blockIdx.y;
  const int tid = threadIdx.x, wave = tid >> 6, lane = tid & 63;
  const int fr = lane & 31, kh = lane >> 5;
  const int wm = (wave >> 1)*32, wn = (wave & 1)*32;

  #pragma unroll
  for (int i = 0; i < 8; ++i){
    int idx = i*256 + tid;
    int row = idx >> 5, cp = idx & 31, csw = cp ^ (row & 7);
    GLD16(&qs[idx*8], qkv + (size_t)(b*F_ + row)*3072 + h*DH_ + csw*8);
  }
  #pragma unroll
  for (int i = 0; i < 8; ++i){
    int idx = i*256 + tid;
    int row = idx >> 5, cp = idx & 31, csw = cp ^ (row & 7);
    GLD16(&ks[idx*8], qkv + (size_t)(b*F_ + row)*3072 + H_ + h*DH_ + csw*8);
  }
  __syncthreads();

  f32x16 acc = {0.f,0.f,0.f,0.f,0.f,0.f,0.f,0.f,0.f,0.f,0.f,0.f,0.f,0.f,0.f,0.f};
  #pragma unroll
  for (int i = 0; i < 16; ++i){
    int ca = i*2 + kh;
    v8bf av = *(const v8bf*)&qs[((wm+fr)*32 + (ca ^ ((wm+fr)&7)))*8];
    v8bf bv = *(const v8bf*)&ks[((wn+fr)*32 + (ca ^ ((wn+fr)&7)))*8];
    acc = __builtin_amdgcn_mfma_f32_32x32x16_bf16(av, bv, acc, 0, 0, 0);
  }
  __syncthreads();
  #pragma unroll
  for (int r = 0; r < 16; ++r){
    int row = wm + (r&3) + 8*(r>>2) + 4*kh;
    sc[row*65 + (wn+fr)] = acc[r]*0.0625f;
  }
  __syncthreads();
  if (tid < F_){
    float m = -1e30f;
    for (int k2 = 0; k2 < F_; ++k2) m = fmaxf(m, sc[tid*65+k2]);
    float s = 0.f;
    for (int k2 = 0; k2 < F_; ++k2){ float e = __expf(sc[tid*65+k2]-m); sc[tid*65+k2] = e; s += e; }
    float is = 1.f/s;
    for (int k2 = 0; k2 < F_; ++k2) sc[tid*65+k2] *= is;
  }
  __syncthreads();
  if (tid < F_){
    float s = 0.f;
    for (int r = 0; r < F_; ++r) s += sc[r*65+tid];
    cs[tid] = s;
  }
  __syncthreads();
  float a = 0.f;
  for (int k2 = 0; k2 < F_; ++k2){
    float v = __bfloat162float(qkv[(size_t)(b*F_+k2)*3072 + 2*H_ + h*DH_ + tid]);
    a += cs[k2]*v;
  }
  ctxbf[(size_t)b*H_ + h*DH_ + tid] = __float2bfloat16(a * (1.f/61.f));
}

// ---------------- SPL final step (R10 version, sW1 strided) ----------------
__global__ __launch_bounds__(128) void spl_all(const float* __restrict__ hh_pre, const float* __restrict__ W1,
                        const float* __restrict__ W2, const float* __restrict__ b2,
                        float* __restrict__ x, bf16* __restrict__ xpk,
                        float* __restrict__ out, int tstep){
  __shared__ float preds_s[4][128];
  __shared__ float hh_s[128][5];
  int b0 = blockIdx.x*4, t = threadIdx.x;   // grid 64, block 128
  for (int L = 0; L < 3; ++L){
    for (int ji = LVO[L]; ji < LVO[L+1]; ++ji){
      int j = LVJ[ji], p = PAR_[j];
      float acc[4];
      #pragma unroll
      for (int bb = 0; bb < 4; ++bb) acc[bb] = hh_pre[(size_t)(b0+bb)*1792 + j*128 + t];
      if (p >= 0){
        #pragma unroll
        for (int ii = 0; ii < 9; ++ii){
          float w = W1[(size_t)(j*128 + t)*1033 + 1024 + ii];
          #pragma unroll
          for (int bb = 0; bb < 4; ++bb) acc[bb] += w * preds_s[bb][p*9 + ii];
        }
      }
      #pragma unroll
      for (int bb = 0; bb < 4; ++bb) hh_s[t][bb] = fmaxf(acc[bb], 0.f);
      __syncthreads();
      if (t < 72){
        int pp = t >> 1, half = t & 1;
        int bb = pp/9, oi = pp%9;
        const float* w2r = W2 + (size_t)(j*9 + oi)*128 + half*64;
        float s = 0.f;
        #pragma unroll
        for (int tt = 0; tt < 64; ++tt) s += hh_s[half*64 + tt][bb] * w2r[tt];
        s += __shfl_xor(s, 1);
        if (half == 0) preds_s[bb][j*9 + oi] = tanhf(s + b2[j*9 + oi]);
      }
      __syncthreads();
    }
  }
  for (int i = t; i < 4*D_; i += 128){
    int bb = i / D_, d = i % D_;
    int row = b0 + bb;
    size_t xi = (size_t)row*D_ + d;
    float v = x[xi] + preds_s[bb][d];
    x[xi] = v;
    xpk[((row>>5)*4 + (d>>5))*1024 + (row&31)*32 + (d&31)] = __float2bfloat16(v);
    out[((size_t)row*PRED_ + tstep)*D_ + d] = v;
  }
}

// ---------------- launch ----------------
extern "C" void kernel_launch(void* const* d_in, const int* in_sizes, int n_in,
                              void* d_out, int out_size, void* d_ws, size_t ws_size,
                              hipStream_t stream){
  (void)in_sizes; (void)n_in; (void)out_size; (void)ws_size;
  const float* poses = (const float*)d_in[0];
  const float* gWih  = (const float*)d_in[1];
  const float* gWhh  = (const float*)d_in[2];
  const float* gbih  = (const float*)d_in[3];
  const float* gbhh  = (const float*)d_in[4];
  const float* preW  = (const float*)d_in[5];
  const float* preb  = (const float*)d_in[6];
  const float* fpW   = (const float*)d_in[7];
  const float* fpb   = (const float*)d_in[8];
  const float* inW   = (const float*)d_in[9];
  const float* inb   = (const float*)d_in[10];
  const float* outW  = (const float*)d_in[11];
  const float* outb  = (const float*)d_in[12];
  const float* sW1   = (const float*)d_in[13];
  const float* sb1   = (const float*)d_in[14];
  const float* sW2   = (const float*)d_in[15];
  const float* sb2   = (const float*)d_in[16];
  float* out = (float*)d_out;

  char* w = (char*)d_ws;
  size_t off = 0;
  auto alloc = [&](size_t bytes)->char*{ char* p = w + off; off += (bytes + 255) & ~(size_t)255; return p; };
  float* cosT   = (float*)alloc(7320*4);
  float* bc     = (float*)alloc(3072*4);
  float* motion = (float*)alloc((size_t)256*1024*4);
  float* hA     = (float*)alloc((size_t)256*1024*4);
  float* hB     = (float*)alloc((size_t)256*1024*4);
  float* xcur   = (float*)alloc((size_t)256*126*4);
  float* hhpre  = (float*)alloc((size_t)256*1792*4);
  float* bcat   = (float*)alloc(4096*4);
  float* w1par  = (float*)alloc(14*9*128*4);
  unsigned* prog= (unsigned*)alloc(2048);
  bf16* posespk = (bf16*)alloc((size_t)121*32768*2);
  bf16* Wcat    = (bf16*)alloc((size_t)4096*1152*2);
  bf16* Wpk     = (bf16*)alloc((size_t)64*108*512*2);
  bf16* prebf   = (bf16*)alloc((size_t)1024*1024*2);
  bf16* outbf   = (bf16*)alloc((size_t)1024*1024*2);
  bf16* inbf    = (bf16*)alloc((size_t)3072*1024*2);
  bf16* fpwt    = (bf16*)alloc((size_t)128*1024*2);
  bf16* w1h     = (bf16*)alloc((size_t)1792*1024*2);
  bf16* ctxbf   = (bf16*)alloc((size_t)256*1024*2);
  bf16* hpkA    = (bf16*)alloc((size_t)256*1024*2);
  bf16* hpkB    = (bf16*)alloc((size_t)256*1024*2);
  bf16* hbplain = (bf16*)alloc((size_t)256*1024*2);
  bf16* xpk     = (bf16*)alloc((size_t)32768*2);
  bf16* hidbf   = (bf16*)alloc((size_t)256*1024*2);
  bf16* Wcbf    = (bf16*)alloc((size_t)3072*128*2);
  bf16* freqbf  = (bf16*)alloc((size_t)B_*F_*128*2);
  bf16* qkvbf   = (bf16*)alloc((size_t)15680*3072*2);

  hipMemsetAsync(hpkA, 0, (size_t)256*1024*2, stream);
  hipMemsetAsync(prog, 0, 2048, stream);

  k_cos<<<29, 256, 0, stream>>>(cosT);
  k_dft2<<<B_, 256, 0, stream>>>(poses, cosT, freqbf);
  c_poses<<<dim3(SEED_, B_), 128, 0, stream>>>(poses, posespk);
  c_xinit<<<B_, 128, 0, stream>>>(poses, xcur, xpk);
  c_wcat<<<4096, 256, 0, stream>>>(gWih, gWhh, Wcat);
  c_bcat<<<16, 256, 0, stream>>>(gbih, gbhh, bcat);
  c_wpk<<<1728, 256, 0, stream>>>(Wcat, Wpk);
  c_bf<<<4096, 256, 0, stream>>>(preW, prebf, 1024*1024);
  c_bf<<<4096, 256, 0, stream>>>(outW, outbf, 1024*1024);
  c_bf<<<12288, 256, 0, stream>>>(inW, inbf, 3072*1024);
  c_fpwt<<<128, 256, 0, stream>>>(fpW, fpwt);
  c_w1hid<<<7168, 256, 0, stream>>>(sW1, w1h);
  c_w1par<<<63, 256, 0, stream>>>(sW1, w1par);
  k_bc<<<768, 256, 0, stream>>>(inW, inb, fpb, bc);

  // Wc = inproj @ fp_W  (3072 x 128, bf16)
  gemm64<<<dim3(48, 2), 256, 0, stream>>>(inbf, fpwt, 1024, nullptr, nullptr, nullptr, Wcbf, 128, 0);
  // qkv = freq @ Wc^T + bc  (15616 x 3072, bf16)
  gemm64<<<dim3(244, 48), 256, 0, stream>>>(freqbf, Wcbf, 128, bc, nullptr, nullptr, qkvbf, 3072, 0);
  k_attn<<<dim3(HEADS_, B_), 256, 0, stream>>>(qkvbf, ctxbf);
  // motion_ctx = ctx_mean @ outproj^T + outb
  gemm64<<<dim3(4, 16), 256, 0, stream>>>(ctxbf, outbf, 1024, outb, nullptr, motion, nullptr, 1024, 0);

  // encoder: cooperative, fence-free coherent h, 120 steps; final h -> hA, packed -> hpkA
  {
    const bf16* a0 = posespk; int a1 = 32768; int a2 = SEED_; int a3 = 1;
    const bf16* a4 = Wpk; const float* a5 = bcat;
    const float* a6 = hA; float* a7 = hA; bf16* a8 = nullptr;
    bf16* a9 = hpkA; bf16* a10 = hpkB; unsigned* a11 = prog;
    void* args[] = { &a0, &a1, &a2, &a3, &a4, &a5, &a6, &a7, &a8, &a9, &a10, &a11 };
    hipLaunchCooperativeKernel(reinterpret_cast<void*>(gru_wave), dim3(128), dim3(512),
                               args, 0, stream);
  }

  float* hc = hA;  float* hn = hB;
  bf16* hpc = hpkA; bf16* hpn = hpkB;
  unsigned* progS = prog + 128;

  // decoder: 24 steps (gru_spl fuses SPL(t-1); final SPL separate)
  for (int t = 0; t < PRED_; ++t){
    gru_spl<<<128, 512, 0, stream>>>(xpk, Wpk, bcat, hc, hn, hbplain, hpc, hpn,
                                     hhpre, w1par, sW2, sb2, xcur, xpk, out, t, progS);
    { float* tf = hc; hc = hn; hn = tf; bf16* tb = hpc; hpc = hpn; hpn = tb; }
    gemm64<<<dim3(4, 16), 256, 0, stream>>>(hbplain, prebf, 1024, preb, motion, nullptr, hidbf, 1024, 1);
    gemm64<<<dim3(4, 28), 256, 0, stream>>>(hidbf, w1h, 1024, sb1, nullptr, hhpre, nullptr, 1792, 0);
  }
  spl_all<<<64, 128, 0, stream>>>(hhpre, sW1, sW2, sb2, xcur, xpk, out, PRED_-1);
}

// Round 16
// 3103.266 us; speedup vs baseline: 1.4176x; 1.0326x over previous
//
#include <hip/hip_runtime.h>
#include <hip/hip_bf16.h>

typedef __hip_bfloat16 bf16;
typedef __attribute__((ext_vector_type(8))) short v8bf;     // 8 bf16 (4 VGPR)
typedef __attribute__((ext_vector_type(16))) float f32x16;
typedef __attribute__((ext_vector_type(4))) float f32x4;
typedef unsigned long long ull;

#define B_    256
#define SEED_ 120
#define PRED_ 24
#define D_    126
#define H_    1024
#define F_    61
#define HEADS_ 4
#define DH_   256

#define GLD16(lds, g) __builtin_amdgcn_global_load_lds( \
    (const __attribute__((address_space(1))) unsigned int*)(g), \
    (__attribute__((address_space(3))) unsigned int*)(lds), 16, 0, 0)
#define VMWAIT(n) asm volatile("s_waitcnt vmcnt(" #n ")" ::: "memory")
#define BARRIER() do { __builtin_amdgcn_s_barrier(); __builtin_amdgcn_sched_barrier(0); } while(0)
#define AL(P) __hip_atomic_load((P), __ATOMIC_RELAXED, __HIP_MEMORY_SCOPE_AGENT)

// ---------------- small precompute kernels ----------------
__global__ void k_cos(float* cosT){
  int i = blockIdx.x*256 + threadIdx.x;
  if (i < F_*SEED_){
    int f = i / SEED_, t = i % SEED_;
    int ph = (f*t) % SEED_;
    cosT[i] = cosf(6.283185307179586f * (float)ph / (float)SEED_);
  }
}

__global__ __launch_bounds__(256) void k_dft2(const float* __restrict__ poses,
                      const float* __restrict__ cosT, bf16* __restrict__ freqbf){
  __shared__ float pl[SEED_*128];      // 60 KB
  int b = blockIdx.x, tid = threadIdx.x;
  for (int i = tid; i < SEED_*D_; i += 256){
    int t = i / D_, d = i - t*D_;
    pl[t*128 + d] = poses[((size_t)b*(SEED_+PRED_) + t)*D_ + d];
  }
  __syncthreads();
  int d = tid & 127, f0 = tid >> 7;    // f = f0 + 2j
  float acc[31];
  #pragma unroll
  for (int j = 0; j < 31; ++j) acc[j] = 0.f;
  for (int t = 0; t < SEED_; ++t){
    float v = pl[t*128 + d];
    #pragma unroll
    for (int j = 0; j < 31; ++j){
      int f = f0 + j*2;
      if (f < F_) acc[j] += cosT[f*SEED_ + t] * v;
    }
  }
  #pragma unroll
  for (int j = 0; j < 31; ++j){
    int f = f0 + j*2;
    if (f < F_) freqbf[((size_t)b*F_ + f)*128 + d] = __float2bfloat16(d < D_ ? acc[j] : 0.f);
  }
}

// pack poses into per-step 32x32 tiles
__global__ void c_poses(const float* __restrict__ poses, bf16* __restrict__ pk){
  int t = blockIdx.x, b = blockIdx.y, c = threadIdx.x;  // block 128
  float v = (c < D_) ? poses[((size_t)b*(SEED_+PRED_) + t)*D_ + c] : 0.f;
  pk[(size_t)t*32768 + ((b>>5)*4 + (c>>5))*1024 + (b&31)*32 + (c&31)] = __float2bfloat16(v);
}

__global__ void c_xinit(const float* __restrict__ poses, float* __restrict__ x, bf16* __restrict__ xpk){
  int b = blockIdx.x, c = threadIdx.x;  // block 128
  float v = (c < D_) ? poses[((size_t)b*(SEED_+PRED_) + (SEED_-1))*D_ + c] : 0.f;
  if (c < D_) x[b*D_ + c] = v;
  xpk[((b>>5)*4 + (c>>5))*1024 + (b&31)*32 + (c&31)] = __float2bfloat16(v);
}

__global__ void c_bf(const float* __restrict__ s, bf16* __restrict__ d, int n){
  int i = blockIdx.x*256 + threadIdx.x;
  if (i < n) d[i] = __float2bfloat16(s[i]);
}

__global__ void c_fpwt(const float* __restrict__ fpW, bf16* __restrict__ o){
  int dd = blockIdx.x;                       // 0..127
  for (int k = threadIdx.x; k < H_; k += 256)
    o[(size_t)dd*H_ + k] = __float2bfloat16(dd < D_ ? fpW[(size_t)k*D_ + dd] : 0.f);
}

// combined GRU weight rows (1152 wide: 128 x-cols | 1024 h-cols)
__global__ void c_wcat(const float* __restrict__ Wih, const float* __restrict__ Whh, bf16* __restrict__ o){
  int r = blockIdx.x;
  int jr; bool hasx, hash;
  if (r < 2048){ jr = r; hasx = true; hash = true; }
  else if (r < 3072){ jr = r; hasx = true; hash = false; }
  else { jr = r - 1024; hasx = false; hash = true; }
  bf16* row = o + (size_t)r*1152;
  for (int c = threadIdx.x; c < 1152; c += 256){
    float v = 0.f;
    if (c < D_) { if (hasx) v = Wih[(size_t)jr*D_ + c]; }
    else if (c >= 128){ if (hash) v = Whh[(size_t)jr*H_ + (c-128)]; }
    row[c] = __float2bfloat16(v);
  }
}

__global__ void c_bcat(const float* __restrict__ bih, const float* __restrict__ bhh, float* __restrict__ o){
  int r = blockIdx.x*256 + threadIdx.x;
  if (r >= 4096) return;
  float v;
  if (r < 2048) v = bih[r] + bhh[r];
  else if (r < 3072) v = bih[r];
  else v = bhh[r - 1024];
  o[r] = v;
}

// pack GRU weights into MFMA B-fragment order
__global__ __launch_bounds__(256) void c_wpk(const bf16* __restrict__ Wcat, bf16* __restrict__ Wpk){
  int chunk = blockIdx.x*4 + (threadIdx.x >> 6);
  int l = threadIdx.x & 63;
  int ks = chunk % 36; int t2 = chunk / 36; int g = t2 % 3; int ub = t2 / 3;
  int unit = ub*16 + (l & 15);
  bf16* dst = Wpk + (size_t)chunk*512 + l*8;
  #pragma unroll
  for (int e = 0; e < 8; ++e){
    int k = ks*32 + (l>>4)*8 + e;
    int row = (g==0) ? unit : (g==1) ? (1024+unit) : (k < 128 ? 2048+unit : 3072+unit);
    dst[e] = Wcat[(size_t)row*1152 + k];
  }
}

// pack W1-hid into fragment order: chunk = ug*32+ks, ug 0..111
__global__ __launch_bounds__(256) void c_w1pk(const float* __restrict__ sW1, bf16* __restrict__ w1pk){
  int chunk = blockIdx.x*4 + (threadIdx.x >> 6);   // 3584 chunks
  int l = threadIdx.x & 63;
  int ks = chunk & 31, ng = chunk >> 5;
  int unit = ng*16 + (l & 15);
  int j = unit >> 7, rr = unit & 127;
  bf16* dst = w1pk + (size_t)chunk*512 + l*8;
  #pragma unroll
  for (int e = 0; e < 8; ++e){
    int k = ks*32 + (l>>4)*8 + e;
    dst[e] = __float2bfloat16(sW1[((size_t)j*128 + rr)*1033 + k]);
  }
}

// pack SPL parent weights
__global__ void c_w1par(const float* __restrict__ sW1, float* __restrict__ w1par){
  int i = blockIdx.x*256 + threadIdx.x;
  if (i < 14*9*128){
    int j = i / (9*128); int rem = i % (9*128); int ii = rem / 128; int th = rem % 128;
    w1par[i] = sW1[((size_t)(j*128 + th))*1033 + 1024 + ii];
  }
}

// bc = inproj @ fp_b + in_b
__global__ __launch_bounds__(256) void k_bc(const float* __restrict__ inW, const float* __restrict__ inb,
                     const float* __restrict__ fpb, float* __restrict__ bc){
  int wave = threadIdx.x >> 6, lane = threadIdx.x & 63;
  int r = blockIdx.x*4 + wave;
  const float4* row = (const float4*)(inW + (size_t)r*H_);
  const float4* fp4 = (const float4*)fpb;
  float s = 0.f;
  #pragma unroll
  for (int i = 0; i < 4; ++i){
    float4 a = row[lane + i*64];
    float4 b = fp4[lane + i*64];
    s += a.x*b.x + a.y*b.y + a.z*b.z + a.w*b.w;
  }
  #pragma unroll
  for (int off = 32; off; off >>= 1) s += __shfl_down(s, off);
  if (lane == 0) bc[r] = s + inb[r];
}

// ---------------- encoder: wave-autonomous GRU (R10, unchanged) ----------------
#define SLCP(QA, QB, KS, GACC) { \
  union { ull u[2]; v8bf v; } cc_; cc_.u[0]=(QA); cc_.u[1]=(QB); \
  v8bf a_ = cc_.v; \
  v8bf w0_ = *(const v8bf*)&Wl[(0*36+(KS))*512 + lane*8]; \
  v8bf w1_ = *(const v8bf*)&Wl[(1*36+(KS))*512 + lane*8]; \
  v8bf w2_ = *(const v8bf*)&Wl[(2*36+(KS))*512 + lane*8]; \
  aR = __builtin_amdgcn_mfma_f32_16x16x32_bf16(a_, w0_, aR, 0,0,0); \
  aZ = __builtin_amdgcn_mfma_f32_16x16x32_bf16(a_, w1_, aZ, 0,0,0); \
  GACC = __builtin_amdgcn_mfma_f32_16x16x32_bf16(a_, w2_, GACC, 0,0,0); }

#define LDHA(DA, DB, C) { \
  const ull* hp_ = (const ull*)(hs + hbase + (size_t)(C)*1024); \
  DA = AL(hp_); DB = AL(hp_+1); }

#define LDXP(DA, DB, TT, C) { \
  const ull* xp_ = (const ull*)(xpk + (size_t)(TT)*xstride + xbase + (size_t)(C)*1024); \
  DA = xp_[0]; DB = xp_[1]; }

__global__ __launch_bounds__(512) void gru_wave(
    const bf16* __restrict__ xpk, int xstride, int nsteps, int coop,
    const bf16* __restrict__ Wpk, const float* __restrict__ bcat,
    const float* __restrict__ hin_plain, float* __restrict__ hout_plain,
    bf16* __restrict__ hbplain,
    bf16* __restrict__ hpk0, bf16* __restrict__ hpk1,
    unsigned* __restrict__ prog)
{
  __shared__ bf16 Wl[3*36*512];       // 108 KB
  const int tid = threadIdx.x, wave = tid >> 6, lane = tid & 63;
  const int ub = blockIdx.x >> 1, bs = blockIdx.x & 1;
  const int u0 = ub*16;

  {
    const bf16* wsrc = Wpk + (size_t)ub*(3*36*512);
    #pragma unroll
    for (int i = 0; i < 14; ++i){
      int c = i*512 + tid;
      if (c < 6912) GLD16(&Wl[c*8], wsrc + (size_t)c*8);
    }
  }
  VMWAIT(0); BARRIER();

  const int la = lane & 15, lb = lane >> 4;
  const int r0 = bs*128 + wave*16;
  const int rb = r0 >> 5, y = wave & 1;
  const int ucol = u0 + la;
  const float bR = bcat[ucol], bZ = bcat[1024+ucol], bI = bcat[2048+ucol], bN = bcat[3072+ucol];
  const size_t hbase = (size_t)rb*32768 + (size_t)y*512 + la*32 + lb*8;
  const size_t xbase = (size_t)rb*4096  + (size_t)y*512 + la*32 + lb*8;
  const size_t pwb = (size_t)rb*32768 + (size_t)(u0>>5)*1024 + (size_t)y*512 + (u0&16) + la;

  float hr[4];
  if (nsteps == 1){
    #pragma unroll
    for (int r = 0; r < 4; ++r) hr[r] = hin_plain[(size_t)(r0 + lb*4 + r)*1024 + ucol];
  } else {
    #pragma unroll
    for (int r = 0; r < 4; ++r) hr[r] = 0.f;
  }

  ull a0,a1,a2,a3,a4,a5,a6,a7,a8,a9,a10,a11;
  ull b0,b1,b2,b3,b4,b5,b6,b7,b8,b9,b10,b11;
  LDXP(a0,b0,0,0); LDXP(a1,b1,0,1); LDXP(a2,b2,0,2); LDXP(a3,b3,0,3);

  for (int t = 0; t < nsteps; ++t){
    if (coop && t > 0){
      if (wave == 0){
        unsigned v = AL(&prog[bs*64 + lane]);
        while (__ballot(v >= (unsigned)t) != ~0ULL){
          __builtin_amdgcn_s_sleep(1);
          v = AL(&prog[bs*64 + lane]);
        }
      }
      __syncthreads();
      __builtin_amdgcn_sched_barrier(0);
    }
    const bf16* hs = (t & 1) ? hpk1 : hpk0;
    LDHA(a4,b4,0) LDHA(a5,b5,1) LDHA(a6,b6,2) LDHA(a7,b7,3)
    LDHA(a8,b8,4) LDHA(a9,b9,5) LDHA(a10,b10,6) LDHA(a11,b11,7)

    f32x4 z4 = {0.f,0.f,0.f,0.f};
    f32x4 aR = z4, aZ = z4, aI = z4, aN = z4;

    SLCP(a0,b0,0,aI)  LDHA(a0,b0,8)
    SLCP(a1,b1,1,aI)  LDHA(a1,b1,9)
    SLCP(a2,b2,2,aI)  LDHA(a2,b2,10)
    SLCP(a3,b3,3,aI)  LDHA(a3,b3,11)
    SLCP(a4,b4,4,aN)  LDHA(a4,b4,12)
    SLCP(a5,b5,5,aN)  LDHA(a5,b5,13)
    SLCP(a6,b6,6,aN)  LDHA(a6,b6,14)
    SLCP(a7,b7,7,aN)  LDHA(a7,b7,15)
    SLCP(a8,b8,8,aN)  LDHA(a8,b8,16)
    SLCP(a9,b9,9,aN)  LDHA(a9,b9,17)
    SLCP(a10,b10,10,aN) LDHA(a10,b10,18)
    SLCP(a11,b11,11,aN) LDHA(a11,b11,19)
    SLCP(a0,b0,12,aN) LDHA(a0,b0,20)
    SLCP(a1,b1,13,aN) LDHA(a1,b1,21)
    SLCP(a2,b2,14,aN) LDHA(a2,b2,22)
    SLCP(a3,b3,15,aN) LDHA(a3,b3,23)
    SLCP(a4,b4,16,aN) LDHA(a4,b4,24)
    SLCP(a5,b5,17,aN) LDHA(a5,b5,25)
    SLCP(a6,b6,18,aN) LDHA(a6,b6,26)
    SLCP(a7,b7,19,aN) LDHA(a7,b7,27)
    SLCP(a8,b8,20,aN) LDHA(a8,b8,28)
    SLCP(a9,b9,21,aN) LDHA(a9,b9,29)
    SLCP(a10,b10,22,aN) LDHA(a10,b10,30)
    SLCP(a11,b11,23,aN) LDHA(a11,b11,31)
    SLCP(a0,b0,24,aN) LDXP(a0,b0,t+1,0)
    SLCP(a1,b1,25,aN) LDXP(a1,b1,t+1,1)
    SLCP(a2,b2,26,aN) LDXP(a2,b2,t+1,2)
    SLCP(a3,b3,27,aN) LDXP(a3,b3,t+1,3)
    SLCP(a4,b4,28,aN)
    SLCP(a5,b5,29,aN)
    SLCP(a6,b6,30,aN)
    SLCP(a7,b7,31,aN)
    SLCP(a8,b8,32,aN)
    SLCP(a9,b9,33,aN)
    SLCP(a10,b10,34,aN)
    SLCP(a11,b11,35,aN)

    bf16* hd = (t & 1) ? hpk0 : hpk1;
    const bool last = (t == nsteps-1);
    #pragma unroll
    for (int r = 0; r < 4; ++r){
      float rg = 1.f/(1.f + __expf(-(aR[r] + bR)));
      float zg = 1.f/(1.f + __expf(-(aZ[r] + bZ)));
      float ng = tanhf((aI[r] + bI) + rg*(aN[r] + bN));
      float hv = (1.f - zg)*ng + zg*hr[r];
      hr[r] = hv;
      bf16 hv16 = __float2bfloat16(hv);
      unsigned short hbits = *(unsigned short*)&hv16;
      __hip_atomic_store((unsigned short*)(hd + pwb + (size_t)(lb*4 + r)*32), hbits,
                         __ATOMIC_RELAXED, __HIP_MEMORY_SCOPE_AGENT);
      if (last){
        hout_plain[(size_t)(r0 + lb*4 + r)*1024 + ucol] = hv;
        if (hbplain) hbplain[(size_t)(r0 + lb*4 + r)*1024 + ucol] = __float2bfloat16(hv);
      }
    }
    if (coop && t + 1 < nsteps){
      VMWAIT(0);
      __syncthreads();
      if (tid == 0)
        __hip_atomic_store(&prog[bs*64 + ub], (unsigned)(t+1), __ATOMIC_RELAXED, __HIP_MEMORY_SCOPE_AGENT);
    }
  }
}

// ---------------- decoder GRU with fused SPL(t-1) prologue (R14, unchanged) ----------------
__constant__ int LVJ[14] = {0,1,6,8,9, 2,3,7,10,11, 4,5,12,13};
__constant__ int LVO[4]  = {0,5,10,14};
__constant__ int PAR_[14] = {-1,-1,0,1,2,3,-1,6,-1,-1,8,9,10,11};

#define DGRL(S,C) { const ull* p_=(const ull*)(hspk + hbase + (size_t)(C)*1024); qa##S=AL(p_); qb##S=AL(p_+1); }
#define DGXL(S,C) { const ull* p_=(const ull*)(xpk + xbase + (size_t)(C)*1024); qa##S=AL(p_); qb##S=AL(p_+1); }
#define DGRC(S,KS,GACC) { union{ull u[2];v8bf v;}c_; c_.u[0]=qa##S;c_.u[1]=qb##S; v8bf a_=c_.v; \
  v8bf w0_=*(const v8bf*)&Wl[(KS)*512+lane*8]; \
  v8bf w1_=*(const v8bf*)&Wl[18432+(KS)*512+lane*8]; \
  v8bf w2_=*(const v8bf*)&Wl[36864+(KS)*512+lane*8]; \
  aR=__builtin_amdgcn_mfma_f32_16x16x32_bf16(a_,w0_,aR,0,0,0); \
  aZ=__builtin_amdgcn_mfma_f32_16x16x32_bf16(a_,w1_,aZ,0,0,0); \
  GACC=__builtin_amdgcn_mfma_f32_16x16x32_bf16(a_,w2_,GACC,0,0,0); }

__global__ __launch_bounds__(512) void gru_spl(
    const bf16* __restrict__ xpk, const bf16* __restrict__ Wpk,
    const float* __restrict__ bcat,
    const float* __restrict__ hin_plain, float* __restrict__ hout_plain,
    bf16* __restrict__ hbplain,
    const bf16* __restrict__ hspk, bf16* __restrict__ hdpk,
    const float* __restrict__ hhpre, const float* __restrict__ w1par,
    const float* __restrict__ sW2, const float* __restrict__ sb2,
    float* __restrict__ xcur, bf16* __restrict__ xpkw, float* __restrict__ out,
    int dt, unsigned* __restrict__ progS)
{
  __shared__ bf16 Wl[3*36*512];     // 108 KB
  __shared__ float hhl[2][1792];    // 14 KB
  __shared__ float preds_s[2][128];
  __shared__ float hh_s[128][2];
  const int tid = threadIdx.x, wave = tid >> 6, lane = tid & 63;
  const int bid = blockIdx.x;
  const int ub = bid >> 1, bs = bid & 1, u0 = ub*16;

  {  // weights -> LDS (async, overlaps SPL)
    const bf16* wsrc = Wpk + (size_t)ub*(3*36*512);
    #pragma unroll
    for (int i = 0; i < 14; ++i){ int c = i*512 + tid; if (c < 6912) GLD16(&Wl[c*8], wsrc + (size_t)c*8); }
  }

  // ---- SPL of previous step (regular loads; coherent via launch boundary) ----
  const int b0s = bid*2, th = tid;
  if (dt > 0){
    for (int i = tid; i < 2*1792; i += 512){
      int bb = i / 1792, col = i - bb*1792;
      hhl[bb][col] = hhpre[(size_t)(b0s+bb)*1792 + col];
    }
    __syncthreads();
    for (int L = 0; L < 3; ++L){
      for (int ji = LVO[L]; ji < LVO[L+1]; ++ji){
        int j = LVJ[ji], p = PAR_[j];
        if (tid < 128){
          float a0s = hhl[0][j*128 + th], a1s = hhl[1][j*128 + th];
          if (p >= 0){
            #pragma unroll
            for (int ii = 0; ii < 9; ++ii){
              float w = w1par[(j*9 + ii)*128 + th];
              a0s += w * preds_s[0][p*9 + ii];
              a1s += w * preds_s[1][p*9 + ii];
            }
          }
          hh_s[th][0] = fmaxf(a0s, 0.f);
          hh_s[th][1] = fmaxf(a1s, 0.f);
        }
        __syncthreads();
        if (tid < 36){
          int pp = th >> 1, half = th & 1;
          int bb = pp/9, oi = pp%9;
          const float4* w4 = (const float4*)(sW2 + (size_t)(j*9 + oi)*128 + half*64);
          float s = 0.f;
          #pragma unroll
          for (int q = 0; q < 16; ++q){
            float4 wv = w4[q];
            s += hh_s[half*64 + q*4 + 0][bb]*wv.x + hh_s[half*64 + q*4 + 1][bb]*wv.y
               + hh_s[half*64 + q*4 + 2][bb]*wv.z + hh_s[half*64 + q*4 + 3][bb]*wv.w;
          }
          s += __shfl_xor(s, 1);
          if (half == 0) preds_s[bb][j*9 + oi] = tanhf(s + sb2[j*9 + oi]);
        }
        __syncthreads();
      }
    }
    if (tid < 128){
      for (int i = th; i < 2*D_; i += 128){
        int bb = i / D_, d = i % D_;
        int row = b0s + bb;
        size_t xi = (size_t)row*D_ + d;
        float v = xcur[xi] + preds_s[bb][d];
        xcur[xi] = v;
        bf16 v16 = __float2bfloat16(v);
        __hip_atomic_store((unsigned short*)(xpkw + ((size_t)(row>>5)*4 + (d>>5))*1024 + (row&31)*32 + (d&31)),
                           *(unsigned short*)&v16, __ATOMIC_RELAXED, __HIP_MEMORY_SCOPE_AGENT);
        out[((size_t)row*PRED_ + (dt-1))*D_ + d] = v;
      }
    }
    VMWAIT(0);
    __syncthreads();
    if (tid == 0)
      __hip_atomic_store(&progS[bid], (unsigned)dt, __ATOMIC_RELAXED, __HIP_MEMORY_SCOPE_AGENT);
  }

  VMWAIT(0); BARRIER();     // weights resident

  const int la = lane & 15, lb = lane >> 4;
  const int r0 = bs*128 + wave*16;
  const int rb = r0 >> 5, y = wave & 1;
  const int ucol = u0 + la;
  const float bR = bcat[ucol], bZ = bcat[1024+ucol], bI = bcat[2048+ucol], bN = bcat[3072+ucol];
  const size_t hbase = (size_t)rb*32768 + (size_t)y*512 + la*32 + lb*8;
  const size_t xbase = (size_t)rb*4096  + (size_t)y*512 + la*32 + lb*8;
  const size_t pwb = (size_t)rb*32768 + (size_t)(u0>>5)*1024 + (size_t)y*512 + (u0&16) + la;

  float hr[4];
  #pragma unroll
  for (int r = 0; r < 4; ++r) hr[r] = hin_plain[(size_t)(r0 + lb*4 + r)*1024 + ucol];

  ull qa0,qa1,qa2,qa3,qa4,qa5,qa6,qa7,qa8,qa9,qa10,qa11;
  ull qb0,qb1,qb2,qb3,qb4,qb5,qb6,qb7,qb8,qb9,qb10,qb11;

  // h-slices first (depend only on h^t)
  DGRL(0,0) DGRL(1,1) DGRL(2,2) DGRL(3,3) DGRL(4,4) DGRL(5,5)
  DGRL(6,6) DGRL(7,7) DGRL(8,8) DGRL(9,9) DGRL(10,10) DGRL(11,11)
  f32x4 z4 = {0.f,0.f,0.f,0.f};
  f32x4 aR = z4, aZ = z4, aI = z4, aN = z4;
  DGRC(0,4,aN)  DGRL(0,12)
  DGRC(1,5,aN)  DGRL(1,13)
  DGRC(2,6,aN)  DGRL(2,14)
  DGRC(3,7,aN)  DGRL(3,15)
  DGRC(4,8,aN)  DGRL(4,16)
  DGRC(5,9,aN)  DGRL(5,17)
  DGRC(6,10,aN) DGRL(6,18)
  DGRC(7,11,aN) DGRL(7,19)
  DGRC(8,12,aN) DGRL(8,20)
  DGRC(9,13,aN) DGRL(9,21)
  DGRC(10,14,aN) DGRL(10,22)
  DGRC(11,15,aN) DGRL(11,23)
  DGRC(0,16,aN) DGRL(0,24)
  DGRC(1,17,aN) DGRL(1,25)
  DGRC(2,18,aN) DGRL(2,26)
  DGRC(3,19,aN) DGRL(3,27)
  DGRC(4,20,aN) DGRL(4,28)
  DGRC(5,21,aN) DGRL(5,29)
  DGRC(6,22,aN) DGRL(6,30)
  DGRC(7,23,aN) DGRL(7,31)
  DGRC(8,24,aN)
  DGRC(9,25,aN)
  DGRC(10,26,aN)
  DGRC(11,27,aN)
  DGRC(0,28,aN)
  DGRC(1,29,aN)
  DGRC(2,30,aN)
  DGRC(3,31,aN)
  DGRC(4,32,aN)
  DGRC(5,33,aN)
  DGRC(6,34,aN)
  DGRC(7,35,aN)
  if (dt > 0){
    if (wave == 0){
      unsigned v1 = AL(&progS[lane]), v2 = AL(&progS[64 + lane]);
      while (__ballot((v1 >= (unsigned)dt) && (v2 >= (unsigned)dt)) != ~0ULL){
        __builtin_amdgcn_s_sleep(2);
        v1 = AL(&progS[lane]); v2 = AL(&progS[64 + lane]);
      }
    }
    __syncthreads();
    __builtin_amdgcn_sched_barrier(0);
  }
  DGXL(8,0) DGXL(9,1) DGXL(10,2) DGXL(11,3)
  DGRC(8,0,aI)
  DGRC(9,1,aI)
  DGRC(10,2,aI)
  DGRC(11,3,aI)
  #pragma unroll
  for (int r = 0; r < 4; ++r){
    float rg = 1.f/(1.f + __expf(-(aR[r] + bR)));
    float zg = 1.f/(1.f + __expf(-(aZ[r] + bZ)));
    float ng = tanhf((aI[r] + bI) + rg*(aN[r] + bN));
    float hv = (1.f - zg)*ng + zg*hr[r];
    bf16 hv16 = __float2bfloat16(hv);
    __hip_atomic_store((unsigned short*)(hdpk + pwb + (size_t)(lb*4 + r)*32),
                       *(unsigned short*)&hv16, __ATOMIC_RELAXED, __HIP_MEMORY_SCOPE_AGENT);
    hout_plain[(size_t)(r0 + lb*4 + r)*1024 + ucol] = hv;
    hbplain[(size_t)(r0 + lb*4 + r)*1024 + ucol] = hv16;
  }
}

// ---------------- fused pre + W1: one launch per decoder step ----------------
// grid 112 x 512. Phase A (blocks 0..63): hid = relu(hb@preW^T + preb) + motion
// (64x64 tile, gemm64-style, A/B coherent via launch boundary), store hid packed
// (h-style tiles: tile = (row>>5)*32 + (col>>5)) via IF atomics, flag.
// Phase B (all): W1 M=64xN=64 (R12 mapping), A = hidpk IF-atomic ring, B = w1pk;
// hhpre stored plain (read next launch).
#define W1L(S,C) { const ull* p_=(const ull*)(hidpk + w1abase + (size_t)(C)*1024); \
  qa##S=AL(p_); qb##S=AL(p_+1); \
  bq##S = *(const uint4*)(w1b0 + (size_t)(C)*512 + lane*8); \
  br##S = *(const uint4*)(w1b1 + (size_t)(C)*512 + lane*8); }
#define W1C(S) { union{ull u[2];v8bf v;}x_; x_.u[0]=qa##S;x_.u[1]=qb##S; \
  union{uint4 q; v8bf v;}b0_,b1_; b0_.q=bq##S; b1_.q=br##S; \
  c0=__builtin_amdgcn_mfma_f32_16x16x32_bf16(x_.v,b0_.v,c0,0,0,0); \
  c1=__builtin_amdgcn_mfma_f32_16x16x32_bf16(x_.v,b1_.v,c1,0,0,0); }

__global__ __launch_bounds__(512) void gemm_pw(
    const bf16* __restrict__ hb, const bf16* __restrict__ prebf,
    const float* __restrict__ preb, const float* __restrict__ motion,
    bf16* __restrict__ hidpk, const bf16* __restrict__ w1pk,
    const float* __restrict__ sb1, float* __restrict__ hhpre,
    int dt, unsigned* __restrict__ progP)
{
  __shared__ bf16 As[3][64*64];
  __shared__ bf16 Bs[3][64*64];
  const int tid = threadIdx.x, wave = tid >> 6, lane = tid & 63;
  const int bid = blockIdx.x;
  const int la = lane & 15, lb = lane >> 4;

  // ---------- phase A: pre (blocks 0..63) ----------
  if (bid < 64){
    const int m0 = (bid & 3)*64, n0 = (bid >> 2)*64;
    const int fr = lane & 31, kh = lane >> 5;
    const int wm = (wave >> 1)*32, wn = (wave & 1)*32;
    f32x16 acc = {0.f,0.f,0.f,0.f,0.f,0.f,0.f,0.f,0.f,0.f,0.f,0.f,0.f,0.f,0.f,0.f};

    auto STAGE = [&](int buf, int kt){
      if (tid < 256){
        #pragma unroll
        for (int q = 0; q < 2; ++q){
          int idx = q*256 + tid;
          int row = idx >> 3, cp = idx & 7, csw = cp ^ (row & 7);
          GLD16(&As[buf][idx*8], hb + (size_t)(m0+row)*1024 + kt*64 + csw*8);
        }
        #pragma unroll
        for (int q = 0; q < 2; ++q){
          int idx = q*256 + tid;
          int row = idx >> 3, cp = idx & 7, csw = cp ^ (row & 7);
          GLD16(&Bs[buf][idx*8], prebf + (size_t)(n0+row)*1024 + kt*64 + csw*8);
        }
      }
    };
    auto COMPUTE = [&](int buf){
      if (wave < 4){
        const bf16* Ab = &As[buf][0];
        const bf16* Bb = &Bs[buf][0];
        #pragma unroll
        for (int ks = 0; ks < 4; ++ks){
          int ca = ks*2 + kh;
          v8bf av = *(const v8bf*)&Ab[(wm+fr)*64 + ((ca ^ ((wm+fr)&7))*8)];
          v8bf bv = *(const v8bf*)&Bb[(wn+fr)*64 + ((ca ^ ((wn+fr)&7))*8)];
          acc = __builtin_amdgcn_mfma_f32_32x32x16_bf16(av, bv, acc, 0, 0, 0);
        }
      }
    };

    STAGE(0, 0); STAGE(1, 1);
    VMWAIT(4); BARRIER();
    for (int kt = 0; kt < 16; ++kt){
      if (kt + 2 < 16) STAGE((kt+2)%3, kt+2);
      COMPUTE(kt%3);
      if (kt + 2 < 16){ VMWAIT(4); BARRIER(); }
      else if (kt + 1 < 16){ VMWAIT(0); BARRIER(); }
    }
    if (wave < 4){
      const int col = n0 + wn + fr;
      const float bb2 = preb[col];
      #pragma unroll
      for (int r = 0; r < 16; ++r){
        int row = m0 + wm + (r&3) + 8*(r>>2) + 4*kh;
        float v = fmaxf(acc[r] + bb2, 0.f) + motion[(size_t)row*1024 + col];
        bf16 v16 = __float2bfloat16(v);
        // h-style packing: tile = (row>>5)*32 + (col>>5)   [FIXED from R15's *4]
        __hip_atomic_store((unsigned short*)(hidpk + ((size_t)(row>>5)*32 + (col>>5))*1024 + (row&31)*32 + (col&31)),
                           *(unsigned short*)&v16, __ATOMIC_RELAXED, __HIP_MEMORY_SCOPE_AGENT);
      }
    }
    VMWAIT(0);
    __syncthreads();
    if (tid == 0)
      __hip_atomic_store(&progP[bid], (unsigned)(dt+1), __ATOMIC_RELAXED, __HIP_MEMORY_SCOPE_AGENT);
  }

  // ---------- wait for all pre flags ----------
  if (wave == 0){
    unsigned v = AL(&progP[lane]);
    while (__ballot(v >= (unsigned)(dt+1)) != ~0ULL){
      __builtin_amdgcn_s_sleep(2);
      v = AL(&progP[lane]);
    }
  }
  __syncthreads();
  __builtin_amdgcn_sched_barrier(0);

  // ---------- phase B: W1 (all 112 blocks) ----------
  const int mq = bid / 28, ng = bid % 28;
  const int mg = wave >> 1, nc = wave & 1;
  const int r0w = mq*64 + mg*16;
  const int w1rb = r0w >> 5, w1y = mg & 1;
  const size_t w1abase = (size_t)w1rb*32768 + (size_t)w1y*512 + la*32 + lb*8;
  const int ug0 = ng*4 + nc*2, ug1 = ug0 + 1;
  const bf16* w1b0 = w1pk + (size_t)ug0*(32*512);
  const bf16* w1b1 = w1pk + (size_t)ug1*(32*512);
  const float sb1a = sb1[ug0*16 + la];
  const float sb1b = sb1[ug1*16 + la];

  ull qa0,qa1,qa2,qa3,qa4,qa5;
  ull qb0,qb1,qb2,qb3,qb4,qb5;
  uint4 bq0,bq1,bq2,bq3,bq4,bq5;
  uint4 br0,br1,br2,br3,br4,br5;

  W1L(0,0) W1L(1,1) W1L(2,2) W1L(3,3) W1L(4,4) W1L(5,5)
  f32x4 c0 = {0.f,0.f,0.f,0.f}, c1 = c0;
  W1C(0) W1L(0,6)
  W1C(1) W1L(1,7)
  W1C(2) W1L(2,8)
  W1C(3) W1L(3,9)
  W1C(4) W1L(4,10)
  W1C(5) W1L(5,11)
  W1C(0) W1L(0,12)
  W1C(1) W1L(1,13)
  W1C(2) W1L(2,14)
  W1C(3) W1L(3,15)
  W1C(4) W1L(4,16)
  W1C(5) W1L(5,17)
  W1C(0) W1L(0,18)
  W1C(1) W1L(1,19)
  W1C(2) W1L(2,20)
  W1C(3) W1L(3,21)
  W1C(4) W1L(4,22)
  W1C(5) W1L(5,23)
  W1C(0) W1L(0,24)
  W1C(1) W1L(1,25)
  W1C(2) W1L(2,26)
  W1C(3) W1L(3,27)
  W1C(4) W1L(4,28)
  W1C(5) W1L(5,29)
  W1C(0) W1L(0,30)
  W1C(1) W1L(1,31)
  W1C(2)
  W1C(3)
  W1C(4)
  W1C(5)
  W1C(0)
  W1C(1)
  #pragma unroll
  for (int r = 0; r < 4; ++r){
    int row = r0w + lb*4 + r;
    hhpre[(size_t)row*1792 + ug0*16 + la] = c0[r] + sb1a;
    hhpre[(size_t)row*1792 + ug1*16 + la] = c1[r] + sb1b;
  }
}

// ---------------- pipelined generic GEMM (preamble only) ----------------
__global__ __launch_bounds__(256) void gemm64(
    const bf16* __restrict__ Am, const bf16* __restrict__ Bm, int K,
    const float* __restrict__ bias, const float* __restrict__ addmat,
    float* __restrict__ C, bf16* __restrict__ Cbf, int N, int MODE)
{
  __shared__ bf16 As[3][64*64];
  __shared__ bf16 Bs[3][64*64];
  const int tid = threadIdx.x;
  const int wave = tid >> 6, lane = tid & 63;
  const int m0 = blockIdx.x*64, n0 = blockIdx.y*64;
  const int fr = lane & 31, kh = lane >> 5;
  const int wm = (wave >> 1)*32, wn = (wave & 1)*32;
  const int KT = K >> 6;

  f32x16 acc = {0.f,0.f,0.f,0.f,0.f,0.f,0.f,0.f,0.f,0.f,0.f,0.f,0.f,0.f,0.f,0.f};

  auto STAGE = [&](int buf, int kt){
    #pragma unroll
    for (int q = 0; q < 2; ++q){
      int idx = q*256 + tid;
      int row = idx >> 3, cp = idx & 7, csw = cp ^ (row & 7);
      GLD16(&As[buf][idx*8], Am + (size_t)(m0+row)*K + kt*64 + csw*8);
    }
    #pragma unroll
    for (int q = 0; q < 2; ++q){
      int idx = q*256 + tid;
      int row = idx >> 3, cp = idx & 7, csw = cp ^ (row & 7);
      GLD16(&Bs[buf][idx*8], Bm + (size_t)(n0+row)*K + kt*64 + csw*8);
    }
  };
  auto COMPUTE = [&](int buf){
    const bf16* Ab = &As[buf][0];
    const bf16* Bb = &Bs[buf][0];
    #pragma unroll
    for (int ks = 0; ks < 4; ++ks){
      int ca = ks*2 + kh;
      v8bf av = *(const v8bf*)&Ab[(wm+fr)*64 + ((ca ^ ((wm+fr)&7))*8)];
      v8bf bv = *(const v8bf*)&Bb[(wn+fr)*64 + ((ca ^ ((wn+fr)&7))*8)];
      acc = __builtin_amdgcn_mfma_f32_32x32x16_bf16(av, bv, acc, 0, 0, 0);
    }
  };

  STAGE(0, 0);
  if (KT > 1){ STAGE(1, 1); VMWAIT(4); } else { VMWAIT(0); }
  BARRIER();
  for (int kt = 0; kt < KT; ++kt){
    if (kt + 2 < KT) STAGE((kt+2)%3, kt+2);
    COMPUTE(kt%3);
    if (kt + 2 < KT){ VMWAIT(4); BARRIER(); }
    else if (kt + 1 < KT){ VMWAIT(0); BARRIER(); }
  }

  const int col = n0 + wn + fr;
  float bb = bias ? bias[col] : 0.f;
  #pragma unroll
  for (int r = 0; r < 16; ++r){
    int row = m0 + wm + (r&3) + 8*(r>>2) + 4*kh;
    float v = acc[r] + bb;
    if (MODE == 1) v = fmaxf(v, 0.f) + addmat[(size_t)row*N + col];
    if (C)   C[(size_t)row*N + col] = v;
    if (Cbf) Cbf[(size_t)row*N + col] = __float2bfloat16(v);
  }
}

// ---------------- attention: one block per (b,h) ----------------
__global__ __launch_bounds__(256) void k_attn(const bf16* __restrict__ qkv,
                                              bf16* __restrict__ ctxbf){
  __shared__ char smem[65536];
  bf16* qs = (bf16*)smem;
  bf16* ks = qs + 64*256;
  float* sc = (float*)smem;
  float* cs = (float*)(smem + 32768);
  const int h = blockIdx.x, b = blockIdx.y;
  const int tid = threadIdx.x, wave = tid >> 6, lane = tid & 63;
  const int fr = lane & 31, kh = lane >> 5;
  const int wm = (wave >> 1)*32, wn = (wave & 1)*32;

  #pragma unroll
  for (int i = 0; i < 8; ++i){
    int idx = i*256 + tid;
    int row = idx >> 5, cp = idx & 31, csw = cp ^ (row & 7);
    GLD16(&qs[idx*8], qkv + (size_t)(b*F_ + row)*3072 + h*DH_ + csw*8);
  }
  #pragma unroll
  for (int i = 0; i < 8; ++i){
    int idx = i*256 + tid;
    int row = idx >> 5, cp = idx & 31, csw = cp ^ (row & 7);
    GLD16(&ks[idx*8], qkv + (size_t)(b*F_ + row)*3072 + H_ + h*DH_ + csw*8);
  }
  __syncthreads();

  f32x16 acc = {0.f,0.f,0.f,0.f,0.f,0.f,0.f,0.f,0.f,0.f,0.f,0.f,0.f,0.f,0.f,0.f};
  #pragma unroll
  for (int i = 0; i < 16; ++i){
    int ca = i*2 + kh;
    v8bf av = *(const v8bf*)&qs[((wm+fr)*32 + (ca ^ ((wm+fr)&7)))*8];
    v8bf bv = *(const v8bf*)&ks[((wn+fr)*32 + (ca ^ ((wn+fr)&7)))*8];
    acc = __builtin_amdgcn_mfma_f32_32x32x16_bf16(av, bv, acc, 0, 0, 0);
  }
  __syncthreads();
  #pragma unroll
  for (int r = 0; r < 16; ++r){
    int row = wm + (r&3) + 8*(r>>2) + 4*kh;
    sc[row*65 + (wn+fr)] = acc[r]*0.0625f;
  }
  __syncthreads();
  if (tid < F_){
    float m = -1e30f;
    for (int k2 = 0; k2 < F_; ++k2) m = fmaxf(m, sc[tid*65+k2]);
    float s = 0.f;
    for (int k2 = 0; k2 < F_; ++k2){ float e = __expf(sc[tid*65+k2]-m); sc[tid*65+k2] = e; s += e; }
    float is = 1.f/s;
    for (int k2 = 0; k2 < F_; ++k2) sc[tid*65+k2] *= is;
  }
  __syncthreads();
  if (tid < F_){
    float s = 0.f;
    for (int r = 0; r < F_; ++r) s += sc[r*65+tid];
    cs[tid] = s;
  }
  __syncthreads();
  float a = 0.f;
  for (int k2 = 0; k2 < F_; ++k2){
    float v = __bfloat162float(qkv[(size_t)(b*F_+k2)*3072 + 2*H_ + h*DH_ + tid]);
    a += cs[k2]*v;
  }
  ctxbf[(size_t)b*H_ + h*DH_ + tid] = __float2bfloat16(a * (1.f/61.f));
}

// ---------------- SPL final step ----------------
__global__ __launch_bounds__(128) void spl_all(const float* __restrict__ hh_pre, const float* __restrict__ w1par,
                        const float* __restrict__ W2, const float* __restrict__ b2,
                        float* __restrict__ x, bf16* __restrict__ xpk,
                        float* __restrict__ out, int tstep){
  __shared__ float preds_s[4][128];
  __shared__ float hh_s[128][5];
  int b0 = blockIdx.x*4, t = threadIdx.x;   // grid 64, block 128
  for (int L = 0; L < 3; ++L){
    for (int ji = LVO[L]; ji < LVO[L+1]; ++ji){
      int j = LVJ[ji], p = PAR_[j];
      float acc[4];
      #pragma unroll
      for (int bb = 0; bb < 4; ++bb) acc[bb] = hh_pre[(size_t)(b0+bb)*1792 + j*128 + t];
      if (p >= 0){
        #pragma unroll
        for (int ii = 0; ii < 9; ++ii){
          float w = w1par[(j*9 + ii)*128 + t];
          #pragma unroll
          for (int bb = 0; bb < 4; ++bb) acc[bb] += w * preds_s[bb][p*9 + ii];
        }
      }
      #pragma unroll
      for (int bb = 0; bb < 4; ++bb) hh_s[t][bb] = fmaxf(acc[bb], 0.f);
      __syncthreads();
      if (t < 72){
        int pp = t >> 1, half = t & 1;
        int bb = pp/9, oi = pp%9;
        const float* w2r = W2 + (size_t)(j*9 + oi)*128 + half*64;
        float s = 0.f;
        #pragma unroll
        for (int tt = 0; tt < 64; ++tt) s += hh_s[half*64 + tt][bb] * w2r[tt];
        s += __shfl_xor(s, 1);
        if (half == 0) preds_s[bb][j*9 + oi] = tanhf(s + b2[j*9 + oi]);
      }
      __syncthreads();
    }
  }
  for (int i = t; i < 4*D_; i += 128){
    int bb = i / D_, d = i % D_;
    int row = b0 + bb;
    size_t xi = (size_t)row*D_ + d;
    float v = x[xi] + preds_s[bb][d];
    x[xi] = v;
    xpk[((row>>5)*4 + (d>>5))*1024 + (row&31)*32 + (d&31)] = __float2bfloat16(v);
    out[((size_t)row*PRED_ + tstep)*D_ + d] = v;
  }
}

// ---------------- launch ----------------
extern "C" void kernel_launch(void* const* d_in, const int* in_sizes, int n_in,
                              void* d_out, int out_size, void* d_ws, size_t ws_size,
                              hipStream_t stream){
  (void)in_sizes; (void)n_in; (void)out_size; (void)ws_size;
  const float* poses = (const float*)d_in[0];
  const float* gWih  = (const float*)d_in[1];
  const float* gWhh  = (const float*)d_in[2];
  const float* gbih  = (const float*)d_in[3];
  const float* gbhh  = (const float*)d_in[4];
  const float* preW  = (const float*)d_in[5];
  const float* preb  = (const float*)d_in[6];
  const float* fpW   = (const float*)d_in[7];
  const float* fpb   = (const float*)d_in[8];
  const float* inW   = (const float*)d_in[9];
  const float* inb   = (const float*)d_in[10];
  const float* outW  = (const float*)d_in[11];
  const float* outb  = (const float*)d_in[12];
  const float* sW1   = (const float*)d_in[13];
  const float* sb1   = (const float*)d_in[14];
  const float* sW2   = (const float*)d_in[15];
  const float* sb2   = (const float*)d_in[16];
  float* out = (float*)d_out;

  char* w = (char*)d_ws;
  size_t off = 0;
  auto alloc = [&](size_t bytes)->char*{ char* p = w + off; off += (bytes + 255) & ~(size_t)255; return p; };
  float* cosT   = (float*)alloc(7320*4);
  float* bc     = (float*)alloc(3072*4);
  float* motion = (float*)alloc((size_t)256*1024*4);
  float* hA     = (float*)alloc((size_t)256*1024*4);
  float* hB     = (float*)alloc((size_t)256*1024*4);
  float* xcur   = (float*)alloc((size_t)256*126*4);
  float* hhpre  = (float*)alloc((size_t)256*1792*4);
  float* bcat   = (float*)alloc(4096*4);
  float* w1par  = (float*)alloc(14*9*128*4);
  unsigned* prog= (unsigned*)alloc(2048);
  bf16* posespk = (bf16*)alloc((size_t)121*32768*2);
  bf16* Wcat    = (bf16*)alloc((size_t)4096*1152*2);
  bf16* Wpk     = (bf16*)alloc((size_t)64*108*512*2);
  bf16* w1pk    = (bf16*)alloc((size_t)112*32*512*2);
  bf16* prebf   = (bf16*)alloc((size_t)1024*1024*2);
  bf16* outbf   = (bf16*)alloc((size_t)1024*1024*2);
  bf16* inbf    = (bf16*)alloc((size_t)3072*1024*2);
  bf16* fpwt    = (bf16*)alloc((size_t)128*1024*2);
  bf16* ctxbf   = (bf16*)alloc((size_t)256*1024*2);
  bf16* hpkA    = (bf16*)alloc((size_t)256*1024*2);
  bf16* hpkB    = (bf16*)alloc((size_t)256*1024*2);
  bf16* hbplain = (bf16*)alloc((size_t)256*1024*2);
  bf16* hidpk   = (bf16*)alloc((size_t)256*1024*2);
  bf16* xpk     = (bf16*)alloc((size_t)32768*2);
  bf16* Wcbf    = (bf16*)alloc((size_t)3072*128*2);
  bf16* freqbf  = (bf16*)alloc((size_t)B_*F_*128*2);
  bf16* qkvbf   = (bf16*)alloc((size_t)15680*3072*2);

  hipMemsetAsync(hpkA, 0, (size_t)256*1024*2, stream);
  hipMemsetAsync(prog, 0, 2048, stream);

  k_cos<<<29, 256, 0, stream>>>(cosT);
  k_dft2<<<B_, 256, 0, stream>>>(poses, cosT, freqbf);
  c_poses<<<dim3(SEED_, B_), 128, 0, stream>>>(poses, posespk);
  c_xinit<<<B_, 128, 0, stream>>>(poses, xcur, xpk);
  c_wcat<<<4096, 256, 0, stream>>>(gWih, gWhh, Wcat);
  c_bcat<<<16, 256, 0, stream>>>(gbih, gbhh, bcat);
  c_wpk<<<1728, 256, 0, stream>>>(Wcat, Wpk);
  c_w1pk<<<896, 256, 0, stream>>>(sW1, w1pk);
  c_w1par<<<63, 256, 0, stream>>>(sW1, w1par);
  c_bf<<<4096, 256, 0, stream>>>(preW, prebf, 1024*1024);
  c_bf<<<4096, 256, 0, stream>>>(outW, outbf, 1024*1024);
  c_bf<<<12288, 256, 0, stream>>>(inW, inbf, 3072*1024);
  c_fpwt<<<128, 256, 0, stream>>>(fpW, fpwt);
  k_bc<<<768, 256, 0, stream>>>(inW, inb, fpb, bc);

  // Wc = inproj @ fp_W  (3072 x 128, bf16)
  gemm64<<<dim3(48, 2), 256, 0, stream>>>(inbf, fpwt, 1024, nullptr, nullptr, nullptr, Wcbf, 128, 0);
  // qkv = freq @ Wc^T + bc  (15616 x 3072, bf16)
  gemm64<<<dim3(244, 48), 256, 0, stream>>>(freqbf, Wcbf, 128, bc, nullptr, nullptr, qkvbf, 3072, 0);
  k_attn<<<dim3(HEADS_, B_), 256, 0, stream>>>(qkvbf, ctxbf);
  // motion_ctx = ctx_mean @ outproj^T + outb
  gemm64<<<dim3(4, 16), 256, 0, stream>>>(ctxbf, outbf, 1024, outb, nullptr, motion, nullptr, 1024, 0);

  // encoder: cooperative, fence-free coherent h, 120 steps; final h -> hA, packed -> hpkA
  {
    const bf16* a0 = posespk; int a1 = 32768; int a2 = SEED_; int a3 = 1;
    const bf16* a4 = Wpk; const float* a5 = bcat;
    const float* a6 = hA; float* a7 = hA; bf16* a8 = nullptr;
    bf16* a9 = hpkA; bf16* a10 = hpkB; unsigned* a11 = prog;
    void* args[] = { &a0, &a1, &a2, &a3, &a4, &a5, &a6, &a7, &a8, &a9, &a10, &a11 };
    hipLaunchCooperativeKernel(reinterpret_cast<void*>(gru_wave), dim3(128), dim3(512),
                               args, 0, stream);
  }

  float* hc = hA;  float* hn = hB;
  bf16* hpc = hpkA; bf16* hpn = hpkB;
  unsigned* progS = prog + 128;
  unsigned* progP = prog + 256;

  // decoder: 24 steps x { gru_spl (SPL(t-1)+GRU(t)), gemm_pw (pre+W1) }; final SPL
  for (int t = 0; t < PRED_; ++t){
    gru_spl<<<128, 512, 0, stream>>>(xpk, Wpk, bcat, hc, hn, hbplain, hpc, hpn,
                                     hhpre, w1par, sW2, sb2, xcur, xpk, out, t, progS);
    { float* tf = hc; hc = hn; hn = tf; bf16* tb = hpc; hpc = hpn; hpn = tb; }
    gemm_pw<<<112, 512, 0, stream>>>(hbplain, prebf, preb, motion, hidpk, w1pk, sb1, hhpre, t, progP);
  }
  spl_all<<<64, 128, 0, stream>>>(hhpre, w1par, sW2, sb2, xcur, xpk, out, PRED_-1);
}

// Round 17
// 2781.066 us; speedup vs baseline: 1.5819x; 1.1159x over previous
//
#include <hip/hip_runtime.h>
#include <hip/hip_bf16.h>

typedef __hip_bfloat16 bf16;
typedef __attribute__((ext_vector_type(8))) short v8bf;     // 8 bf16 (4 VGPR)
typedef __attribute__((ext_vector_type(16))) float f32x16;
typedef __attribute__((ext_vector_type(4))) float f32x4;
typedef unsigned long long ull;

#define B_    256
#define SEED_ 120
#define PRED_ 24
#define D_    126
#define H_    1024
#define F_    61
#define HEADS_ 4
#define DH_   256

#define GLD16(lds, g) __builtin_amdgcn_global_load_lds( \
    (const __attribute__((address_space(1))) unsigned int*)(g), \
    (__attribute__((address_space(3))) unsigned int*)(lds), 16, 0, 0)
#define VMWAIT(n) asm volatile("s_waitcnt vmcnt(" #n ")" ::: "memory")
#define BARRIER() do { __builtin_amdgcn_s_barrier(); __builtin_amdgcn_sched_barrier(0); } while(0)
#define AL(P) __hip_atomic_load((P), __ATOMIC_RELAXED, __HIP_MEMORY_SCOPE_AGENT)

// ---------------- small precompute kernels ----------------
__global__ void k_cos(float* cosT){
  int i = blockIdx.x*256 + threadIdx.x;
  if (i < F_*SEED_){
    int f = i / SEED_, t = i % SEED_;
    int ph = (f*t) % SEED_;
    cosT[i] = cosf(6.283185307179586f * (float)ph / (float)SEED_);
  }
}

__global__ __launch_bounds__(256) void k_dft2(const float* __restrict__ poses,
                      const float* __restrict__ cosT, bf16* __restrict__ freqbf){
  __shared__ float pl[SEED_*128];      // 60 KB
  int b = blockIdx.x, tid = threadIdx.x;
  for (int i = tid; i < SEED_*D_; i += 256){
    int t = i / D_, d = i - t*D_;
    pl[t*128 + d] = poses[((size_t)b*(SEED_+PRED_) + t)*D_ + d];
  }
  __syncthreads();
  int d = tid & 127, f0 = tid >> 7;    // f = f0 + 2j
  float acc[31];
  #pragma unroll
  for (int j = 0; j < 31; ++j) acc[j] = 0.f;
  for (int t = 0; t < SEED_; ++t){
    float v = pl[t*128 + d];
    #pragma unroll
    for (int j = 0; j < 31; ++j){
      int f = f0 + j*2;
      if (f < F_) acc[j] += cosT[f*SEED_ + t] * v;
    }
  }
  #pragma unroll
  for (int j = 0; j < 31; ++j){
    int f = f0 + j*2;
    if (f < F_) freqbf[((size_t)b*F_ + f)*128 + d] = __float2bfloat16(d < D_ ? acc[j] : 0.f);
  }
}

// pack poses into per-step 32x32 tiles
__global__ void c_poses(const float* __restrict__ poses, bf16* __restrict__ pk){
  int t = blockIdx.x, b = blockIdx.y, c = threadIdx.x;  // block 128
  float v = (c < D_) ? poses[((size_t)b*(SEED_+PRED_) + t)*D_ + c] : 0.f;
  pk[(size_t)t*32768 + ((b>>5)*4 + (c>>5))*1024 + (b&31)*32 + (c&31)] = __float2bfloat16(v);
}

__global__ void c_xinit(const float* __restrict__ poses, float* __restrict__ x, bf16* __restrict__ xpk){
  int b = blockIdx.x, c = threadIdx.x;  // block 128
  float v = (c < D_) ? poses[((size_t)b*(SEED_+PRED_) + (SEED_-1))*D_ + c] : 0.f;
  if (c < D_) x[b*D_ + c] = v;
  xpk[((b>>5)*4 + (c>>5))*1024 + (b&31)*32 + (c&31)] = __float2bfloat16(v);
}

__global__ void c_bf(const float* __restrict__ s, bf16* __restrict__ d, int n){
  int i = blockIdx.x*256 + threadIdx.x;
  if (i < n) d[i] = __float2bfloat16(s[i]);
}

__global__ void c_fpwt(const float* __restrict__ fpW, bf16* __restrict__ o){
  int dd = blockIdx.x;                       // 0..127
  for (int k = threadIdx.x; k < H_; k += 256)
    o[(size_t)dd*H_ + k] = __float2bfloat16(dd < D_ ? fpW[(size_t)k*D_ + dd] : 0.f);
}

// combined GRU weight rows (1152 wide: 128 x-cols | 1024 h-cols)
__global__ void c_wcat(const float* __restrict__ Wih, const float* __restrict__ Whh, bf16* __restrict__ o){
  int r = blockIdx.x;
  int jr; bool hasx, hash;
  if (r < 2048){ jr = r; hasx = true; hash = true; }
  else if (r < 3072){ jr = r; hasx = true; hash = false; }
  else { jr = r - 1024; hasx = false; hash = true; }
  bf16* row = o + (size_t)r*1152;
  for (int c = threadIdx.x; c < 1152; c += 256){
    float v = 0.f;
    if (c < D_) { if (hasx) v = Wih[(size_t)jr*D_ + c]; }
    else if (c >= 128){ if (hash) v = Whh[(size_t)jr*H_ + (c-128)]; }
    row[c] = __float2bfloat16(v);
  }
}

__global__ void c_bcat(const float* __restrict__ bih, const float* __restrict__ bhh, float* __restrict__ o){
  int r = blockIdx.x*256 + threadIdx.x;
  if (r >= 4096) return;
  float v;
  if (r < 2048) v = bih[r] + bhh[r];
  else if (r < 3072) v = bih[r];
  else v = bhh[r - 1024];
  o[r] = v;
}

// pack GRU weights into MFMA B-fragment order
__global__ __launch_bounds__(256) void c_wpk(const bf16* __restrict__ Wcat, bf16* __restrict__ Wpk){
  int chunk = blockIdx.x*4 + (threadIdx.x >> 6);
  int l = threadIdx.x & 63;
  int ks = chunk % 36; int t2 = chunk / 36; int g = t2 % 3; int ub = t2 / 3;
  int unit = ub*16 + (l & 15);
  bf16* dst = Wpk + (size_t)chunk*512 + l*8;
  #pragma unroll
  for (int e = 0; e < 8; ++e){
    int k = ks*32 + (l>>4)*8 + e;
    int row = (g==0) ? unit : (g==1) ? (1024+unit) : (k < 128 ? 2048+unit : 3072+unit);
    dst[e] = Wcat[(size_t)row*1152 + k];
  }
}

// pack W1-hid into fragment order: chunk = ug*32+ks, ug 0..111
__global__ __launch_bounds__(256) void c_w1pk(const float* __restrict__ sW1, bf16* __restrict__ w1pk){
  int chunk = blockIdx.x*4 + (threadIdx.x >> 6);   // 3584 chunks
  int l = threadIdx.x & 63;
  int ks = chunk & 31, ng = chunk >> 5;
  int unit = ng*16 + (l & 15);
  int j = unit >> 7, rr = unit & 127;
  bf16* dst = w1pk + (size_t)chunk*512 + l*8;
  #pragma unroll
  for (int e = 0; e < 8; ++e){
    int k = ks*32 + (l>>4)*8 + e;
    dst[e] = __float2bfloat16(sW1[((size_t)j*128 + rr)*1033 + k]);
  }
}

// pack SPL parent weights
__global__ void c_w1par(const float* __restrict__ sW1, float* __restrict__ w1par){
  int i = blockIdx.x*256 + threadIdx.x;
  if (i < 14*9*128){
    int j = i / (9*128); int rem = i % (9*128); int ii = rem / 128; int th = rem % 128;
    w1par[i] = sW1[((size_t)(j*128 + th))*1033 + 1024 + ii];
  }
}

// bc = inproj @ fp_b + in_b
__global__ __launch_bounds__(256) void k_bc(const float* __restrict__ inW, const float* __restrict__ inb,
                     const float* __restrict__ fpb, float* __restrict__ bc){
  int wave = threadIdx.x >> 6, lane = threadIdx.x & 63;
  int r = blockIdx.x*4 + wave;
  const float4* row = (const float4*)(inW + (size_t)r*H_);
  const float4* fp4 = (const float4*)fpb;
  float s = 0.f;
  #pragma unroll
  for (int i = 0; i < 4; ++i){
    float4 a = row[lane + i*64];
    float4 b = fp4[lane + i*64];
    s += a.x*b.x + a.y*b.y + a.z*b.z + a.w*b.w;
  }
  #pragma unroll
  for (int off = 32; off; off >>= 1) s += __shfl_down(s, off);
  if (lane == 0) bc[r] = s + inb[r];
}

// ---------------- encoder: wave-autonomous GRU, 256 blocks x 4 waves ----------------
// grid 256 = 64 unit-slices (ub) x 4 batch quarters (q); block 256 (4 waves x 16 rows).
// Weights LDS-resident (108KB, 1 block/CU -> all 256 CUs). h via relaxed IF atomics;
// per-quarter flag sync (producers of a quarter's rows == its readers -> 2-buf safe).
#define SLCP(QA, QB, KS, GACC) { \
  union { ull u[2]; v8bf v; } cc_; cc_.u[0]=(QA); cc_.u[1]=(QB); \
  v8bf a_ = cc_.v; \
  v8bf w0_ = *(const v8bf*)&Wl[(0*36+(KS))*512 + lane*8]; \
  v8bf w1_ = *(const v8bf*)&Wl[(1*36+(KS))*512 + lane*8]; \
  v8bf w2_ = *(const v8bf*)&Wl[(2*36+(KS))*512 + lane*8]; \
  aR = __builtin_amdgcn_mfma_f32_16x16x32_bf16(a_, w0_, aR, 0,0,0); \
  aZ = __builtin_amdgcn_mfma_f32_16x16x32_bf16(a_, w1_, aZ, 0,0,0); \
  GACC = __builtin_amdgcn_mfma_f32_16x16x32_bf16(a_, w2_, GACC, 0,0,0); }

#define LDHA(DA, DB, C) { \
  const ull* hp_ = (const ull*)(hs + hbase + (size_t)(C)*1024); \
  DA = AL(hp_); DB = AL(hp_+1); }

#define LDXP(DA, DB, TT, C) { \
  const ull* xp_ = (const ull*)(xpk + (size_t)(TT)*xstride + xbase + (size_t)(C)*1024); \
  DA = xp_[0]; DB = xp_[1]; }

__global__ __launch_bounds__(256) void gru_wave(
    const bf16* __restrict__ xpk, int xstride, int nsteps, int coop,
    const bf16* __restrict__ Wpk, const float* __restrict__ bcat,
    const float* __restrict__ hin_plain, float* __restrict__ hout_plain,
    bf16* __restrict__ hbplain,
    bf16* __restrict__ hpk0, bf16* __restrict__ hpk1,
    unsigned* __restrict__ prog)
{
  __shared__ bf16 Wl[3*36*512];       // 108 KB
  const int tid = threadIdx.x, wave = tid >> 6, lane = tid & 63;
  const int ub = blockIdx.x & 63, q = blockIdx.x >> 6;
  const int u0 = ub*16;

  {
    const bf16* wsrc = Wpk + (size_t)ub*(3*36*512);
    #pragma unroll
    for (int i = 0; i < 27; ++i){
      int c = i*256 + tid;
      GLD16(&Wl[c*8], wsrc + (size_t)c*8);
    }
  }
  VMWAIT(0); BARRIER();

  const int la = lane & 15, lb = lane >> 4;
  const int r0 = q*64 + wave*16;
  const int rb = r0 >> 5, y = wave & 1;
  const int ucol = u0 + la;
  const float bR = bcat[ucol], bZ = bcat[1024+ucol], bI = bcat[2048+ucol], bN = bcat[3072+ucol];
  const size_t hbase = (size_t)rb*32768 + (size_t)y*512 + la*32 + lb*8;
  const size_t xbase = (size_t)rb*4096  + (size_t)y*512 + la*32 + lb*8;
  const size_t pwb = (size_t)rb*32768 + (size_t)(u0>>5)*1024 + (size_t)y*512 + (u0&16) + la;

  float hr[4];
  if (nsteps == 1){
    #pragma unroll
    for (int r = 0; r < 4; ++r) hr[r] = hin_plain[(size_t)(r0 + lb*4 + r)*1024 + ucol];
  } else {
    #pragma unroll
    for (int r = 0; r < 4; ++r) hr[r] = 0.f;
  }

  ull a0,a1,a2,a3,a4,a5,a6,a7,a8,a9,a10,a11;
  ull b0,b1,b2,b3,b4,b5,b6,b7,b8,b9,b10,b11;
  LDXP(a0,b0,0,0); LDXP(a1,b1,0,1); LDXP(a2,b2,0,2); LDXP(a3,b3,0,3);

  for (int t = 0; t < nsteps; ++t){
    if (coop && t > 0){
      if (wave == 0){
        unsigned v = AL(&prog[q*64 + lane]);
        while (__ballot(v >= (unsigned)t) != ~0ULL){
          __builtin_amdgcn_s_sleep(1);
          v = AL(&prog[q*64 + lane]);
        }
      }
      __syncthreads();
      __builtin_amdgcn_sched_barrier(0);
    }
    const bf16* hs = (t & 1) ? hpk1 : hpk0;
    LDHA(a4,b4,0) LDHA(a5,b5,1) LDHA(a6,b6,2) LDHA(a7,b7,3)
    LDHA(a8,b8,4) LDHA(a9,b9,5) LDHA(a10,b10,6) LDHA(a11,b11,7)

    f32x4 z4 = {0.f,0.f,0.f,0.f};
    f32x4 aR = z4, aZ = z4, aI = z4, aN = z4;

    SLCP(a0,b0,0,aI)  LDHA(a0,b0,8)
    SLCP(a1,b1,1,aI)  LDHA(a1,b1,9)
    SLCP(a2,b2,2,aI)  LDHA(a2,b2,10)
    SLCP(a3,b3,3,aI)  LDHA(a3,b3,11)
    SLCP(a4,b4,4,aN)  LDHA(a4,b4,12)
    SLCP(a5,b5,5,aN)  LDHA(a5,b5,13)
    SLCP(a6,b6,6,aN)  LDHA(a6,b6,14)
    SLCP(a7,b7,7,aN)  LDHA(a7,b7,15)
    SLCP(a8,b8,8,aN)  LDHA(a8,b8,16)
    SLCP(a9,b9,9,aN)  LDHA(a9,b9,17)
    SLCP(a10,b10,10,aN) LDHA(a10,b10,18)
    SLCP(a11,b11,11,aN) LDHA(a11,b11,19)
    SLCP(a0,b0,12,aN) LDHA(a0,b0,20)
    SLCP(a1,b1,13,aN) LDHA(a1,b1,21)
    SLCP(a2,b2,14,aN) LDHA(a2,b2,22)
    SLCP(a3,b3,15,aN) LDHA(a3,b3,23)
    SLCP(a4,b4,16,aN) LDHA(a4,b4,24)
    SLCP(a5,b5,17,aN) LDHA(a5,b5,25)
    SLCP(a6,b6,18,aN) LDHA(a6,b6,26)
    SLCP(a7,b7,19,aN) LDHA(a7,b7,27)
    SLCP(a8,b8,20,aN) LDHA(a8,b8,28)
    SLCP(a9,b9,21,aN) LDHA(a9,b9,29)
    SLCP(a10,b10,22,aN) LDHA(a10,b10,30)
    SLCP(a11,b11,23,aN) LDHA(a11,b11,31)
    SLCP(a0,b0,24,aN) LDXP(a0,b0,t+1,0)
    SLCP(a1,b1,25,aN) LDXP(a1,b1,t+1,1)
    SLCP(a2,b2,26,aN) LDXP(a2,b2,t+1,2)
    SLCP(a3,b3,27,aN) LDXP(a3,b3,t+1,3)
    SLCP(a4,b4,28,aN)
    SLCP(a5,b5,29,aN)
    SLCP(a6,b6,30,aN)
    SLCP(a7,b7,31,aN)
    SLCP(a8,b8,32,aN)
    SLCP(a9,b9,33,aN)
    SLCP(a10,b10,34,aN)
    SLCP(a11,b11,35,aN)

    bf16* hd = (t & 1) ? hpk0 : hpk1;
    const bool last = (t == nsteps-1);
    #pragma unroll
    for (int r = 0; r < 4; ++r){
      float rg = 1.f/(1.f + __expf(-(aR[r] + bR)));
      float zg = 1.f/(1.f + __expf(-(aZ[r] + bZ)));
      float ng = tanhf((aI[r] + bI) + rg*(aN[r] + bN));
      float hv = (1.f - zg)*ng + zg*hr[r];
      hr[r] = hv;
      bf16 hv16 = __float2bfloat16(hv);
      unsigned short hbits = *(unsigned short*)&hv16;
      __hip_atomic_store((unsigned short*)(hd + pwb + (size_t)(lb*4 + r)*32), hbits,
                         __ATOMIC_RELAXED, __HIP_MEMORY_SCOPE_AGENT);
      if (last){
        hout_plain[(size_t)(r0 + lb*4 + r)*1024 + ucol] = hv;
        if (hbplain) hbplain[(size_t)(r0 + lb*4 + r)*1024 + ucol] = __float2bfloat16(hv);
      }
    }
    if (coop && t + 1 < nsteps){
      VMWAIT(0);
      __syncthreads();
      if (tid == 0)
        __hip_atomic_store(&prog[q*64 + ub], (unsigned)(t+1), __ATOMIC_RELAXED, __HIP_MEMORY_SCOPE_AGENT);
    }
  }
}

// ---------------- decoder GRU with fused SPL(t-1) prologue (R16, unchanged) ----------------
__constant__ int LVJ[14] = {0,1,6,8,9, 2,3,7,10,11, 4,5,12,13};
__constant__ int LVO[4]  = {0,5,10,14};
__constant__ int PAR_[14] = {-1,-1,0,1,2,3,-1,6,-1,-1,8,9,10,11};

#define DGRL(S,C) { const ull* p_=(const ull*)(hspk + hbase + (size_t)(C)*1024); qa##S=AL(p_); qb##S=AL(p_+1); }
#define DGXL(S,C) { const ull* p_=(const ull*)(xpk + xbase + (size_t)(C)*1024); qa##S=AL(p_); qb##S=AL(p_+1); }
#define DGRC(S,KS,GACC) { union{ull u[2];v8bf v;}c_; c_.u[0]=qa##S;c_.u[1]=qb##S; v8bf a_=c_.v; \
  v8bf w0_=*(const v8bf*)&Wl[(KS)*512+lane*8]; \
  v8bf w1_=*(const v8bf*)&Wl[18432+(KS)*512+lane*8]; \
  v8bf w2_=*(const v8bf*)&Wl[36864+(KS)*512+lane*8]; \
  aR=__builtin_amdgcn_mfma_f32_16x16x32_bf16(a_,w0_,aR,0,0,0); \
  aZ=__builtin_amdgcn_mfma_f32_16x16x32_bf16(a_,w1_,aZ,0,0,0); \
  GACC=__builtin_amdgcn_mfma_f32_16x16x32_bf16(a_,w2_,GACC,0,0,0); }

__global__ __launch_bounds__(512) void gru_spl(
    const bf16* __restrict__ xpk, const bf16* __restrict__ Wpk,
    const float* __restrict__ bcat,
    const float* __restrict__ hin_plain, float* __restrict__ hout_plain,
    bf16* __restrict__ hbplain,
    const bf16* __restrict__ hspk, bf16* __restrict__ hdpk,
    const float* __restrict__ hhpre, const float* __restrict__ w1par,
    const float* __restrict__ sW2, const float* __restrict__ sb2,
    float* __restrict__ xcur, bf16* __restrict__ xpkw, float* __restrict__ out,
    int dt, unsigned* __restrict__ progS)
{
  __shared__ bf16 Wl[3*36*512];     // 108 KB
  __shared__ float hhl[2][1792];    // 14 KB
  __shared__ float preds_s[2][128];
  __shared__ float hh_s[128][2];
  const int tid = threadIdx.x, wave = tid >> 6, lane = tid & 63;
  const int bid = blockIdx.x;
  const int ub = bid >> 1, bs = bid & 1, u0 = ub*16;

  {  // weights -> LDS (async, overlaps SPL)
    const bf16* wsrc = Wpk + (size_t)ub*(3*36*512);
    #pragma unroll
    for (int i = 0; i < 14; ++i){ int c = i*512 + tid; if (c < 6912) GLD16(&Wl[c*8], wsrc + (size_t)c*8); }
  }

  // ---- SPL of previous step (regular loads; coherent via launch boundary) ----
  const int b0s = bid*2, th = tid;
  if (dt > 0){
    for (int i = tid; i < 2*1792; i += 512){
      int bb = i / 1792, col = i - bb*1792;
      hhl[bb][col] = hhpre[(size_t)(b0s+bb)*1792 + col];
    }
    __syncthreads();
    for (int L = 0; L < 3; ++L){
      for (int ji = LVO[L]; ji < LVO[L+1]; ++ji){
        int j = LVJ[ji], p = PAR_[j];
        if (tid < 128){
          float a0s = hhl[0][j*128 + th], a1s = hhl[1][j*128 + th];
          if (p >= 0){
            #pragma unroll
            for (int ii = 0; ii < 9; ++ii){
              float w = w1par[(j*9 + ii)*128 + th];
              a0s += w * preds_s[0][p*9 + ii];
              a1s += w * preds_s[1][p*9 + ii];
            }
          }
          hh_s[th][0] = fmaxf(a0s, 0.f);
          hh_s[th][1] = fmaxf(a1s, 0.f);
        }
        __syncthreads();
        if (tid < 36){
          int pp = th >> 1, half = th & 1;
          int bb = pp/9, oi = pp%9;
          const float4* w4 = (const float4*)(sW2 + (size_t)(j*9 + oi)*128 + half*64);
          float s = 0.f;
          #pragma unroll
          for (int q2 = 0; q2 < 16; ++q2){
            float4 wv = w4[q2];
            s += hh_s[half*64 + q2*4 + 0][bb]*wv.x + hh_s[half*64 + q2*4 + 1][bb]*wv.y
               + hh_s[half*64 + q2*4 + 2][bb]*wv.z + hh_s[half*64 + q2*4 + 3][bb]*wv.w;
          }
          s += __shfl_xor(s, 1);
          if (half == 0) preds_s[bb][j*9 + oi] = tanhf(s + sb2[j*9 + oi]);
        }
        __syncthreads();
      }
    }
    if (tid < 128){
      for (int i = th; i < 2*D_; i += 128){
        int bb = i / D_, d = i % D_;
        int row = b0s + bb;
        size_t xi = (size_t)row*D_ + d;
        float v = xcur[xi] + preds_s[bb][d];
        xcur[xi] = v;
        bf16 v16 = __float2bfloat16(v);
        __hip_atomic_store((unsigned short*)(xpkw + ((size_t)(row>>5)*4 + (d>>5))*1024 + (row&31)*32 + (d&31)),
                           *(unsigned short*)&v16, __ATOMIC_RELAXED, __HIP_MEMORY_SCOPE_AGENT);
        out[((size_t)row*PRED_ + (dt-1))*D_ + d] = v;
      }
    }
    VMWAIT(0);
    __syncthreads();
    if (tid == 0)
      __hip_atomic_store(&progS[bid], (unsigned)dt, __ATOMIC_RELAXED, __HIP_MEMORY_SCOPE_AGENT);
  }

  VMWAIT(0); BARRIER();     // weights resident

  const int la = lane & 15, lb = lane >> 4;
  const int r0 = bs*128 + wave*16;
  const int rb = r0 >> 5, y = wave & 1;
  const int ucol = u0 + la;
  const float bR = bcat[ucol], bZ = bcat[1024+ucol], bI = bcat[2048+ucol], bN = bcat[3072+ucol];
  const size_t hbase = (size_t)rb*32768 + (size_t)y*512 + la*32 + lb*8;
  const size_t xbase = (size_t)rb*4096  + (size_t)y*512 + la*32 + lb*8;
  const size_t pwb = (size_t)rb*32768 + (size_t)(u0>>5)*1024 + (size_t)y*512 + (u0&16) + la;

  float hr[4];
  #pragma unroll
  for (int r = 0; r < 4; ++r) hr[r] = hin_plain[(size_t)(r0 + lb*4 + r)*1024 + ucol];

  ull qa0,qa1,qa2,qa3,qa4,qa5,qa6,qa7,qa8,qa9,qa10,qa11;
  ull qb0,qb1,qb2,qb3,qb4,qb5,qb6,qb7,qb8,qb9,qb10,qb11;

  // h-slices first (depend only on h^t)
  DGRL(0,0) DGRL(1,1) DGRL(2,2) DGRL(3,3) DGRL(4,4) DGRL(5,5)
  DGRL(6,6) DGRL(7,7) DGRL(8,8) DGRL(9,9) DGRL(10,10) DGRL(11,11)
  f32x4 z4 = {0.f,0.f,0.f,0.f};
  f32x4 aR = z4, aZ = z4, aI = z4, aN = z4;
  DGRC(0,4,aN)  DGRL(0,12)
  DGRC(1,5,aN)  DGRL(1,13)
  DGRC(2,6,aN)  DGRL(2,14)
  DGRC(3,7,aN)  DGRL(3,15)
  DGRC(4,8,aN)  DGRL(4,16)
  DGRC(5,9,aN)  DGRL(5,17)
  DGRC(6,10,aN) DGRL(6,18)
  DGRC(7,11,aN) DGRL(7,19)
  DGRC(8,12,aN) DGRL(8,20)
  DGRC(9,13,aN) DGRL(9,21)
  DGRC(10,14,aN) DGRL(10,22)
  DGRC(11,15,aN) DGRL(11,23)
  DGRC(0,16,aN) DGRL(0,24)
  DGRC(1,17,aN) DGRL(1,25)
  DGRC(2,18,aN) DGRL(2,26)
  DGRC(3,19,aN) DGRL(3,27)
  DGRC(4,20,aN) DGRL(4,28)
  DGRC(5,21,aN) DGRL(5,29)
  DGRC(6,22,aN) DGRL(6,30)
  DGRC(7,23,aN) DGRL(7,31)
  DGRC(8,24,aN)
  DGRC(9,25,aN)
  DGRC(10,26,aN)
  DGRC(11,27,aN)
  DGRC(0,28,aN)
  DGRC(1,29,aN)
  DGRC(2,30,aN)
  DGRC(3,31,aN)
  DGRC(4,32,aN)
  DGRC(5,33,aN)
  DGRC(6,34,aN)
  DGRC(7,35,aN)
  if (dt > 0){
    if (wave == 0){
      unsigned v1 = AL(&progS[lane]), v2 = AL(&progS[64 + lane]);
      while (__ballot((v1 >= (unsigned)dt) && (v2 >= (unsigned)dt)) != ~0ULL){
        __builtin_amdgcn_s_sleep(2);
        v1 = AL(&progS[lane]); v2 = AL(&progS[64 + lane]);
      }
    }
    __syncthreads();
    __builtin_amdgcn_sched_barrier(0);
  }
  DGXL(8,0) DGXL(9,1) DGXL(10,2) DGXL(11,3)
  DGRC(8,0,aI)
  DGRC(9,1,aI)
  DGRC(10,2,aI)
  DGRC(11,3,aI)
  #pragma unroll
  for (int r = 0; r < 4; ++r){
    float rg = 1.f/(1.f + __expf(-(aR[r] + bR)));
    float zg = 1.f/(1.f + __expf(-(aZ[r] + bZ)));
    float ng = tanhf((aI[r] + bI) + rg*(aN[r] + bN));
    float hv = (1.f - zg)*ng + zg*hr[r];
    bf16 hv16 = __float2bfloat16(hv);
    __hip_atomic_store((unsigned short*)(hdpk + pwb + (size_t)(lb*4 + r)*32),
                       *(unsigned short*)&hv16, __ATOMIC_RELAXED, __HIP_MEMORY_SCOPE_AGENT);
    hout_plain[(size_t)(r0 + lb*4 + r)*1024 + ucol] = hv;
    hbplain[(size_t)(r0 + lb*4 + r)*1024 + ucol] = hv16;
  }
}

// ---------------- fused pre + W1 (R16, unchanged) ----------------
#define W1L(S,C) { const ull* p_=(const ull*)(hidpk + w1abase + (size_t)(C)*1024); \
  qa##S=AL(p_); qb##S=AL(p_+1); \
  bq##S = *(const uint4*)(w1b0 + (size_t)(C)*512 + lane*8); \
  br##S = *(const uint4*)(w1b1 + (size_t)(C)*512 + lane*8); }
#define W1C(S) { union{ull u[2];v8bf v;}x_; x_.u[0]=qa##S;x_.u[1]=qb##S; \
  union{uint4 q; v8bf v;}b0_,b1_; b0_.q=bq##S; b1_.q=br##S; \
  c0=__builtin_amdgcn_mfma_f32_16x16x32_bf16(x_.v,b0_.v,c0,0,0,0); \
  c1=__builtin_amdgcn_mfma_f32_16x16x32_bf16(x_.v,b1_.v,c1,0,0,0); }

__global__ __launch_bounds__(512) void gemm_pw(
    const bf16* __restrict__ hb, const bf16* __restrict__ prebf,
    const float* __restrict__ preb, const float* __restrict__ motion,
    bf16* __restrict__ hidpk, const bf16* __restrict__ w1pk,
    const float* __restrict__ sb1, float* __restrict__ hhpre,
    int dt, unsigned* __restrict__ progP)
{
  __shared__ bf16 As[3][64*64];
  __shared__ bf16 Bs[3][64*64];
  const int tid = threadIdx.x, wave = tid >> 6, lane = tid & 63;
  const int bid = blockIdx.x;
  const int la = lane & 15, lb = lane >> 4;

  // ---------- phase A: pre (blocks 0..63) ----------
  if (bid < 64){
    const int m0 = (bid & 3)*64, n0 = (bid >> 2)*64;
    const int fr = lane & 31, kh = lane >> 5;
    const int wm = (wave >> 1)*32, wn = (wave & 1)*32;
    f32x16 acc = {0.f,0.f,0.f,0.f,0.f,0.f,0.f,0.f,0.f,0.f,0.f,0.f,0.f,0.f,0.f,0.f};

    auto STAGE = [&](int buf, int kt){
      if (tid < 256){
        #pragma unroll
        for (int q2 = 0; q2 < 2; ++q2){
          int idx = q2*256 + tid;
          int row = idx >> 3, cp = idx & 7, csw = cp ^ (row & 7);
          GLD16(&As[buf][idx*8], hb + (size_t)(m0+row)*1024 + kt*64 + csw*8);
        }
        #pragma unroll
        for (int q2 = 0; q2 < 2; ++q2){
          int idx = q2*256 + tid;
          int row = idx >> 3, cp = idx & 7, csw = cp ^ (row & 7);
          GLD16(&Bs[buf][idx*8], prebf + (size_t)(n0+row)*1024 + kt*64 + csw*8);
        }
      }
    };
    auto COMPUTE = [&](int buf){
      if (wave < 4){
        const bf16* Ab = &As[buf][0];
        const bf16* Bb = &Bs[buf][0];
        #pragma unroll
        for (int ks = 0; ks < 4; ++ks){
          int ca = ks*2 + kh;
          v8bf av = *(const v8bf*)&Ab[(wm+fr)*64 + ((ca ^ ((wm+fr)&7))*8)];
          v8bf bv = *(const v8bf*)&Bb[(wn+fr)*64 + ((ca ^ ((wn+fr)&7))*8)];
          acc = __builtin_amdgcn_mfma_f32_32x32x16_bf16(av, bv, acc, 0, 0, 0);
        }
      }
    };

    STAGE(0, 0); STAGE(1, 1);
    VMWAIT(4); BARRIER();
    for (int kt = 0; kt < 16; ++kt){
      if (kt + 2 < 16) STAGE((kt+2)%3, kt+2);
      COMPUTE(kt%3);
      if (kt + 2 < 16){ VMWAIT(4); BARRIER(); }
      else if (kt + 1 < 16){ VMWAIT(0); BARRIER(); }
    }
    if (wave < 4){
      const int col = n0 + wn + fr;
      const float bb2 = preb[col];
      #pragma unroll
      for (int r = 0; r < 16; ++r){
        int row = m0 + wm + (r&3) + 8*(r>>2) + 4*kh;
        float v = fmaxf(acc[r] + bb2, 0.f) + motion[(size_t)row*1024 + col];
        bf16 v16 = __float2bfloat16(v);
        __hip_atomic_store((unsigned short*)(hidpk + ((size_t)(row>>5)*32 + (col>>5))*1024 + (row&31)*32 + (col&31)),
                           *(unsigned short*)&v16, __ATOMIC_RELAXED, __HIP_MEMORY_SCOPE_AGENT);
      }
    }
    VMWAIT(0);
    __syncthreads();
    if (tid == 0)
      __hip_atomic_store(&progP[bid], (unsigned)(dt+1), __ATOMIC_RELAXED, __HIP_MEMORY_SCOPE_AGENT);
  }

  // ---------- wait for all pre flags ----------
  if (wave == 0){
    unsigned v = AL(&progP[lane]);
    while (__ballot(v >= (unsigned)(dt+1)) != ~0ULL){
      __builtin_amdgcn_s_sleep(2);
      v = AL(&progP[lane]);
    }
  }
  __syncthreads();
  __builtin_amdgcn_sched_barrier(0);

  // ---------- phase B: W1 (all 112 blocks) ----------
  const int mq = bid / 28, ng = bid % 28;
  const int mg = wave >> 1, nc = wave & 1;
  const int r0w = mq*64 + mg*16;
  const int w1rb = r0w >> 5, w1y = mg & 1;
  const size_t w1abase = (size_t)w1rb*32768 + (size_t)w1y*512 + la*32 + lb*8;
  const int ug0 = ng*4 + nc*2, ug1 = ug0 + 1;
  const bf16* w1b0 = w1pk + (size_t)ug0*(32*512);
  const bf16* w1b1 = w1pk + (size_t)ug1*(32*512);
  const float sb1a = sb1[ug0*16 + la];
  const float sb1b = sb1[ug1*16 + la];

  ull qa0,qa1,qa2,qa3,qa4,qa5;
  ull qb0,qb1,qb2,qb3,qb4,qb5;
  uint4 bq0,bq1,bq2,bq3,bq4,bq5;
  uint4 br0,br1,br2,br3,br4,br5;

  W1L(0,0) W1L(1,1) W1L(2,2) W1L(3,3) W1L(4,4) W1L(5,5)
  f32x4 c0 = {0.f,0.f,0.f,0.f}, c1 = c0;
  W1C(0) W1L(0,6)
  W1C(1) W1L(1,7)
  W1C(2) W1L(2,8)
  W1C(3) W1L(3,9)
  W1C(4) W1L(4,10)
  W1C(5) W1L(5,11)
  W1C(0) W1L(0,12)
  W1C(1) W1L(1,13)
  W1C(2) W1L(2,14)
  W1C(3) W1L(3,15)
  W1C(4) W1L(4,16)
  W1C(5) W1L(5,17)
  W1C(0) W1L(0,18)
  W1C(1) W1L(1,19)
  W1C(2) W1L(2,20)
  W1C(3) W1L(3,21)
  W1C(4) W1L(4,22)
  W1C(5) W1L(5,23)
  W1C(0) W1L(0,24)
  W1C(1) W1L(1,25)
  W1C(2) W1L(2,26)
  W1C(3) W1L(3,27)
  W1C(4) W1L(4,28)
  W1C(5) W1L(5,29)
  W1C(0) W1L(0,30)
  W1C(1) W1L(1,31)
  W1C(2)
  W1C(3)
  W1C(4)
  W1C(5)
  W1C(0)
  W1C(1)
  #pragma unroll
  for (int r = 0; r < 4; ++r){
    int row = r0w + lb*4 + r;
    hhpre[(size_t)row*1792 + ug0*16 + la] = c0[r] + sb1a;
    hhpre[(size_t)row*1792 + ug1*16 + la] = c1[r] + sb1b;
  }
}

// ---------------- pipelined generic GEMM (preamble only) ----------------
__global__ __launch_bounds__(256) void gemm64(
    const bf16* __restrict__ Am, const bf16* __restrict__ Bm, int K,
    const float* __restrict__ bias, const float* __restrict__ addmat,
    float* __restrict__ C, bf16* __restrict__ Cbf, int N, int MODE)
{
  __shared__ bf16 As[3][64*64];
  __shared__ bf16 Bs[3][64*64];
  const int tid = threadIdx.x;
  const int wave = tid >> 6, lane = tid & 63;
  const int m0 = blockIdx.x*64, n0 = blockIdx.y*64;
  const int fr = lane & 31, kh = lane >> 5;
  const int wm = (wave >> 1)*32, wn = (wave & 1)*32;
  const int KT = K >> 6;

  f32x16 acc = {0.f,0.f,0.f,0.f,0.f,0.f,0.f,0.f,0.f,0.f,0.f,0.f,0.f,0.f,0.f,0.f};

  auto STAGE = [&](int buf, int kt){
    #pragma unroll
    for (int q = 0; q < 2; ++q){
      int idx = q*256 + tid;
      int row = idx >> 3, cp = idx & 7, csw = cp ^ (row & 7);
      GLD16(&As[buf][idx*8], Am + (size_t)(m0+row)*K + kt*64 + csw*8);
    }
    #pragma unroll
    for (int q = 0; q < 2; ++q){
      int idx = q*256 + tid;
      int row = idx >> 3, cp = idx & 7, csw = cp ^ (row & 7);
      GLD16(&Bs[buf][idx*8], Bm + (size_t)(n0+row)*K + kt*64 + csw*8);
    }
  };
  auto COMPUTE = [&](int buf){
    const bf16* Ab = &As[buf][0];
    const bf16* Bb = &Bs[buf][0];
    #pragma unroll
    for (int ks = 0; ks < 4; ++ks){
      int ca = ks*2 + kh;
      v8bf av = *(const v8bf*)&Ab[(wm+fr)*64 + ((ca ^ ((wm+fr)&7))*8)];
      v8bf bv = *(const v8bf*)&Bb[(wn+fr)*64 + ((ca ^ ((wn+fr)&7))*8)];
      acc = __builtin_amdgcn_mfma_f32_32x32x16_bf16(av, bv, acc, 0, 0, 0);
    }
  };

  STAGE(0, 0);
  if (KT > 1){ STAGE(1, 1); VMWAIT(4); } else { VMWAIT(0); }
  BARRIER();
  for (int kt = 0; kt < KT; ++kt){
    if (kt + 2 < KT) STAGE((kt+2)%3, kt+2);
    COMPUTE(kt%3);
    if (kt + 2 < KT){ VMWAIT(4); BARRIER(); }
    else if (kt + 1 < KT){ VMWAIT(0); BARRIER(); }
  }

  const int col = n0 + wn + fr;
  float bb = bias ? bias[col] : 0.f;
  #pragma unroll
  for (int r = 0; r < 16; ++r){
    int row = m0 + wm + (r&3) + 8*(r>>2) + 4*kh;
    float v = acc[r] + bb;
    if (MODE == 1) v = fmaxf(v, 0.f) + addmat[(size_t)row*N + col];
    if (C)   C[(size_t)row*N + col] = v;
    if (Cbf) Cbf[(size_t)row*N + col] = __float2bfloat16(v);
  }
}

// ---------------- attention: one block per (b,h) ----------------
__global__ __launch_bounds__(256) void k_attn(const bf16* __restrict__ qkv,
                                              bf16* __restrict__ ctxbf){
  __shared__ char smem[65536];
  bf16* qs = (bf16*)smem;
  bf16* ks = qs + 64*256;
  float* sc = (float*)smem;
  float* cs = (float*)(smem + 32768);
  const int h = blockIdx.x, b = blockIdx.y;
  const int tid = threadIdx.x, wave = tid >> 6, lane = tid & 63;
  const int fr = lane & 31, kh = lane >> 5;
  const int wm = (wave >> 1)*32, wn = (wave & 1)*32;

  #pragma unroll
  for (int i = 0; i < 8; ++i){
    int idx = i*256 + tid;
    int row = idx >> 5, cp = idx & 31, csw = cp ^ (row & 7);
    GLD16(&qs[idx*8], qkv + (size_t)(b*F_ + row)*3072 + h*DH_ + csw*8);
  }
  #pragma unroll
  for (int i = 0; i < 8; ++i){
    int idx = i*256 + tid;
    int row = idx >> 5, cp = idx & 31, csw = cp ^ (row & 7);
    GLD16(&ks[idx*8], qkv + (size_t)(b*F_ + row)*3072 + H_ + h*DH_ + csw*8);
  }
  __syncthreads();

  f32x16 acc = {0.f,0.f,0.f,0.f,0.f,0.f,0.f,0.f,0.f,0.f,0.f,0.f,0.f,0.f,0.f,0.f};
  #pragma unroll
  for (int i = 0; i < 16; ++i){
    int ca = i*2 + kh;
    v8bf av = *(const v8bf*)&qs[((wm+fr)*32 + (ca ^ ((wm+fr)&7)))*8];
    v8bf bv = *(const v8bf*)&ks[((wn+fr)*32 + (ca ^ ((wn+fr)&7)))*8];
    acc = __builtin_amdgcn_mfma_f32_32x32x16_bf16(av, bv, acc, 0, 0, 0);
  }
  __syncthreads();
  #pragma unroll
  for (int r = 0; r < 16; ++r){
    int row = wm + (r&3) + 8*(r>>2) + 4*kh;
    sc[row*65 + (wn+fr)] = acc[r]*0.0625f;
  }
  __syncthreads();
  if (tid < F_){
    float m = -1e30f;
    for (int k2 = 0; k2 < F_; ++k2) m = fmaxf(m, sc[tid*65+k2]);
    float s = 0.f;
    for (int k2 = 0; k2 < F_; ++k2){ float e = __expf(sc[tid*65+k2]-m); sc[tid*65+k2] = e; s += e; }
    float is = 1.f/s;
    for (int k2 = 0; k2 < F_; ++k2) sc[tid*65+k2] *= is;
  }
  __syncthreads();
  if (tid < F_){
    float s = 0.f;
    for (int r = 0; r < F_; ++r) s += sc[r*65+tid];
    cs[tid] = s;
  }
  __syncthreads();
  float a = 0.f;
  for (int k2 = 0; k2 < F_; ++k2){
    float v = __bfloat162float(qkv[(size_t)(b*F_+k2)*3072 + 2*H_ + h*DH_ + tid]);
    a += cs[k2]*v;
  }
  ctxbf[(size_t)b*H_ + h*DH_ + tid] = __float2bfloat16(a * (1.f/61.f));
}

// ---------------- SPL final step ----------------
__global__ __launch_bounds__(128) void spl_all(const float* __restrict__ hh_pre, const float* __restrict__ w1par,
                        const float* __restrict__ W2, const float* __restrict__ b2,
                        float* __restrict__ x, bf16* __restrict__ xpk,
                        float* __restrict__ out, int tstep){
  __shared__ float preds_s[4][128];
  __shared__ float hh_s[128][5];
  int b0 = blockIdx.x*4, t = threadIdx.x;   // grid 64, block 128
  for (int L = 0; L < 3; ++L){
    for (int ji = LVO[L]; ji < LVO[L+1]; ++ji){
      int j = LVJ[ji], p = PAR_[j];
      float acc[4];
      #pragma unroll
      for (int bb = 0; bb < 4; ++bb) acc[bb] = hh_pre[(size_t)(b0+bb)*1792 + j*128 + t];
      if (p >= 0){
        #pragma unroll
        for (int ii = 0; ii < 9; ++ii){
          float w = w1par[(j*9 + ii)*128 + t];
          #pragma unroll
          for (int bb = 0; bb < 4; ++bb) acc[bb] += w * preds_s[bb][p*9 + ii];
        }
      }
      #pragma unroll
      for (int bb = 0; bb < 4; ++bb) hh_s[t][bb] = fmaxf(acc[bb], 0.f);
      __syncthreads();
      if (t < 72){
        int pp = t >> 1, half = t & 1;
        int bb = pp/9, oi = pp%9;
        const float* w2r = W2 + (size_t)(j*9 + oi)*128 + half*64;
        float s = 0.f;
        #pragma unroll
        for (int tt = 0; tt < 64; ++tt) s += hh_s[half*64 + tt][bb] * w2r[tt];
        s += __shfl_xor(s, 1);
        if (half == 0) preds_s[bb][j*9 + oi] = tanhf(s + b2[j*9 + oi]);
      }
      __syncthreads();
    }
  }
  for (int i = t; i < 4*D_; i += 128){
    int bb = i / D_, d = i % D_;
    int row = b0 + bb;
    size_t xi = (size_t)row*D_ + d;
    float v = x[xi] + preds_s[bb][d];
    x[xi] = v;
    xpk[((row>>5)*4 + (d>>5))*1024 + (row&31)*32 + (d&31)] = __float2bfloat16(v);
    out[((size_t)row*PRED_ + tstep)*D_ + d] = v;
  }
}

// ---------------- launch ----------------
extern "C" void kernel_launch(void* const* d_in, const int* in_sizes, int n_in,
                              void* d_out, int out_size, void* d_ws, size_t ws_size,
                              hipStream_t stream){
  (void)in_sizes; (void)n_in; (void)out_size; (void)ws_size;
  const float* poses = (const float*)d_in[0];
  const float* gWih  = (const float*)d_in[1];
  const float* gWhh  = (const float*)d_in[2];
  const float* gbih  = (const float*)d_in[3];
  const float* gbhh  = (const float*)d_in[4];
  const float* preW  = (const float*)d_in[5];
  const float* preb  = (const float*)d_in[6];
  const float* fpW   = (const float*)d_in[7];
  const float* fpb   = (const float*)d_in[8];
  const float* inW   = (const float*)d_in[9];
  const float* inb   = (const float*)d_in[10];
  const float* outW  = (const float*)d_in[11];
  const float* outb  = (const float*)d_in[12];
  const float* sW1   = (const float*)d_in[13];
  const float* sb1   = (const float*)d_in[14];
  const float* sW2   = (const float*)d_in[15];
  const float* sb2   = (const float*)d_in[16];
  float* out = (float*)d_out;

  char* w = (char*)d_ws;
  size_t off = 0;
  auto alloc = [&](size_t bytes)->char*{ char* p = w + off; off += (bytes + 255) & ~(size_t)255; return p; };
  float* cosT   = (float*)alloc(7320*4);
  float* bc     = (float*)alloc(3072*4);
  float* motion = (float*)alloc((size_t)256*1024*4);
  float* hA     = (float*)alloc((size_t)256*1024*4);
  float* hB     = (float*)alloc((size_t)256*1024*4);
  float* xcur   = (float*)alloc((size_t)256*126*4);
  float* hhpre  = (float*)alloc((size_t)256*1792*4);
  float* bcat   = (float*)alloc(4096*4);
  float* w1par  = (float*)alloc(14*9*128*4);
  unsigned* prog= (unsigned*)alloc(4096);
  bf16* posespk = (bf16*)alloc((size_t)121*32768*2);
  bf16* Wcat    = (bf16*)alloc((size_t)4096*1152*2);
  bf16* Wpk     = (bf16*)alloc((size_t)64*108*512*2);
  bf16* w1pk    = (bf16*)alloc((size_t)112*32*512*2);
  bf16* prebf   = (bf16*)alloc((size_t)1024*1024*2);
  bf16* outbf   = (bf16*)alloc((size_t)1024*1024*2);
  bf16* inbf    = (bf16*)alloc((size_t)3072*1024*2);
  bf16* fpwt    = (bf16*)alloc((size_t)128*1024*2);
  bf16* ctxbf   = (bf16*)alloc((size_t)256*1024*2);
  bf16* hpkA    = (bf16*)alloc((size_t)256*1024*2);
  bf16* hpkB    = (bf16*)alloc((size_t)256*1024*2);
  bf16* hbplain = (bf16*)alloc((size_t)256*1024*2);
  bf16* hidpk   = (bf16*)alloc((size_t)256*1024*2);
  bf16* xpk     = (bf16*)alloc((size_t)32768*2);
  bf16* Wcbf    = (bf16*)alloc((size_t)3072*128*2);
  bf16* freqbf  = (bf16*)alloc((size_t)B_*F_*128*2);
  bf16* qkvbf   = (bf16*)alloc((size_t)15680*3072*2);

  hipMemsetAsync(hpkA, 0, (size_t)256*1024*2, stream);
  hipMemsetAsync(prog, 0, 4096, stream);

  k_cos<<<29, 256, 0, stream>>>(cosT);
  k_dft2<<<B_, 256, 0, stream>>>(poses, cosT, freqbf);
  c_poses<<<dim3(SEED_, B_), 128, 0, stream>>>(poses, posespk);
  c_xinit<<<B_, 128, 0, stream>>>(poses, xcur, xpk);
  c_wcat<<<4096, 256, 0, stream>>>(gWih, gWhh, Wcat);
  c_bcat<<<16, 256, 0, stream>>>(gbih, gbhh, bcat);
  c_wpk<<<1728, 256, 0, stream>>>(Wcat, Wpk);
  c_w1pk<<<896, 256, 0, stream>>>(sW1, w1pk);
  c_w1par<<<63, 256, 0, stream>>>(sW1, w1par);
  c_bf<<<4096, 256, 0, stream>>>(preW, prebf, 1024*1024);
  c_bf<<<4096, 256, 0, stream>>>(outW, outbf, 1024*1024);
  c_bf<<<12288, 256, 0, stream>>>(inW, inbf, 3072*1024);
  c_fpwt<<<128, 256, 0, stream>>>(fpW, fpwt);
  k_bc<<<768, 256, 0, stream>>>(inW, inb, fpb, bc);

  // Wc = inproj @ fp_W  (3072 x 128, bf16)
  gemm64<<<dim3(48, 2), 256, 0, stream>>>(inbf, fpwt, 1024, nullptr, nullptr, nullptr, Wcbf, 128, 0);
  // qkv = freq @ Wc^T + bc  (15616 x 3072, bf16)
  gemm64<<<dim3(244, 48), 256, 0, stream>>>(freqbf, Wcbf, 128, bc, nullptr, nullptr, qkvbf, 3072, 0);
  k_attn<<<dim3(HEADS_, B_), 256, 0, stream>>>(qkvbf, ctxbf);
  // motion_ctx = ctx_mean @ outproj^T + outb
  gemm64<<<dim3(4, 16), 256, 0, stream>>>(ctxbf, outbf, 1024, outb, nullptr, motion, nullptr, 1024, 0);

  // encoder: cooperative, 256 blocks x 256 threads (all CUs), fence-free coherent h
  {
    const bf16* a0 = posespk; int a1 = 32768; int a2 = SEED_; int a3 = 1;
    const bf16* a4 = Wpk; const float* a5 = bcat;
    const float* a6 = hA; float* a7 = hA; bf16* a8 = nullptr;
    bf16* a9 = hpkA; bf16* a10 = hpkB; unsigned* a11 = prog;
    void* args[] = { &a0, &a1, &a2, &a3, &a4, &a5, &a6, &a7, &a8, &a9, &a10, &a11 };
    hipLaunchCooperativeKernel(reinterpret_cast<void*>(gru_wave), dim3(256), dim3(256),
                               args, 0, stream);
  }

  float* hc = hA;  float* hn = hB;
  bf16* hpc = hpkA; bf16* hpn = hpkB;
  unsigned* progS = prog + 256;
  unsigned* progP = prog + 384;

  // decoder: 24 steps x { gru_spl (SPL(t-1)+GRU(t)), gemm_pw (pre+W1) }; final SPL
  for (int t = 0; t < PRED_; ++t){
    gru_spl<<<128, 512, 0, stream>>>(xpk, Wpk, bcat, hc, hn, hbplain, hpc, hpn,
                                     hhpre, w1par, sW2, sb2, xcur, xpk, out, t, progS);
    { float* tf = hc; hc = hn; hn = tf; bf16* tb = hpc; hpc = hpn; hpn = tb; }
    gemm_pw<<<112, 512, 0, stream>>>(hbplain, prebf, preb, motion, hidpk, w1pk, sb1, hhpre, t, progP);
  }
  spl_all<<<64, 128, 0, stream>>>(hhpre, w1par, sW2, sb2, xcur, xpk, out, PRED_-1);
}

// Round 18
// 2609.504 us; speedup vs baseline: 1.6859x; 1.0657x over previous
//
#include <hip/hip_runtime.h>
#include <hip/hip_bf16.h>

typedef __hip_bfloat16 bf16;
typedef __attribute__((ext_vector_type(8))) short v8bf;     // 8 bf16 (4 VGPR)
typedef __attribute__((ext_vector_type(16))) float f32x16;
typedef __attribute__((ext_vector_type(4))) float f32x4;
typedef unsigned long long ull;

#define B_    256
#define SEED_ 120
#define PRED_ 24
#define D_    126
#define H_    1024
#define F_    61
#define HEADS_ 4
#define DH_   256

#define GLD16(lds, g) __builtin_amdgcn_global_load_lds( \
    (const __attribute__((address_space(1))) unsigned int*)(g), \
    (__attribute__((address_space(3))) unsigned int*)(lds), 16, 0, 0)
#define VMWAIT(n) asm volatile("s_waitcnt vmcnt(" #n ")" ::: "memory")
#define BARRIER() do { __builtin_amdgcn_s_barrier(); __builtin_amdgcn_sched_barrier(0); } while(0)
#define AL(P) __hip_atomic_load((P), __ATOMIC_RELAXED, __HIP_MEMORY_SCOPE_AGENT)

// ---------------- small precompute kernels ----------------
__global__ void k_cos(float* cosT){
  int i = blockIdx.x*256 + threadIdx.x;
  if (i < F_*SEED_){
    int f = i / SEED_, t = i % SEED_;
    int ph = (f*t) % SEED_;
    cosT[i] = cosf(6.283185307179586f * (float)ph / (float)SEED_);
  }
}

__global__ __launch_bounds__(256) void k_dft2(const float* __restrict__ poses,
                      const float* __restrict__ cosT, bf16* __restrict__ freqbf){
  __shared__ float pl[SEED_*128];      // 60 KB
  int b = blockIdx.x, tid = threadIdx.x;
  for (int i = tid; i < SEED_*D_; i += 256){
    int t = i / D_, d = i - t*D_;
    pl[t*128 + d] = poses[((size_t)b*(SEED_+PRED_) + t)*D_ + d];
  }
  __syncthreads();
  int d = tid & 127, f0 = tid >> 7;    // f = f0 + 2j
  float acc[31];
  #pragma unroll
  for (int j = 0; j < 31; ++j) acc[j] = 0.f;
  for (int t = 0; t < SEED_; ++t){
    float v = pl[t*128 + d];
    #pragma unroll
    for (int j = 0; j < 31; ++j){
      int f = f0 + j*2;
      if (f < F_) acc[j] += cosT[f*SEED_ + t] * v;
    }
  }
  #pragma unroll
  for (int j = 0; j < 31; ++j){
    int f = f0 + j*2;
    if (f < F_) freqbf[((size_t)b*F_ + f)*128 + d] = __float2bfloat16(d < D_ ? acc[j] : 0.f);
  }
}

// pack poses into per-step 32x32 tiles
__global__ void c_poses(const float* __restrict__ poses, bf16* __restrict__ pk){
  int t = blockIdx.x, b = blockIdx.y, c = threadIdx.x;  // block 128
  float v = (c < D_) ? poses[((size_t)b*(SEED_+PRED_) + t)*D_ + c] : 0.f;
  pk[(size_t)t*32768 + ((b>>5)*4 + (c>>5))*1024 + (b&31)*32 + (c&31)] = __float2bfloat16(v);
}

__global__ void c_xinit(const float* __restrict__ poses, float* __restrict__ x, bf16* __restrict__ xpk){
  int b = blockIdx.x, c = threadIdx.x;  // block 128
  float v = (c < D_) ? poses[((size_t)b*(SEED_+PRED_) + (SEED_-1))*D_ + c] : 0.f;
  if (c < D_) x[b*D_ + c] = v;
  xpk[((b>>5)*4 + (c>>5))*1024 + (b&31)*32 + (c&31)] = __float2bfloat16(v);
}

__global__ void c_bf(const float* __restrict__ s, bf16* __restrict__ d, int n){
  int i = blockIdx.x*256 + threadIdx.x;
  if (i < n) d[i] = __float2bfloat16(s[i]);
}

__global__ void c_fpwt(const float* __restrict__ fpW, bf16* __restrict__ o){
  int dd = blockIdx.x;                       // 0..127
  for (int k = threadIdx.x; k < H_; k += 256)
    o[(size_t)dd*H_ + k] = __float2bfloat16(dd < D_ ? fpW[(size_t)k*D_ + dd] : 0.f);
}

// combined GRU weight rows (1152 wide: 128 x-cols | 1024 h-cols)
__global__ void c_wcat(const float* __restrict__ Wih, const float* __restrict__ Whh, bf16* __restrict__ o){
  int r = blockIdx.x;
  int jr; bool hasx, hash;
  if (r < 2048){ jr = r; hasx = true; hash = true; }
  else if (r < 3072){ jr = r; hasx = true; hash = false; }
  else { jr = r - 1024; hasx = false; hash = true; }
  bf16* row = o + (size_t)r*1152;
  for (int c = threadIdx.x; c < 1152; c += 256){
    float v = 0.f;
    if (c < D_) { if (hasx) v = Wih[(size_t)jr*D_ + c]; }
    else if (c >= 128){ if (hash) v = Whh[(size_t)jr*H_ + (c-128)]; }
    row[c] = __float2bfloat16(v);
  }
}

__global__ void c_bcat(const float* __restrict__ bih, const float* __restrict__ bhh, float* __restrict__ o){
  int r = blockIdx.x*256 + threadIdx.x;
  if (r >= 4096) return;
  float v;
  if (r < 2048) v = bih[r] + bhh[r];
  else if (r < 3072) v = bih[r];
  else v = bhh[r - 1024];
  o[r] = v;
}

// pack GRU weights into MFMA B-fragment order
__global__ __launch_bounds__(256) void c_wpk(const bf16* __restrict__ Wcat, bf16* __restrict__ Wpk){
  int chunk = blockIdx.x*4 + (threadIdx.x >> 6);
  int l = threadIdx.x & 63;
  int ks = chunk % 36; int t2 = chunk / 36; int g = t2 % 3; int ub = t2 / 3;
  int unit = ub*16 + (l & 15);
  bf16* dst = Wpk + (size_t)chunk*512 + l*8;
  #pragma unroll
  for (int e = 0; e < 8; ++e){
    int k = ks*32 + (l>>4)*8 + e;
    int row = (g==0) ? unit : (g==1) ? (1024+unit) : (k < 128 ? 2048+unit : 3072+unit);
    dst[e] = Wcat[(size_t)row*1152 + k];
  }
}

// pack W1-hid into fragment order: chunk = ug*32+ks, ug 0..111
__global__ __launch_bounds__(256) void c_w1pk(const float* __restrict__ sW1, bf16* __restrict__ w1pk){
  int chunk = blockIdx.x*4 + (threadIdx.x >> 6);   // 3584 chunks
  int l = threadIdx.x & 63;
  int ks = chunk & 31, ng = chunk >> 5;
  int unit = ng*16 + (l & 15);
  int j = unit >> 7, rr = unit & 127;
  bf16* dst = w1pk + (size_t)chunk*512 + l*8;
  #pragma unroll
  for (int e = 0; e < 8; ++e){
    int k = ks*32 + (l>>4)*8 + e;
    dst[e] = __float2bfloat16(sW1[((size_t)j*128 + rr)*1033 + k]);
  }
}

// pack SPL parent weights
__global__ void c_w1par(const float* __restrict__ sW1, float* __restrict__ w1par){
  int i = blockIdx.x*256 + threadIdx.x;
  if (i < 14*9*128){
    int j = i / (9*128); int rem = i % (9*128); int ii = rem / 128; int th = rem % 128;
    w1par[i] = sW1[((size_t)(j*128 + th))*1033 + 1024 + ii];
  }
}

// bc = inproj @ fp_b + in_b
__global__ __launch_bounds__(256) void k_bc(const float* __restrict__ inW, const float* __restrict__ inb,
                     const float* __restrict__ fpb, float* __restrict__ bc){
  int wave = threadIdx.x >> 6, lane = threadIdx.x & 63;
  int r = blockIdx.x*4 + wave;
  const float4* row = (const float4*)(inW + (size_t)r*H_);
  const float4* fp4 = (const float4*)fpb;
  float s = 0.f;
  #pragma unroll
  for (int i = 0; i < 4; ++i){
    float4 a = row[lane + i*64];
    float4 b = fp4[lane + i*64];
    s += a.x*b.x + a.y*b.y + a.z*b.z + a.w*b.w;
  }
  #pragma unroll
  for (int off = 32; off; off >>= 1) s += __shfl_down(s, off);
  if (lane == 0) bc[r] = s + inb[r];
}

// ---------------- encoder: wave-autonomous GRU, 256 blocks x 4 waves (R17) ----------------
#define SLCP(QA, QB, KS, GACC) { \
  union { ull u[2]; v8bf v; } cc_; cc_.u[0]=(QA); cc_.u[1]=(QB); \
  v8bf a_ = cc_.v; \
  v8bf w0_ = *(const v8bf*)&Wl[(0*36+(KS))*512 + lane*8]; \
  v8bf w1_ = *(const v8bf*)&Wl[(1*36+(KS))*512 + lane*8]; \
  v8bf w2_ = *(const v8bf*)&Wl[(2*36+(KS))*512 + lane*8]; \
  aR = __builtin_amdgcn_mfma_f32_16x16x32_bf16(a_, w0_, aR, 0,0,0); \
  aZ = __builtin_amdgcn_mfma_f32_16x16x32_bf16(a_, w1_, aZ, 0,0,0); \
  GACC = __builtin_amdgcn_mfma_f32_16x16x32_bf16(a_, w2_, GACC, 0,0,0); }

#define LDHA(DA, DB, C) { \
  const ull* hp_ = (const ull*)(hs + hbase + (size_t)(C)*1024); \
  DA = AL(hp_); DB = AL(hp_+1); }

#define LDXP(DA, DB, TT, C) { \
  const ull* xp_ = (const ull*)(xpk + (size_t)(TT)*xstride + xbase + (size_t)(C)*1024); \
  DA = xp_[0]; DB = xp_[1]; }

__global__ __launch_bounds__(256) void gru_wave(
    const bf16* __restrict__ xpk, int xstride, int nsteps, int coop,
    const bf16* __restrict__ Wpk, const float* __restrict__ bcat,
    const float* __restrict__ hin_plain, float* __restrict__ hout_plain,
    bf16* __restrict__ hbplain,
    bf16* __restrict__ hpk0, bf16* __restrict__ hpk1,
    unsigned* __restrict__ prog)
{
  __shared__ bf16 Wl[3*36*512];       // 108 KB
  const int tid = threadIdx.x, wave = tid >> 6, lane = tid & 63;
  const int ub = blockIdx.x & 63, q = blockIdx.x >> 6;
  const int u0 = ub*16;

  {
    const bf16* wsrc = Wpk + (size_t)ub*(3*36*512);
    #pragma unroll
    for (int i = 0; i < 27; ++i){
      int c = i*256 + tid;
      GLD16(&Wl[c*8], wsrc + (size_t)c*8);
    }
  }
  VMWAIT(0); BARRIER();

  const int la = lane & 15, lb = lane >> 4;
  const int r0 = q*64 + wave*16;
  const int rb = r0 >> 5, y = wave & 1;
  const int ucol = u0 + la;
  const float bR = bcat[ucol], bZ = bcat[1024+ucol], bI = bcat[2048+ucol], bN = bcat[3072+ucol];
  const size_t hbase = (size_t)rb*32768 + (size_t)y*512 + la*32 + lb*8;
  const size_t xbase = (size_t)rb*4096  + (size_t)y*512 + la*32 + lb*8;
  const size_t pwb = (size_t)rb*32768 + (size_t)(u0>>5)*1024 + (size_t)y*512 + (u0&16) + la;

  float hr[4];
  if (nsteps == 1){
    #pragma unroll
    for (int r = 0; r < 4; ++r) hr[r] = hin_plain[(size_t)(r0 + lb*4 + r)*1024 + ucol];
  } else {
    #pragma unroll
    for (int r = 0; r < 4; ++r) hr[r] = 0.f;
  }

  ull a0,a1,a2,a3,a4,a5,a6,a7,a8,a9,a10,a11;
  ull b0,b1,b2,b3,b4,b5,b6,b7,b8,b9,b10,b11;
  LDXP(a0,b0,0,0); LDXP(a1,b1,0,1); LDXP(a2,b2,0,2); LDXP(a3,b3,0,3);

  for (int t = 0; t < nsteps; ++t){
    if (coop && t > 0){
      if (wave == 0){
        unsigned v = AL(&prog[q*64 + lane]);
        while (__ballot(v >= (unsigned)t) != ~0ULL){
          __builtin_amdgcn_s_sleep(1);
          v = AL(&prog[q*64 + lane]);
        }
      }
      __syncthreads();
      __builtin_amdgcn_sched_barrier(0);
    }
    const bf16* hs = (t & 1) ? hpk1 : hpk0;
    LDHA(a4,b4,0) LDHA(a5,b5,1) LDHA(a6,b6,2) LDHA(a7,b7,3)
    LDHA(a8,b8,4) LDHA(a9,b9,5) LDHA(a10,b10,6) LDHA(a11,b11,7)

    f32x4 z4 = {0.f,0.f,0.f,0.f};
    f32x4 aR = z4, aZ = z4, aI = z4, aN = z4;

    SLCP(a0,b0,0,aI)  LDHA(a0,b0,8)
    SLCP(a1,b1,1,aI)  LDHA(a1,b1,9)
    SLCP(a2,b2,2,aI)  LDHA(a2,b2,10)
    SLCP(a3,b3,3,aI)  LDHA(a3,b3,11)
    SLCP(a4,b4,4,aN)  LDHA(a4,b4,12)
    SLCP(a5,b5,5,aN)  LDHA(a5,b5,13)
    SLCP(a6,b6,6,aN)  LDHA(a6,b6,14)
    SLCP(a7,b7,7,aN)  LDHA(a7,b7,15)
    SLCP(a8,b8,8,aN)  LDHA(a8,b8,16)
    SLCP(a9,b9,9,aN)  LDHA(a9,b9,17)
    SLCP(a10,b10,10,aN) LDHA(a10,b10,18)
    SLCP(a11,b11,11,aN) LDHA(a11,b11,19)
    SLCP(a0,b0,12,aN) LDHA(a0,b0,20)
    SLCP(a1,b1,13,aN) LDHA(a1,b1,21)
    SLCP(a2,b2,14,aN) LDHA(a2,b2,22)
    SLCP(a3,b3,15,aN) LDHA(a3,b3,23)
    SLCP(a4,b4,16,aN) LDHA(a4,b4,24)
    SLCP(a5,b5,17,aN) LDHA(a5,b5,25)
    SLCP(a6,b6,18,aN) LDHA(a6,b6,26)
    SLCP(a7,b7,19,aN) LDHA(a7,b7,27)
    SLCP(a8,b8,20,aN) LDHA(a8,b8,28)
    SLCP(a9,b9,21,aN) LDHA(a9,b9,29)
    SLCP(a10,b10,22,aN) LDHA(a10,b10,30)
    SLCP(a11,b11,23,aN) LDHA(a11,b11,31)
    SLCP(a0,b0,24,aN) LDXP(a0,b0,t+1,0)
    SLCP(a1,b1,25,aN) LDXP(a1,b1,t+1,1)
    SLCP(a2,b2,26,aN) LDXP(a2,b2,t+1,2)
    SLCP(a3,b3,27,aN) LDXP(a3,b3,t+1,3)
    SLCP(a4,b4,28,aN)
    SLCP(a5,b5,29,aN)
    SLCP(a6,b6,30,aN)
    SLCP(a7,b7,31,aN)
    SLCP(a8,b8,32,aN)
    SLCP(a9,b9,33,aN)
    SLCP(a10,b10,34,aN)
    SLCP(a11,b11,35,aN)

    bf16* hd = (t & 1) ? hpk0 : hpk1;
    const bool last = (t == nsteps-1);
    #pragma unroll
    for (int r = 0; r < 4; ++r){
      float rg = 1.f/(1.f + __expf(-(aR[r] + bR)));
      float zg = 1.f/(1.f + __expf(-(aZ[r] + bZ)));
      float ng = tanhf((aI[r] + bI) + rg*(aN[r] + bN));
      float hv = (1.f - zg)*ng + zg*hr[r];
      hr[r] = hv;
      bf16 hv16 = __float2bfloat16(hv);
      unsigned short hbits = *(unsigned short*)&hv16;
      __hip_atomic_store((unsigned short*)(hd + pwb + (size_t)(lb*4 + r)*32), hbits,
                         __ATOMIC_RELAXED, __HIP_MEMORY_SCOPE_AGENT);
      if (last){
        hout_plain[(size_t)(r0 + lb*4 + r)*1024 + ucol] = hv;
        if (hbplain) hbplain[(size_t)(r0 + lb*4 + r)*1024 + ucol] = __float2bfloat16(hv);
      }
    }
    if (coop && t + 1 < nsteps){
      VMWAIT(0);
      __syncthreads();
      if (tid == 0)
        __hip_atomic_store(&prog[q*64 + ub], (unsigned)(t+1), __ATOMIC_RELAXED, __HIP_MEMORY_SCOPE_AGENT);
    }
  }
}

// ---------------- decoder GRU + SPL(t-1): 256 blocks x 256 threads ----------------
__constant__ int LVJ[14] = {0,1,6,8,9, 2,3,7,10,11, 4,5,12,13};
__constant__ int LVO[4]  = {0,5,10,14};
__constant__ int PAR_[14] = {-1,-1,0,1,2,3,-1,6,-1,-1,8,9,10,11};

#define DGRL(S,C) { const ull* p_=(const ull*)(hspk + hbase + (size_t)(C)*1024); qa##S=AL(p_); qb##S=AL(p_+1); }
#define DGXL(S,C) { const ull* p_=(const ull*)(xpk + xbase + (size_t)(C)*1024); qa##S=AL(p_); qb##S=AL(p_+1); }
#define DGRC(S,KS,GACC) { union{ull u[2];v8bf v;}c_; c_.u[0]=qa##S;c_.u[1]=qb##S; v8bf a_=c_.v; \
  v8bf w0_=*(const v8bf*)&Wl[(KS)*512+lane*8]; \
  v8bf w1_=*(const v8bf*)&Wl[18432+(KS)*512+lane*8]; \
  v8bf w2_=*(const v8bf*)&Wl[36864+(KS)*512+lane*8]; \
  aR=__builtin_amdgcn_mfma_f32_16x16x32_bf16(a_,w0_,aR,0,0,0); \
  aZ=__builtin_amdgcn_mfma_f32_16x16x32_bf16(a_,w1_,aZ,0,0,0); \
  GACC=__builtin_amdgcn_mfma_f32_16x16x32_bf16(a_,w2_,GACC,0,0,0); }

__global__ __launch_bounds__(256) void gru_spl(
    const bf16* __restrict__ xpk, const bf16* __restrict__ Wpk,
    const float* __restrict__ bcat,
    const float* __restrict__ hin_plain, float* __restrict__ hout_plain,
    bf16* __restrict__ hbplain,
    const bf16* __restrict__ hspk, bf16* __restrict__ hdpk,
    const float* __restrict__ hhpre, const float* __restrict__ w1par,
    const float* __restrict__ sW2, const float* __restrict__ sb2,
    float* __restrict__ xcur, bf16* __restrict__ xpkw, float* __restrict__ out,
    int dt, unsigned* __restrict__ progS)
{
  __shared__ bf16 Wl[3*36*512];     // 108 KB
  __shared__ float hhl[1792];       // 7 KB
  __shared__ float preds_s[128];
  __shared__ float hh_s[128];
  const int tid = threadIdx.x, wave = tid >> 6, lane = tid & 63;
  const int bid = blockIdx.x;
  const int ub = bid & 63, q = bid >> 6, u0 = ub*16;

  {  // weights -> LDS (async, overlaps SPL)
    const bf16* wsrc = Wpk + (size_t)ub*(3*36*512);
    #pragma unroll
    for (int i = 0; i < 27; ++i){ int c = i*256 + tid; GLD16(&Wl[c*8], wsrc + (size_t)c*8); }
  }

  // ---- SPL of previous step: 1 batch row per block ----
  const int brow = bid, th = tid;
  if (dt > 0){
    for (int i = tid; i < 1792; i += 256) hhl[i] = hhpre[(size_t)brow*1792 + i];
    __syncthreads();
    for (int L = 0; L < 3; ++L){
      for (int ji = LVO[L]; ji < LVO[L+1]; ++ji){
        int j = LVJ[ji], p = PAR_[j];
        if (tid < 128){
          float a0s = hhl[j*128 + th];
          if (p >= 0){
            #pragma unroll
            for (int ii = 0; ii < 9; ++ii)
              a0s += w1par[(j*9 + ii)*128 + th] * preds_s[p*9 + ii];
          }
          hh_s[th] = fmaxf(a0s, 0.f);
        }
        __syncthreads();
        if (tid < 18){
          int oi = th >> 1, half = th & 1;
          const float4* w4 = (const float4*)(sW2 + (size_t)(j*9 + oi)*128 + half*64);
          float s = 0.f;
          #pragma unroll
          for (int q2 = 0; q2 < 16; ++q2){
            float4 wv = w4[q2];
            s += hh_s[half*64 + q2*4 + 0]*wv.x + hh_s[half*64 + q2*4 + 1]*wv.y
               + hh_s[half*64 + q2*4 + 2]*wv.z + hh_s[half*64 + q2*4 + 3]*wv.w;
          }
          s += __shfl_xor(s, 1);
          if (half == 0) preds_s[j*9 + oi] = tanhf(s + sb2[j*9 + oi]);
        }
        __syncthreads();
      }
    }
    if (tid < D_){
      int d = tid;
      size_t xi = (size_t)brow*D_ + d;
      float v = xcur[xi] + preds_s[d];
      xcur[xi] = v;
      bf16 v16 = __float2bfloat16(v);
      __hip_atomic_store((unsigned short*)(xpkw + ((size_t)(brow>>5)*4 + (d>>5))*1024 + (brow&31)*32 + (d&31)),
                         *(unsigned short*)&v16, __ATOMIC_RELAXED, __HIP_MEMORY_SCOPE_AGENT);
      out[((size_t)brow*PRED_ + (dt-1))*D_ + d] = v;
    }
    VMWAIT(0);
    __syncthreads();
    if (tid == 0)
      __hip_atomic_store(&progS[bid], (unsigned)dt, __ATOMIC_RELAXED, __HIP_MEMORY_SCOPE_AGENT);
  }

  VMWAIT(0); BARRIER();     // weights resident

  const int la = lane & 15, lb = lane >> 4;
  const int r0 = q*64 + wave*16;
  const int rb = r0 >> 5, y = wave & 1;
  const int ucol = u0 + la;
  const float bR = bcat[ucol], bZ = bcat[1024+ucol], bI = bcat[2048+ucol], bN = bcat[3072+ucol];
  const size_t hbase = (size_t)rb*32768 + (size_t)y*512 + la*32 + lb*8;
  const size_t xbase = (size_t)rb*4096  + (size_t)y*512 + la*32 + lb*8;
  const size_t pwb = (size_t)rb*32768 + (size_t)(u0>>5)*1024 + (size_t)y*512 + (u0&16) + la;

  float hr[4];
  #pragma unroll
  for (int r = 0; r < 4; ++r) hr[r] = hin_plain[(size_t)(r0 + lb*4 + r)*1024 + ucol];

  ull qa0,qa1,qa2,qa3,qa4,qa5,qa6,qa7,qa8,qa9,qa10,qa11;
  ull qb0,qb1,qb2,qb3,qb4,qb5,qb6,qb7,qb8,qb9,qb10,qb11;

  // h-slices first (depend only on h^t)
  DGRL(0,0) DGRL(1,1) DGRL(2,2) DGRL(3,3) DGRL(4,4) DGRL(5,5)
  DGRL(6,6) DGRL(7,7) DGRL(8,8) DGRL(9,9) DGRL(10,10) DGRL(11,11)
  f32x4 z4 = {0.f,0.f,0.f,0.f};
  f32x4 aR = z4, aZ = z4, aI = z4, aN = z4;
  DGRC(0,4,aN)  DGRL(0,12)
  DGRC(1,5,aN)  DGRL(1,13)
  DGRC(2,6,aN)  DGRL(2,14)
  DGRC(3,7,aN)  DGRL(3,15)
  DGRC(4,8,aN)  DGRL(4,16)
  DGRC(5,9,aN)  DGRL(5,17)
  DGRC(6,10,aN) DGRL(6,18)
  DGRC(7,11,aN) DGRL(7,19)
  DGRC(8,12,aN) DGRL(8,20)
  DGRC(9,13,aN) DGRL(9,21)
  DGRC(10,14,aN) DGRL(10,22)
  DGRC(11,15,aN) DGRL(11,23)
  DGRC(0,16,aN) DGRL(0,24)
  DGRC(1,17,aN) DGRL(1,25)
  DGRC(2,18,aN) DGRL(2,26)
  DGRC(3,19,aN) DGRL(3,27)
  DGRC(4,20,aN) DGRL(4,28)
  DGRC(5,21,aN) DGRL(5,29)
  DGRC(6,22,aN) DGRL(6,30)
  DGRC(7,23,aN) DGRL(7,31)
  DGRC(8,24,aN)
  DGRC(9,25,aN)
  DGRC(10,26,aN)
  DGRC(11,27,aN)
  DGRC(0,28,aN)
  DGRC(1,29,aN)
  DGRC(2,30,aN)
  DGRC(3,31,aN)
  DGRC(4,32,aN)
  DGRC(5,33,aN)
  DGRC(6,34,aN)
  DGRC(7,35,aN)
  // wait for all 256 blocks' SPL (x^t ready); each wave polls its 64-flag segment
  if (dt > 0){
    unsigned v = AL(&progS[wave*64 + lane]);
    while (__ballot(v >= (unsigned)dt) != ~0ULL){
      __builtin_amdgcn_s_sleep(2);
      v = AL(&progS[wave*64 + lane]);
    }
    __syncthreads();
    __builtin_amdgcn_sched_barrier(0);
  }
  DGXL(8,0) DGXL(9,1) DGXL(10,2) DGXL(11,3)
  DGRC(8,0,aI)
  DGRC(9,1,aI)
  DGRC(10,2,aI)
  DGRC(11,3,aI)
  #pragma unroll
  for (int r = 0; r < 4; ++r){
    float rg = 1.f/(1.f + __expf(-(aR[r] + bR)));
    float zg = 1.f/(1.f + __expf(-(aZ[r] + bZ)));
    float ng = tanhf((aI[r] + bI) + rg*(aN[r] + bN));
    float hv = (1.f - zg)*ng + zg*hr[r];
    bf16 hv16 = __float2bfloat16(hv);
    __hip_atomic_store((unsigned short*)(hdpk + pwb + (size_t)(lb*4 + r)*32),
                       *(unsigned short*)&hv16, __ATOMIC_RELAXED, __HIP_MEMORY_SCOPE_AGENT);
    hout_plain[(size_t)(r0 + lb*4 + r)*1024 + ucol] = hv;
    hbplain[(size_t)(r0 + lb*4 + r)*1024 + ucol] = hv16;
  }
}

// ---------------- fused pre + W1 (R16, unchanged) ----------------
#define W1L(S,C) { const ull* p_=(const ull*)(hidpk + w1abase + (size_t)(C)*1024); \
  qa##S=AL(p_); qb##S=AL(p_+1); \
  bq##S = *(const uint4*)(w1b0 + (size_t)(C)*512 + lane*8); \
  br##S = *(const uint4*)(w1b1 + (size_t)(C)*512 + lane*8); }
#define W1C(S) { union{ull u[2];v8bf v;}x_; x_.u[0]=qa##S;x_.u[1]=qb##S; \
  union{uint4 q; v8bf v;}b0_,b1_; b0_.q=bq##S; b1_.q=br##S; \
  c0=__builtin_amdgcn_mfma_f32_16x16x32_bf16(x_.v,b0_.v,c0,0,0,0); \
  c1=__builtin_amdgcn_mfma_f32_16x16x32_bf16(x_.v,b1_.v,c1,0,0,0); }

__global__ __launch_bounds__(512) void gemm_pw(
    const bf16* __restrict__ hb, const bf16* __restrict__ prebf,
    const float* __restrict__ preb, const float* __restrict__ motion,
    bf16* __restrict__ hidpk, const bf16* __restrict__ w1pk,
    const float* __restrict__ sb1, float* __restrict__ hhpre,
    int dt, unsigned* __restrict__ progP)
{
  __shared__ bf16 As[3][64*64];
  __shared__ bf16 Bs[3][64*64];
  const int tid = threadIdx.x, wave = tid >> 6, lane = tid & 63;
  const int bid = blockIdx.x;
  const int la = lane & 15, lb = lane >> 4;

  // ---------- phase A: pre (blocks 0..63) ----------
  if (bid < 64){
    const int m0 = (bid & 3)*64, n0 = (bid >> 2)*64;
    const int fr = lane & 31, kh = lane >> 5;
    const int wm = (wave >> 1)*32, wn = (wave & 1)*32;
    f32x16 acc = {0.f,0.f,0.f,0.f,0.f,0.f,0.f,0.f,0.f,0.f,0.f,0.f,0.f,0.f,0.f,0.f};

    auto STAGE = [&](int buf, int kt){
      if (tid < 256){
        #pragma unroll
        for (int q2 = 0; q2 < 2; ++q2){
          int idx = q2*256 + tid;
          int row = idx >> 3, cp = idx & 7, csw = cp ^ (row & 7);
          GLD16(&As[buf][idx*8], hb + (size_t)(m0+row)*1024 + kt*64 + csw*8);
        }
        #pragma unroll
        for (int q2 = 0; q2 < 2; ++q2){
          int idx = q2*256 + tid;
          int row = idx >> 3, cp = idx & 7, csw = cp ^ (row & 7);
          GLD16(&Bs[buf][idx*8], prebf + (size_t)(n0+row)*1024 + kt*64 + csw*8);
        }
      }
    };
    auto COMPUTE = [&](int buf){
      if (wave < 4){
        const bf16* Ab = &As[buf][0];
        const bf16* Bb = &Bs[buf][0];
        #pragma unroll
        for (int ks = 0; ks < 4; ++ks){
          int ca = ks*2 + kh;
          v8bf av = *(const v8bf*)&Ab[(wm+fr)*64 + ((ca ^ ((wm+fr)&7))*8)];
          v8bf bv = *(const v8bf*)&Bb[(wn+fr)*64 + ((ca ^ ((wn+fr)&7))*8)];
          acc = __builtin_amdgcn_mfma_f32_32x32x16_bf16(av, bv, acc, 0, 0, 0);
        }
      }
    };

    STAGE(0, 0); STAGE(1, 1);
    VMWAIT(4); BARRIER();
    for (int kt = 0; kt < 16; ++kt){
      if (kt + 2 < 16) STAGE((kt+2)%3, kt+2);
      COMPUTE(kt%3);
      if (kt + 2 < 16){ VMWAIT(4); BARRIER(); }
      else if (kt + 1 < 16){ VMWAIT(0); BARRIER(); }
    }
    if (wave < 4){
      const int col = n0 + wn + fr;
      const float bb2 = preb[col];
      #pragma unroll
      for (int r = 0; r < 16; ++r){
        int row = m0 + wm + (r&3) + 8*(r>>2) + 4*kh;
        float v = fmaxf(acc[r] + bb2, 0.f) + motion[(size_t)row*1024 + col];
        bf16 v16 = __float2bfloat16(v);
        __hip_atomic_store((unsigned short*)(hidpk + ((size_t)(row>>5)*32 + (col>>5))*1024 + (row&31)*32 + (col&31)),
                           *(unsigned short*)&v16, __ATOMIC_RELAXED, __HIP_MEMORY_SCOPE_AGENT);
      }
    }
    VMWAIT(0);
    __syncthreads();
    if (tid == 0)
      __hip_atomic_store(&progP[bid], (unsigned)(dt+1), __ATOMIC_RELAXED, __HIP_MEMORY_SCOPE_AGENT);
  }

  // ---------- wait for all pre flags ----------
  if (wave == 0){
    unsigned v = AL(&progP[lane]);
    while (__ballot(v >= (unsigned)(dt+1)) != ~0ULL){
      __builtin_amdgcn_s_sleep(2);
      v = AL(&progP[lane]);
    }
  }
  __syncthreads();
  __builtin_amdgcn_sched_barrier(0);

  // ---------- phase B: W1 (all 112 blocks) ----------
  const int mq = bid / 28, ng = bid % 28;
  const int mg = wave >> 1, nc = wave & 1;
  const int r0w = mq*64 + mg*16;
  const int w1rb = r0w >> 5, w1y = mg & 1;
  const size_t w1abase = (size_t)w1rb*32768 + (size_t)w1y*512 + la*32 + lb*8;
  const int ug0 = ng*4 + nc*2, ug1 = ug0 + 1;
  const bf16* w1b0 = w1pk + (size_t)ug0*(32*512);
  const bf16* w1b1 = w1pk + (size_t)ug1*(32*512);
  const float sb1a = sb1[ug0*16 + la];
  const float sb1b = sb1[ug1*16 + la];

  ull qa0,qa1,qa2,qa3,qa4,qa5;
  ull qb0,qb1,qb2,qb3,qb4,qb5;
  uint4 bq0,bq1,bq2,bq3,bq4,bq5;
  uint4 br0,br1,br2,br3,br4,br5;

  W1L(0,0) W1L(1,1) W1L(2,2) W1L(3,3) W1L(4,4) W1L(5,5)
  f32x4 c0 = {0.f,0.f,0.f,0.f}, c1 = c0;
  W1C(0) W1L(0,6)
  W1C(1) W1L(1,7)
  W1C(2) W1L(2,8)
  W1C(3) W1L(3,9)
  W1C(4) W1L(4,10)
  W1C(5) W1L(5,11)
  W1C(0) W1L(0,12)
  W1C(1) W1L(1,13)
  W1C(2) W1L(2,14)
  W1C(3) W1L(3,15)
  W1C(4) W1L(4,16)
  W1C(5) W1L(5,17)
  W1C(0) W1L(0,18)
  W1C(1) W1L(1,19)
  W1C(2) W1L(2,20)
  W1C(3) W1L(3,21)
  W1C(4) W1L(4,22)
  W1C(5) W1L(5,23)
  W1C(0) W1L(0,24)
  W1C(1) W1L(1,25)
  W1C(2) W1L(2,26)
  W1C(3) W1L(3,27)
  W1C(4) W1L(4,28)
  W1C(5) W1L(5,29)
  W1C(0) W1L(0,30)
  W1C(1) W1L(1,31)
  W1C(2)
  W1C(3)
  W1C(4)
  W1C(5)
  W1C(0)
  W1C(1)
  #pragma unroll
  for (int r = 0; r < 4; ++r){
    int row = r0w + lb*4 + r;
    hhpre[(size_t)row*1792 + ug0*16 + la] = c0[r] + sb1a;
    hhpre[(size_t)row*1792 + ug1*16 + la] = c1[r] + sb1b;
  }
}

// ---------------- pipelined generic GEMM (preamble only) ----------------
__global__ __launch_bounds__(256) void gemm64(
    const bf16* __restrict__ Am, const bf16* __restrict__ Bm, int K,
    const float* __restrict__ bias, const float* __restrict__ addmat,
    float* __restrict__ C, bf16* __restrict__ Cbf, int N, int MODE)
{
  __shared__ bf16 As[3][64*64];
  __shared__ bf16 Bs[3][64*64];
  const int tid = threadIdx.x;
  const int wave = tid >> 6, lane = tid & 63;
  const int m0 = blockIdx.x*64, n0 = blockIdx.y*64;
  const int fr = lane & 31, kh = lane >> 5;
  const int wm = (wave >> 1)*32, wn = (wave & 1)*32;
  const int KT = K >> 6;

  f32x16 acc = {0.f,0.f,0.f,0.f,0.f,0.f,0.f,0.f,0.f,0.f,0.f,0.f,0.f,0.f,0.f,0.f};

  auto STAGE = [&](int buf, int kt){
    #pragma unroll
    for (int q = 0; q < 2; ++q){
      int idx = q*256 + tid;
      int row = idx >> 3, cp = idx & 7, csw = cp ^ (row & 7);
      GLD16(&As[buf][idx*8], Am + (size_t)(m0+row)*K + kt*64 + csw*8);
    }
    #pragma unroll
    for (int q = 0; q < 2; ++q){
      int idx = q*256 + tid;
      int row = idx >> 3, cp = idx & 7, csw = cp ^ (row & 7);
      GLD16(&Bs[buf][idx*8], Bm + (size_t)(n0+row)*K + kt*64 + csw*8);
    }
  };
  auto COMPUTE = [&](int buf){
    const bf16* Ab = &As[buf][0];
    const bf16* Bb = &Bs[buf][0];
    #pragma unroll
    for (int ks = 0; ks < 4; ++ks){
      int ca = ks*2 + kh;
      v8bf av = *(const v8bf*)&Ab[(wm+fr)*64 + ((ca ^ ((wm+fr)&7))*8)];
      v8bf bv = *(const v8bf*)&Bb[(wn+fr)*64 + ((ca ^ ((wn+fr)&7))*8)];
      acc = __builtin_amdgcn_mfma_f32_32x32x16_bf16(av, bv, acc, 0, 0, 0);
    }
  };

  STAGE(0, 0);
  if (KT > 1){ STAGE(1, 1); VMWAIT(4); } else { VMWAIT(0); }
  BARRIER();
  for (int kt = 0; kt < KT; ++kt){
    if (kt + 2 < KT) STAGE((kt+2)%3, kt+2);
    COMPUTE(kt%3);
    if (kt + 2 < KT){ VMWAIT(4); BARRIER(); }
    else if (kt + 1 < KT){ VMWAIT(0); BARRIER(); }
  }

  const int col = n0 + wn + fr;
  float bb = bias ? bias[col] : 0.f;
  #pragma unroll
  for (int r = 0; r < 16; ++r){
    int row = m0 + wm + (r&3) + 8*(r>>2) + 4*kh;
    float v = acc[r] + bb;
    if (MODE == 1) v = fmaxf(v, 0.f) + addmat[(size_t)row*N + col];
    if (C)   C[(size_t)row*N + col] = v;
    if (Cbf) Cbf[(size_t)row*N + col] = __float2bfloat16(v);
  }
}

// ---------------- attention: one block per (b,h) ----------------
__global__ __launch_bounds__(256) void k_attn(const bf16* __restrict__ qkv,
                                              bf16* __restrict__ ctxbf){
  __shared__ char smem[65536];
  bf16* qs = (bf16*)smem;
  bf16* ks = qs + 64*256;
  float* sc = (float*)smem;
  float* cs = (float*)(smem + 32768);
  const int h = blockIdx.x, b = blockIdx.y;
  const int tid = threadIdx.x, wave = tid >> 6, lane = tid & 63;
  const int fr = lane & 31, kh = lane >> 5;
  const int wm = (wave >> 1)*32, wn = (wave & 1)*32;

  #pragma unroll
  for (int i = 0; i < 8; ++i){
    int idx = i*256 + tid;
    int row = idx >> 5, cp = idx & 31, csw = cp ^ (row & 7);
    GLD16(&qs[idx*8], qkv + (size_t)(b*F_ + row)*3072 + h*DH_ + csw*8);
  }
  #pragma unroll
  for (int i = 0; i < 8; ++i){
    int idx = i*256 + tid;
    int row = idx >> 5, cp = idx & 31, csw = cp ^ (row & 7);
    GLD16(&ks[idx*8], qkv + (size_t)(b*F_ + row)*3072 + H_ + h*DH_ + csw*8);
  }
  __syncthreads();

  f32x16 acc = {0.f,0.f,0.f,0.f,0.f,0.f,0.f,0.f,0.f,0.f,0.f,0.f,0.f,0.f,0.f,0.f};
  #pragma unroll
  for (int i = 0; i < 16; ++i){
    int ca = i*2 + kh;
    v8bf av = *(const v8bf*)&qs[((wm+fr)*32 + (ca ^ ((wm+fr)&7)))*8];
    v8bf bv = *(const v8bf*)&ks[((wn+fr)*32 + (ca ^ ((wn+fr)&7)))*8];
    acc = __builtin_amdgcn_mfma_f32_32x32x16_bf16(av, bv, acc, 0, 0, 0);
  }
  __syncthreads();
  #pragma unroll
  for (int r = 0; r < 16; ++r){
    int row = wm + (r&3) + 8*(r>>2) + 4*kh;
    sc[row*65 + (wn+fr)] = acc[r]*0.0625f;
  }
  __syncthreads();
  if (tid < F_){
    float m = -1e30f;
    for (int k2 = 0; k2 < F_; ++k2) m = fmaxf(m, sc[tid*65+k2]);
    float s = 0.f;
    for (int k2 = 0; k2 < F_; ++k2){ float e = __expf(sc[tid*65+k2]-m); sc[tid*65+k2] = e; s += e; }
    float is = 1.f/s;
    for (int k2 = 0; k2 < F_; ++k2) sc[tid*65+k2] *= is;
  }
  __syncthreads();
  if (tid < F_){
    float s = 0.f;
    for (int r = 0; r < F_; ++r) s += sc[r*65+tid];
    cs[tid] = s;
  }
  __syncthreads();
  float a = 0.f;
  for (int k2 = 0; k2 < F_; ++k2){
    float v = __bfloat162float(qkv[(size_t)(b*F_+k2)*3072 + 2*H_ + h*DH_ + tid]);
    a += cs[k2]*v;
  }
  ctxbf[(size_t)b*H_ + h*DH_ + tid] = __float2bfloat16(a * (1.f/61.f));
}

// ---------------- SPL final step ----------------
__global__ __launch_bounds__(128) void spl_all(const float* __restrict__ hh_pre, const float* __restrict__ w1par,
                        const float* __restrict__ W2, const float* __restrict__ b2,
                        float* __restrict__ x, bf16* __restrict__ xpk,
                        float* __restrict__ out, int tstep){
  __shared__ float preds_s[4][128];
  __shared__ float hh_s[128][5];
  int b0 = blockIdx.x*4, t = threadIdx.x;   // grid 64, block 128
  for (int L = 0; L < 3; ++L){
    for (int ji = LVO[L]; ji < LVO[L+1]; ++ji){
      int j = LVJ[ji], p = PAR_[j];
      float acc[4];
      #pragma unroll
      for (int bb = 0; bb < 4; ++bb) acc[bb] = hh_pre[(size_t)(b0+bb)*1792 + j*128 + t];
      if (p >= 0){
        #pragma unroll
        for (int ii = 0; ii < 9; ++ii){
          float w = w1par[(j*9 + ii)*128 + t];
          #pragma unroll
          for (int bb = 0; bb < 4; ++bb) acc[bb] += w * preds_s[bb][p*9 + ii];
        }
      }
      #pragma unroll
      for (int bb = 0; bb < 4; ++bb) hh_s[t][bb] = fmaxf(acc[bb], 0.f);
      __syncthreads();
      if (t < 72){
        int pp = t >> 1, half = t & 1;
        int bb = pp/9, oi = pp%9;
        const float* w2r = W2 + (size_t)(j*9 + oi)*128 + half*64;
        float s = 0.f;
        #pragma unroll
        for (int tt = 0; tt < 64; ++tt) s += hh_s[half*64 + tt][bb] * w2r[tt];
        s += __shfl_xor(s, 1);
        if (half == 0) preds_s[bb][j*9 + oi] = tanhf(s + b2[j*9 + oi]);
      }
      __syncthreads();
    }
  }
  for (int i = t; i < 4*D_; i += 128){
    int bb = i / D_, d = i % D_;
    int row = b0 + bb;
    size_t xi = (size_t)row*D_ + d;
    float v = x[xi] + preds_s[bb][d];
    x[xi] = v;
    xpk[((row>>5)*4 + (d>>5))*1024 + (row&31)*32 + (d&31)] = __float2bfloat16(v);
    out[((size_t)row*PRED_ + tstep)*D_ + d] = v;
  }
}

// ---------------- launch ----------------
extern "C" void kernel_launch(void* const* d_in, const int* in_sizes, int n_in,
                              void* d_out, int out_size, void* d_ws, size_t ws_size,
                              hipStream_t stream){
  (void)in_sizes; (void)n_in; (void)out_size; (void)ws_size;
  const float* poses = (const float*)d_in[0];
  const float* gWih  = (const float*)d_in[1];
  const float* gWhh  = (const float*)d_in[2];
  const float* gbih  = (const float*)d_in[3];
  const float* gbhh  = (const float*)d_in[4];
  const float* preW  = (const float*)d_in[5];
  const float* preb  = (const float*)d_in[6];
  const float* fpW   = (const float*)d_in[7];
  const float* fpb   = (const float*)d_in[8];
  const float* inW   = (const float*)d_in[9];
  const float* inb   = (const float*)d_in[10];
  const float* outW  = (const float*)d_in[11];
  const float* outb  = (const float*)d_in[12];
  const float* sW1   = (const float*)d_in[13];
  const float* sb1   = (const float*)d_in[14];
  const float* sW2   = (const float*)d_in[15];
  const float* sb2   = (const float*)d_in[16];
  float* out = (float*)d_out;

  char* w = (char*)d_ws;
  size_t off = 0;
  auto alloc = [&](size_t bytes)->char*{ char* p = w + off; off += (bytes + 255) & ~(size_t)255; return p; };
  float* cosT   = (float*)alloc(7320*4);
  float* bc     = (float*)alloc(3072*4);
  float* motion = (float*)alloc((size_t)256*1024*4);
  float* hA     = (float*)alloc((size_t)256*1024*4);
  float* hB     = (float*)alloc((size_t)256*1024*4);
  float* xcur   = (float*)alloc((size_t)256*126*4);
  float* hhpre  = (float*)alloc((size_t)256*1792*4);
  float* bcat   = (float*)alloc(4096*4);
  float* w1par  = (float*)alloc(14*9*128*4);
  unsigned* prog= (unsigned*)alloc(4096);
  bf16* posespk = (bf16*)alloc((size_t)121*32768*2);
  bf16* Wcat    = (bf16*)alloc((size_t)4096*1152*2);
  bf16* Wpk     = (bf16*)alloc((size_t)64*108*512*2);
  bf16* w1pk    = (bf16*)alloc((size_t)112*32*512*2);
  bf16* prebf   = (bf16*)alloc((size_t)1024*1024*2);
  bf16* outbf   = (bf16*)alloc((size_t)1024*1024*2);
  bf16* inbf    = (bf16*)alloc((size_t)3072*1024*2);
  bf16* fpwt    = (bf16*)alloc((size_t)128*1024*2);
  bf16* ctxbf   = (bf16*)alloc((size_t)256*1024*2);
  bf16* hpkA    = (bf16*)alloc((size_t)256*1024*2);
  bf16* hpkB    = (bf16*)alloc((size_t)256*1024*2);
  bf16* hbplain = (bf16*)alloc((size_t)256*1024*2);
  bf16* hidpk   = (bf16*)alloc((size_t)256*1024*2);
  bf16* xpk     = (bf16*)alloc((size_t)32768*2);
  bf16* Wcbf    = (bf16*)alloc((size_t)3072*128*2);
  bf16* freqbf  = (bf16*)alloc((size_t)B_*F_*128*2);
  bf16* qkvbf   = (bf16*)alloc((size_t)15680*3072*2);

  hipMemsetAsync(hpkA, 0, (size_t)256*1024*2, stream);
  hipMemsetAsync(prog, 0, 4096, stream);

  k_cos<<<29, 256, 0, stream>>>(cosT);
  k_dft2<<<B_, 256, 0, stream>>>(poses, cosT, freqbf);
  c_poses<<<dim3(SEED_, B_), 128, 0, stream>>>(poses, posespk);
  c_xinit<<<B_, 128, 0, stream>>>(poses, xcur, xpk);
  c_wcat<<<4096, 256, 0, stream>>>(gWih, gWhh, Wcat);
  c_bcat<<<16, 256, 0, stream>>>(gbih, gbhh, bcat);
  c_wpk<<<1728, 256, 0, stream>>>(Wcat, Wpk);
  c_w1pk<<<896, 256, 0, stream>>>(sW1, w1pk);
  c_w1par<<<63, 256, 0, stream>>>(sW1, w1par);
  c_bf<<<4096, 256, 0, stream>>>(preW, prebf, 1024*1024);
  c_bf<<<4096, 256, 0, stream>>>(outW, outbf, 1024*1024);
  c_bf<<<12288, 256, 0, stream>>>(inW, inbf, 3072*1024);
  c_fpwt<<<128, 256, 0, stream>>>(fpW, fpwt);
  k_bc<<<768, 256, 0, stream>>>(inW, inb, fpb, bc);

  // Wc = inproj @ fp_W  (3072 x 128, bf16)
  gemm64<<<dim3(48, 2), 256, 0, stream>>>(inbf, fpwt, 1024, nullptr, nullptr, nullptr, Wcbf, 128, 0);
  // qkv = freq @ Wc^T + bc  (15616 x 3072, bf16)
  gemm64<<<dim3(244, 48), 256, 0, stream>>>(freqbf, Wcbf, 128, bc, nullptr, nullptr, qkvbf, 3072, 0);
  k_attn<<<dim3(HEADS_, B_), 256, 0, stream>>>(qkvbf, ctxbf);
  // motion_ctx = ctx_mean @ outproj^T + outb
  gemm64<<<dim3(4, 16), 256, 0, stream>>>(ctxbf, outbf, 1024, outb, nullptr, motion, nullptr, 1024, 0);

  // encoder: cooperative, 256 blocks x 256 threads (all CUs), fence-free coherent h
  {
    const bf16* a0 = posespk; int a1 = 32768; int a2 = SEED_; int a3 = 1;
    const bf16* a4 = Wpk; const float* a5 = bcat;
    const float* a6 = hA; float* a7 = hA; bf16* a8 = nullptr;
    bf16* a9 = hpkA; bf16* a10 = hpkB; unsigned* a11 = prog;
    void* args[] = { &a0, &a1, &a2, &a3, &a4, &a5, &a6, &a7, &a8, &a9, &a10, &a11 };
    hipLaunchCooperativeKernel(reinterpret_cast<void*>(gru_wave), dim3(256), dim3(256),
                               args, 0, stream);
  }

  float* hc = hA;  float* hn = hB;
  bf16* hpc = hpkA; bf16* hpn = hpkB;
  unsigned* progS = prog + 256;
  unsigned* progP = prog + 512;

  // decoder: 24 steps x { gru_spl (SPL(t-1)+GRU(t), 256x256), gemm_pw (pre+W1) }; final SPL
  for (int t = 0; t < PRED_; ++t){
    gru_spl<<<256, 256, 0, stream>>>(xpk, Wpk, bcat, hc, hn, hbplain, hpc, hpn,
                                     hhpre, w1par, sW2, sb2, xcur, xpk, out, t, progS);
    { float* tf = hc; hc = hn; hn = tf; bf16* tb = hpc; hpc = hpn; hpn = tb; }
    gemm_pw<<<112, 512, 0, stream>>>(hbplain, prebf, preb, motion, hidpk, w1pk, sb1, hhpre, t, progP);
  }
  spl_all<<<64, 128, 0, stream>>>(hhpre, w1par, sW2, sb2, xcur, xpk, out, PRED_-1);
}

// Round 19
// 2357.523 us; speedup vs baseline: 1.8660x; 1.1069x over previous
//
#include <hip/hip_runtime.h>
#include <hip/hip_bf16.h>

typedef __hip_bfloat16 bf16;
typedef __attribute__((ext_vector_type(8))) short v8bf;     // 8 bf16 (4 VGPR)
typedef __attribute__((ext_vector_type(16))) float f32x16;
typedef __attribute__((ext_vector_type(4))) float f32x4;
typedef unsigned long long ull;

#define B_    256
#define SEED_ 120
#define PRED_ 24
#define D_    126
#define H_    1024
#define F_    61
#define HEADS_ 4
#define DH_   256

#define GLD16(lds, g) __builtin_amdgcn_global_load_lds( \
    (const __attribute__((address_space(1))) unsigned int*)(g), \
    (__attribute__((address_space(3))) unsigned int*)(lds), 16, 0, 0)
#define VMWAIT(n) asm volatile("s_waitcnt vmcnt(" #n ")" ::: "memory")
#define BARRIER() do { __builtin_amdgcn_s_barrier(); __builtin_amdgcn_sched_barrier(0); } while(0)
#define AL(P) __hip_atomic_load((P), __ATOMIC_RELAXED, __HIP_MEMORY_SCOPE_AGENT)

// ---------------- small precompute kernels ----------------
__global__ void k_cos(float* cosT){
  int i = blockIdx.x*256 + threadIdx.x;
  if (i < F_*SEED_){
    int f = i / SEED_, t = i % SEED_;
    int ph = (f*t) % SEED_;
    cosT[i] = cosf(6.283185307179586f * (float)ph / (float)SEED_);
  }
}

__global__ __launch_bounds__(256) void k_dft2(const float* __restrict__ poses,
                      const float* __restrict__ cosT, bf16* __restrict__ freqbf){
  __shared__ float pl[SEED_*128];      // 60 KB
  int b = blockIdx.x, tid = threadIdx.x;
  for (int i = tid; i < SEED_*D_; i += 256){
    int t = i / D_, d = i - t*D_;
    pl[t*128 + d] = poses[((size_t)b*(SEED_+PRED_) + t)*D_ + d];
  }
  __syncthreads();
  int d = tid & 127, f0 = tid >> 7;    // f = f0 + 2j
  float acc[31];
  #pragma unroll
  for (int j = 0; j < 31; ++j) acc[j] = 0.f;
  for (int t = 0; t < SEED_; ++t){
    float v = pl[t*128 + d];
    #pragma unroll
    for (int j = 0; j < 31; ++j){
      int f = f0 + j*2;
      if (f < F_) acc[j] += cosT[f*SEED_ + t] * v;
    }
  }
  #pragma unroll
  for (int j = 0; j < 31; ++j){
    int f = f0 + j*2;
    if (f < F_) freqbf[((size_t)b*F_ + f)*128 + d] = __float2bfloat16(d < D_ ? acc[j] : 0.f);
  }
}

// pack poses into per-step 32x32 tiles
__global__ void c_poses(const float* __restrict__ poses, bf16* __restrict__ pk){
  int t = blockIdx.x, b = blockIdx.y, c = threadIdx.x;  // block 128
  float v = (c < D_) ? poses[((size_t)b*(SEED_+PRED_) + t)*D_ + c] : 0.f;
  pk[(size_t)t*32768 + ((b>>5)*4 + (c>>5))*1024 + (b&31)*32 + (c&31)] = __float2bfloat16(v);
}

__global__ void c_xinit(const float* __restrict__ poses, float* __restrict__ x, bf16* __restrict__ xpk){
  int b = blockIdx.x, c = threadIdx.x;  // block 128
  float v = (c < D_) ? poses[((size_t)b*(SEED_+PRED_) + (SEED_-1))*D_ + c] : 0.f;
  if (c < D_) x[b*D_ + c] = v;
  xpk[((b>>5)*4 + (c>>5))*1024 + (b&31)*32 + (c&31)] = __float2bfloat16(v);
}

__global__ void c_bf(const float* __restrict__ s, bf16* __restrict__ d, int n){
  int i = blockIdx.x*256 + threadIdx.x;
  if (i < n) d[i] = __float2bfloat16(s[i]);
}

__global__ void c_fpwt(const float* __restrict__ fpW, bf16* __restrict__ o){
  int dd = blockIdx.x;                       // 0..127
  for (int k = threadIdx.x; k < H_; k += 256)
    o[(size_t)dd*H_ + k] = __float2bfloat16(dd < D_ ? fpW[(size_t)k*D_ + dd] : 0.f);
}

// combined GRU weight rows (1152 wide: 128 x-cols | 1024 h-cols)
__global__ void c_wcat(const float* __restrict__ Wih, const float* __restrict__ Whh, bf16* __restrict__ o){
  int r = blockIdx.x;
  int jr; bool hasx, hash;
  if (r < 2048){ jr = r; hasx = true; hash = true; }
  else if (r < 3072){ jr = r; hasx = true; hash = false; }
  else { jr = r - 1024; hasx = false; hash = true; }
  bf16* row = o + (size_t)r*1152;
  for (int c = threadIdx.x; c < 1152; c += 256){
    float v = 0.f;
    if (c < D_) { if (hasx) v = Wih[(size_t)jr*D_ + c]; }
    else if (c >= 128){ if (hash) v = Whh[(size_t)jr*H_ + (c-128)]; }
    row[c] = __float2bfloat16(v);
  }
}

__global__ void c_bcat(const float* __restrict__ bih, const float* __restrict__ bhh, float* __restrict__ o){
  int r = blockIdx.x*256 + threadIdx.x;
  if (r >= 4096) return;
  float v;
  if (r < 2048) v = bih[r] + bhh[r];
  else if (r < 3072) v = bih[r];
  else v = bhh[r - 1024];
  o[r] = v;
}

// pack GRU weights into MFMA B-fragment order
__global__ __launch_bounds__(256) void c_wpk(const bf16* __restrict__ Wcat, bf16* __restrict__ Wpk){
  int chunk = blockIdx.x*4 + (threadIdx.x >> 6);
  int l = threadIdx.x & 63;
  int ks = chunk % 36; int t2 = chunk / 36; int g = t2 % 3; int ub = t2 / 3;
  int unit = ub*16 + (l & 15);
  bf16* dst = Wpk + (size_t)chunk*512 + l*8;
  #pragma unroll
  for (int e = 0; e < 8; ++e){
    int k = ks*32 + (l>>4)*8 + e;
    int row = (g==0) ? unit : (g==1) ? (1024+unit) : (k < 128 ? 2048+unit : 3072+unit);
    dst[e] = Wcat[(size_t)row*1152 + k];
  }
}

// pack preW into fragment order: chunk = ub*32+ks  (2048 chunks)
__global__ __launch_bounds__(256) void c_ppk(const float* __restrict__ preW, bf16* __restrict__ prepk){
  int chunk = blockIdx.x*4 + (threadIdx.x >> 6);
  int l = threadIdx.x & 63;
  int ks = chunk & 31, ub = chunk >> 5;
  int unit = ub*16 + (l & 15);
  bf16* dst = prepk + (size_t)chunk*512 + l*8;
  #pragma unroll
  for (int e = 0; e < 8; ++e)
    dst[e] = __float2bfloat16(preW[(size_t)unit*1024 + ks*32 + (l>>4)*8 + e]);
}

// pack W1-hid into fragment order: chunk = ug*32+ks, ug 0..111
__global__ __launch_bounds__(256) void c_w1pk(const float* __restrict__ sW1, bf16* __restrict__ w1pk){
  int chunk = blockIdx.x*4 + (threadIdx.x >> 6);   // 3584 chunks
  int l = threadIdx.x & 63;
  int ks = chunk & 31, ng = chunk >> 5;
  int unit = ng*16 + (l & 15);
  int j = unit >> 7, rr = unit & 127;
  bf16* dst = w1pk + (size_t)chunk*512 + l*8;
  #pragma unroll
  for (int e = 0; e < 8; ++e){
    int k = ks*32 + (l>>4)*8 + e;
    dst[e] = __float2bfloat16(sW1[((size_t)j*128 + rr)*1033 + k]);
  }
}

// pack SPL parent weights
__global__ void c_w1par(const float* __restrict__ sW1, float* __restrict__ w1par){
  int i = blockIdx.x*256 + threadIdx.x;
  if (i < 14*9*128){
    int j = i / (9*128); int rem = i % (9*128); int ii = rem / 128; int th = rem % 128;
    w1par[i] = sW1[((size_t)(j*128 + th))*1033 + 1024 + ii];
  }
}

// bc = inproj @ fp_b + in_b
__global__ __launch_bounds__(256) void k_bc(const float* __restrict__ inW, const float* __restrict__ inb,
                     const float* __restrict__ fpb, float* __restrict__ bc){
  int wave = threadIdx.x >> 6, lane = threadIdx.x & 63;
  int r = blockIdx.x*4 + wave;
  const float4* row = (const float4*)(inW + (size_t)r*H_);
  const float4* fp4 = (const float4*)fpb;
  float s = 0.f;
  #pragma unroll
  for (int i = 0; i < 4; ++i){
    float4 a = row[lane + i*64];
    float4 b = fp4[lane + i*64];
    s += a.x*b.x + a.y*b.y + a.z*b.z + a.w*b.w;
  }
  #pragma unroll
  for (int off = 32; off; off >>= 1) s += __shfl_down(s, off);
  if (lane == 0) bc[r] = s + inb[r];
}

// ---------------- encoder: wave-autonomous GRU, 256 blocks x 4 waves (R17) ----------------
#define SLCP(QA, QB, KS, GACC) { \
  union { ull u[2]; v8bf v; } cc_; cc_.u[0]=(QA); cc_.u[1]=(QB); \
  v8bf a_ = cc_.v; \
  v8bf w0_ = *(const v8bf*)&Wl[(0*36+(KS))*512 + lane*8]; \
  v8bf w1_ = *(const v8bf*)&Wl[(1*36+(KS))*512 + lane*8]; \
  v8bf w2_ = *(const v8bf*)&Wl[(2*36+(KS))*512 + lane*8]; \
  aR = __builtin_amdgcn_mfma_f32_16x16x32_bf16(a_, w0_, aR, 0,0,0); \
  aZ = __builtin_amdgcn_mfma_f32_16x16x32_bf16(a_, w1_, aZ, 0,0,0); \
  GACC = __builtin_amdgcn_mfma_f32_16x16x32_bf16(a_, w2_, GACC, 0,0,0); }

#define LDHA(DA, DB, C) { \
  const ull* hp_ = (const ull*)(hs + hbase + (size_t)(C)*1024); \
  DA = AL(hp_); DB = AL(hp_+1); }

#define LDXP(DA, DB, TT, C) { \
  const ull* xp_ = (const ull*)(xpk + (size_t)(TT)*xstride + xbase + (size_t)(C)*1024); \
  DA = xp_[0]; DB = xp_[1]; }

__global__ __launch_bounds__(256) void gru_wave(
    const bf16* __restrict__ xpk, int xstride, int nsteps, int coop,
    const bf16* __restrict__ Wpk, const float* __restrict__ bcat,
    const float* __restrict__ hin_plain, float* __restrict__ hout_plain,
    bf16* __restrict__ hbplain,
    bf16* __restrict__ hpk0, bf16* __restrict__ hpk1,
    unsigned* __restrict__ prog)
{
  __shared__ bf16 Wl[3*36*512];       // 108 KB
  const int tid = threadIdx.x, wave = tid >> 6, lane = tid & 63;
  const int ub = blockIdx.x & 63, q = blockIdx.x >> 6;
  const int u0 = ub*16;

  {
    const bf16* wsrc = Wpk + (size_t)ub*(3*36*512);
    #pragma unroll
    for (int i = 0; i < 27; ++i){
      int c = i*256 + tid;
      GLD16(&Wl[c*8], wsrc + (size_t)c*8);
    }
  }
  VMWAIT(0); BARRIER();

  const int la = lane & 15, lb = lane >> 4;
  const int r0 = q*64 + wave*16;
  const int rb = r0 >> 5, y = wave & 1;
  const int ucol = u0 + la;
  const float bR = bcat[ucol], bZ = bcat[1024+ucol], bI = bcat[2048+ucol], bN = bcat[3072+ucol];
  const size_t hbase = (size_t)rb*32768 + (size_t)y*512 + la*32 + lb*8;
  const size_t xbase = (size_t)rb*4096  + (size_t)y*512 + la*32 + lb*8;
  const size_t pwb = (size_t)rb*32768 + (size_t)(u0>>5)*1024 + (size_t)y*512 + (u0&16) + la;

  float hr[4];
  if (nsteps == 1){
    #pragma unroll
    for (int r = 0; r < 4; ++r) hr[r] = hin_plain[(size_t)(r0 + lb*4 + r)*1024 + ucol];
  } else {
    #pragma unroll
    for (int r = 0; r < 4; ++r) hr[r] = 0.f;
  }

  ull a0,a1,a2,a3,a4,a5,a6,a7,a8,a9,a10,a11;
  ull b0,b1,b2,b3,b4,b5,b6,b7,b8,b9,b10,b11;
  LDXP(a0,b0,0,0); LDXP(a1,b1,0,1); LDXP(a2,b2,0,2); LDXP(a3,b3,0,3);

  for (int t = 0; t < nsteps; ++t){
    if (coop && t > 0){
      if (wave == 0){
        unsigned v = AL(&prog[q*64 + lane]);
        while (__ballot(v >= (unsigned)t) != ~0ULL){
          __builtin_amdgcn_s_sleep(1);
          v = AL(&prog[q*64 + lane]);
        }
      }
      __syncthreads();
      __builtin_amdgcn_sched_barrier(0);
    }
    const bf16* hs = (t & 1) ? hpk1 : hpk0;
    LDHA(a4,b4,0) LDHA(a5,b5,1) LDHA(a6,b6,2) LDHA(a7,b7,3)
    LDHA(a8,b8,4) LDHA(a9,b9,5) LDHA(a10,b10,6) LDHA(a11,b11,7)

    f32x4 z4 = {0.f,0.f,0.f,0.f};
    f32x4 aR = z4, aZ = z4, aI = z4, aN = z4;

    SLCP(a0,b0,0,aI)  LDHA(a0,b0,8)
    SLCP(a1,b1,1,aI)  LDHA(a1,b1,9)
    SLCP(a2,b2,2,aI)  LDHA(a2,b2,10)
    SLCP(a3,b3,3,aI)  LDHA(a3,b3,11)
    SLCP(a4,b4,4,aN)  LDHA(a4,b4,12)
    SLCP(a5,b5,5,aN)  LDHA(a5,b5,13)
    SLCP(a6,b6,6,aN)  LDHA(a6,b6,14)
    SLCP(a7,b7,7,aN)  LDHA(a7,b7,15)
    SLCP(a8,b8,8,aN)  LDHA(a8,b8,16)
    SLCP(a9,b9,9,aN)  LDHA(a9,b9,17)
    SLCP(a10,b10,10,aN) LDHA(a10,b10,18)
    SLCP(a11,b11,11,aN) LDHA(a11,b11,19)
    SLCP(a0,b0,12,aN) LDHA(a0,b0,20)
    SLCP(a1,b1,13,aN) LDHA(a1,b1,21)
    SLCP(a2,b2,14,aN) LDHA(a2,b2,22)
    SLCP(a3,b3,15,aN) LDHA(a3,b3,23)
    SLCP(a4,b4,16,aN) LDHA(a4,b4,24)
    SLCP(a5,b5,17,aN) LDHA(a5,b5,25)
    SLCP(a6,b6,18,aN) LDHA(a6,b6,26)
    SLCP(a7,b7,19,aN) LDHA(a7,b7,27)
    SLCP(a8,b8,20,aN) LDHA(a8,b8,28)
    SLCP(a9,b9,21,aN) LDHA(a9,b9,29)
    SLCP(a10,b10,22,aN) LDHA(a10,b10,30)
    SLCP(a11,b11,23,aN) LDHA(a11,b11,31)
    SLCP(a0,b0,24,aN) LDXP(a0,b0,t+1,0)
    SLCP(a1,b1,25,aN) LDXP(a1,b1,t+1,1)
    SLCP(a2,b2,26,aN) LDXP(a2,b2,t+1,2)
    SLCP(a3,b3,27,aN) LDXP(a3,b3,t+1,3)
    SLCP(a4,b4,28,aN)
    SLCP(a5,b5,29,aN)
    SLCP(a6,b6,30,aN)
    SLCP(a7,b7,31,aN)
    SLCP(a8,b8,32,aN)
    SLCP(a9,b9,33,aN)
    SLCP(a10,b10,34,aN)
    SLCP(a11,b11,35,aN)

    bf16* hd = (t & 1) ? hpk0 : hpk1;
    const bool last = (t == nsteps-1);
    #pragma unroll
    for (int r = 0; r < 4; ++r){
      float rg = 1.f/(1.f + __expf(-(aR[r] + bR)));
      float zg = 1.f/(1.f + __expf(-(aZ[r] + bZ)));
      float ng = tanhf((aI[r] + bI) + rg*(aN[r] + bN));
      float hv = (1.f - zg)*ng + zg*hr[r];
      hr[r] = hv;
      bf16 hv16 = __float2bfloat16(hv);
      unsigned short hbits = *(unsigned short*)&hv16;
      __hip_atomic_store((unsigned short*)(hd + pwb + (size_t)(lb*4 + r)*32), hbits,
                         __ATOMIC_RELAXED, __HIP_MEMORY_SCOPE_AGENT);
      if (last){
        hout_plain[(size_t)(r0 + lb*4 + r)*1024 + ucol] = hv;
        if (hbplain) hbplain[(size_t)(r0 + lb*4 + r)*1024 + ucol] = __float2bfloat16(hv);
      }
    }
    if (coop && t + 1 < nsteps){
      VMWAIT(0);
      __syncthreads();
      if (tid == 0)
        __hip_atomic_store(&prog[q*64 + ub], (unsigned)(t+1), __ATOMIC_RELAXED, __HIP_MEMORY_SCOPE_AGENT);
    }
  }
}

// ---------------- merged decoder step: SPL(t-1) + GRU + pre + W1, one launch ----------------
__constant__ int LVJ[14] = {0,1,6,8,9, 2,3,7,10,11, 4,5,12,13};
__constant__ int LVO[4]  = {0,5,10,14};
__constant__ int PAR_[14] = {-1,-1,0,1,2,3,-1,6,-1,-1,8,9,10,11};

#define DGRL(S,C) { const ull* p_=(const ull*)(hspk + hbase + (size_t)(C)*1024); qa##S=AL(p_); qb##S=AL(p_+1); }
#define DGXL(S,C) { const ull* p_=(const ull*)(xpk + xbase + (size_t)(C)*1024); qa##S=AL(p_); qb##S=AL(p_+1); }
#define DGRC(S,KS,GACC) { union{ull u[2];v8bf v;}c_; c_.u[0]=qa##S;c_.u[1]=qb##S; v8bf a_=c_.v; \
  v8bf w0_=*(const v8bf*)&Wl[(KS)*512+lane*8]; \
  v8bf w1_=*(const v8bf*)&Wl[18432+(KS)*512+lane*8]; \
  v8bf w2_=*(const v8bf*)&Wl[36864+(KS)*512+lane*8]; \
  aR=__builtin_amdgcn_mfma_f32_16x16x32_bf16(a_,w0_,aR,0,0,0); \
  aZ=__builtin_amdgcn_mfma_f32_16x16x32_bf16(a_,w1_,aZ,0,0,0); \
  GACC=__builtin_amdgcn_mfma_f32_16x16x32_bf16(a_,w2_,GACC,0,0,0); }

// pre phase: ring reads h^t packed (hdpk) via IF atomics, B = Wp LDS
#define PRL(S,C) { const ull* p_=(const ull*)(hdpk + hbase + (size_t)(C)*1024); qa##S=AL(p_); qb##S=AL(p_+1); }
#define PRC(S,KS) { union{ull u[2];v8bf v;}c_; c_.u[0]=qa##S;c_.u[1]=qb##S; \
  aP=__builtin_amdgcn_mfma_f32_16x16x32_bf16(c_.v, *(const v8bf*)&Wp[(KS)*512+lane*8], aP,0,0,0); }

// W1 phase: 4-slot ring, A = hidpk IF atomics, 4 B streams from w1pk
#define WLD(S,C) { const ull* p_=(const ull*)(hidpk + w1abase + (size_t)(C)*1024); \
  wa##S=AL(p_); wb##S=AL(p_+1); \
  wq##S##0 = *(const uint4*)(w1b0 + (size_t)(C)*512 + lane*8); \
  wq##S##1 = *(const uint4*)(w1b1 + (size_t)(C)*512 + lane*8); \
  wq##S##2 = *(const uint4*)(w1b2 + (size_t)(C)*512 + lane*8); \
  wq##S##3 = *(const uint4*)(w1b3 + (size_t)(C)*512 + lane*8); }
#define WCC(S) { union{ull u[2];v8bf v;}x_; x_.u[0]=wa##S;x_.u[1]=wb##S; \
  union{uint4 q; v8bf v;}b_; \
  b_.q=wq##S##0; c0=__builtin_amdgcn_mfma_f32_16x16x32_bf16(x_.v,b_.v,c0,0,0,0); \
  b_.q=wq##S##1; c1=__builtin_amdgcn_mfma_f32_16x16x32_bf16(x_.v,b_.v,c1,0,0,0); \
  b_.q=wq##S##2; c2=__builtin_amdgcn_mfma_f32_16x16x32_bf16(x_.v,b_.v,c2,0,0,0); \
  b_.q=wq##S##3; c3=__builtin_amdgcn_mfma_f32_16x16x32_bf16(x_.v,b_.v,c3,0,0,0); }

__global__ __launch_bounds__(256) void dec_step(
    const bf16* __restrict__ xpk, const bf16* __restrict__ Wpk,
    const float* __restrict__ bcat,
    const float* __restrict__ hin_plain, float* __restrict__ hout_plain,
    const bf16* __restrict__ hspk, bf16* __restrict__ hdpk,
    const float* __restrict__ hhpre_in, float* __restrict__ hhpre_out,
    const float* __restrict__ w1par,
    const float* __restrict__ sW2, const float* __restrict__ sb2,
    const bf16* __restrict__ prepk, const float* __restrict__ preb,
    const float* __restrict__ motion, bf16* __restrict__ hidpk,
    const bf16* __restrict__ w1pk, const float* __restrict__ sb1,
    float* __restrict__ xcur, bf16* __restrict__ xpkw, float* __restrict__ out,
    int dt, unsigned* __restrict__ progS, unsigned* __restrict__ progG,
    unsigned* __restrict__ progH)
{
  __shared__ bf16 Wl[3*36*512];     // 108 KB GRU weights
  __shared__ bf16 Wp[32*512];       // 32 KB preW slice
  __shared__ float hhl[1792];       // 7 KB
  __shared__ float preds_s[128];
  __shared__ float hh_s[128];
  const int tid = threadIdx.x, wave = tid >> 6, lane = tid & 63;
  const int bid = blockIdx.x;
  const int ub = bid & 63, q = bid >> 6, u0 = ub*16;

  {  // weights -> LDS (async, overlaps SPL)
    const bf16* wsrc = Wpk + (size_t)ub*(3*36*512);
    #pragma unroll
    for (int i = 0; i < 27; ++i){ int c = i*256 + tid; GLD16(&Wl[c*8], wsrc + (size_t)c*8); }
    const bf16* psrc = prepk + (size_t)ub*(32*512);
    #pragma unroll
    for (int i = 0; i < 8; ++i){ int c = i*256 + tid; GLD16(&Wp[c*8], psrc + (size_t)c*8); }
  }

  // ---- phase 0: SPL of previous step (1 batch row per block) ----
  const int brow = bid, th = tid;
  if (dt > 0){
    for (int i = tid; i < 1792; i += 256) hhl[i] = hhpre_in[(size_t)brow*1792 + i];
    __syncthreads();
    for (int L = 0; L < 3; ++L){
      for (int ji = LVO[L]; ji < LVO[L+1]; ++ji){
        int j = LVJ[ji], p = PAR_[j];
        if (tid < 128){
          float a0s = hhl[j*128 + th];
          if (p >= 0){
            #pragma unroll
            for (int ii = 0; ii < 9; ++ii)
              a0s += w1par[(j*9 + ii)*128 + th] * preds_s[p*9 + ii];
          }
          hh_s[th] = fmaxf(a0s, 0.f);
        }
        __syncthreads();
        if (tid < 18){
          int oi = th >> 1, half = th & 1;
          const float4* w4 = (const float4*)(sW2 + (size_t)(j*9 + oi)*128 + half*64);
          float s = 0.f;
          #pragma unroll
          for (int q2 = 0; q2 < 16; ++q2){
            float4 wv = w4[q2];
            s += hh_s[half*64 + q2*4 + 0]*wv.x + hh_s[half*64 + q2*4 + 1]*wv.y
               + hh_s[half*64 + q2*4 + 2]*wv.z + hh_s[half*64 + q2*4 + 3]*wv.w;
          }
          s += __shfl_xor(s, 1);
          if (half == 0) preds_s[j*9 + oi] = tanhf(s + sb2[j*9 + oi]);
        }
        __syncthreads();
      }
    }
    if (tid < D_){
      int d = tid;
      size_t xi = (size_t)brow*D_ + d;
      float v = xcur[xi] + preds_s[d];
      xcur[xi] = v;
      bf16 v16 = __float2bfloat16(v);
      __hip_atomic_store((unsigned short*)(xpkw + ((size_t)(brow>>5)*4 + (d>>5))*1024 + (brow&31)*32 + (d&31)),
                         *(unsigned short*)&v16, __ATOMIC_RELAXED, __HIP_MEMORY_SCOPE_AGENT);
      out[((size_t)brow*PRED_ + (dt-1))*D_ + d] = v;
    }
    VMWAIT(0);
    __syncthreads();
    if (tid == 0)
      __hip_atomic_store(&progS[bid], (unsigned)dt, __ATOMIC_RELAXED, __HIP_MEMORY_SCOPE_AGENT);
  }

  VMWAIT(0); BARRIER();     // weights resident

  // ---- phase 1: GRU ----
  const int la = lane & 15, lb = lane >> 4;
  const int r0 = q*64 + wave*16;
  const int rb = r0 >> 5, y = wave & 1;
  const int ucol = u0 + la;
  const float bR = bcat[ucol], bZ = bcat[1024+ucol], bI = bcat[2048+ucol], bN = bcat[3072+ucol];
  const size_t hbase = (size_t)rb*32768 + (size_t)y*512 + la*32 + lb*8;
  const size_t xbase = (size_t)rb*4096  + (size_t)y*512 + la*32 + lb*8;
  const size_t pwb = (size_t)rb*32768 + (size_t)(u0>>5)*1024 + (size_t)y*512 + (u0&16) + la;

  float hr[4];
  #pragma unroll
  for (int r = 0; r < 4; ++r) hr[r] = hin_plain[(size_t)(r0 + lb*4 + r)*1024 + ucol];

  ull qa0,qa1,qa2,qa3,qa4,qa5,qa6,qa7,qa8,qa9,qa10,qa11;
  ull qb0,qb1,qb2,qb3,qb4,qb5,qb6,qb7,qb8,qb9,qb10,qb11;

  {
    DGRL(0,0) DGRL(1,1) DGRL(2,2) DGRL(3,3) DGRL(4,4) DGRL(5,5)
    DGRL(6,6) DGRL(7,7) DGRL(8,8) DGRL(9,9) DGRL(10,10) DGRL(11,11)
    f32x4 z4 = {0.f,0.f,0.f,0.f};
    f32x4 aR = z4, aZ = z4, aI = z4, aN = z4;
    DGRC(0,4,aN)  DGRL(0,12)
    DGRC(1,5,aN)  DGRL(1,13)
    DGRC(2,6,aN)  DGRL(2,14)
    DGRC(3,7,aN)  DGRL(3,15)
    DGRC(4,8,aN)  DGRL(4,16)
    DGRC(5,9,aN)  DGRL(5,17)
    DGRC(6,10,aN) DGRL(6,18)
    DGRC(7,11,aN) DGRL(7,19)
    DGRC(8,12,aN) DGRL(8,20)
    DGRC(9,13,aN) DGRL(9,21)
    DGRC(10,14,aN) DGRL(10,22)
    DGRC(11,15,aN) DGRL(11,23)
    DGRC(0,16,aN) DGRL(0,24)
    DGRC(1,17,aN) DGRL(1,25)
    DGRC(2,18,aN) DGRL(2,26)
    DGRC(3,19,aN) DGRL(3,27)
    DGRC(4,20,aN) DGRL(4,28)
    DGRC(5,21,aN) DGRL(5,29)
    DGRC(6,22,aN) DGRL(6,30)
    DGRC(7,23,aN) DGRL(7,31)
    DGRC(8,24,aN)
    DGRC(9,25,aN)
    DGRC(10,26,aN)
    DGRC(11,27,aN)
    DGRC(0,28,aN)
    DGRC(1,29,aN)
    DGRC(2,30,aN)
    DGRC(3,31,aN)
    DGRC(4,32,aN)
    DGRC(5,33,aN)
    DGRC(6,34,aN)
    DGRC(7,35,aN)
    // wait for all 256 blocks' SPL (x^t ready); each wave polls its 64-flag segment
    if (dt > 0){
      unsigned v = AL(&progS[wave*64 + lane]);
      while (__ballot(v >= (unsigned)dt) != ~0ULL){
        __builtin_amdgcn_s_sleep(2);
        v = AL(&progS[wave*64 + lane]);
      }
      __syncthreads();
      __builtin_amdgcn_sched_barrier(0);
    }
    DGXL(8,0) DGXL(9,1) DGXL(10,2) DGXL(11,3)
    DGRC(8,0,aI)
    DGRC(9,1,aI)
    DGRC(10,2,aI)
    DGRC(11,3,aI)
    #pragma unroll
    for (int r = 0; r < 4; ++r){
      float rg = 1.f/(1.f + __expf(-(aR[r] + bR)));
      float zg = 1.f/(1.f + __expf(-(aZ[r] + bZ)));
      float ng = tanhf((aI[r] + bI) + rg*(aN[r] + bN));
      float hv = (1.f - zg)*ng + zg*hr[r];
      bf16 hv16 = __float2bfloat16(hv);
      __hip_atomic_store((unsigned short*)(hdpk + pwb + (size_t)(lb*4 + r)*32),
                         *(unsigned short*)&hv16, __ATOMIC_RELAXED, __HIP_MEMORY_SCOPE_AGENT);
      hout_plain[(size_t)(r0 + lb*4 + r)*1024 + ucol] = hv;
    }
  }
  VMWAIT(0);
  __syncthreads();
  if (tid == 0)
    __hip_atomic_store(&progG[bid], (unsigned)(dt+1), __ATOMIC_RELAXED, __HIP_MEMORY_SCOPE_AGENT);

  // ---- phase 2: pre (hid = relu(h^t@preW^T + preb) + motion) ----
  // wait for this quarter's 64 GRU flags
  if (wave == 0){
    unsigned v = AL(&progG[q*64 + lane]);
    while (__ballot(v >= (unsigned)(dt+1)) != ~0ULL){
      __builtin_amdgcn_s_sleep(2);
      v = AL(&progG[q*64 + lane]);
    }
  }
  __syncthreads();
  __builtin_amdgcn_sched_barrier(0);
  {
    PRL(0,0) PRL(1,1) PRL(2,2) PRL(3,3) PRL(4,4) PRL(5,5)
    PRL(6,6) PRL(7,7) PRL(8,8) PRL(9,9) PRL(10,10) PRL(11,11)
    f32x4 aP = {0.f,0.f,0.f,0.f};
    PRC(0,0)  PRL(0,12)
    PRC(1,1)  PRL(1,13)
    PRC(2,2)  PRL(2,14)
    PRC(3,3)  PRL(3,15)
    PRC(4,4)  PRL(4,16)
    PRC(5,5)  PRL(5,17)
    PRC(6,6)  PRL(6,18)
    PRC(7,7)  PRL(7,19)
    PRC(8,8)  PRL(8,20)
    PRC(9,9)  PRL(9,21)
    PRC(10,10) PRL(10,22)
    PRC(11,11) PRL(11,23)
    PRC(0,12) PRL(0,24)
    PRC(1,13) PRL(1,25)
    PRC(2,14) PRL(2,26)
    PRC(3,15) PRL(3,27)
    PRC(4,16) PRL(4,28)
    PRC(5,17) PRL(5,29)
    PRC(6,18) PRL(6,30)
    PRC(7,19) PRL(7,31)
    PRC(8,20)
    PRC(9,21)
    PRC(10,22)
    PRC(11,23)
    PRC(0,24)
    PRC(1,25)
    PRC(2,26)
    PRC(3,27)
    PRC(4,28)
    PRC(5,29)
    PRC(6,30)
    PRC(7,31)
    const float pB = preb[ucol];
    #pragma unroll
    for (int r = 0; r < 4; ++r){
      int row = r0 + lb*4 + r;
      float v = fmaxf(aP[r] + pB, 0.f) + motion[(size_t)row*1024 + ucol];
      bf16 v16 = __float2bfloat16(v);
      __hip_atomic_store((unsigned short*)(hidpk + pwb + (size_t)(lb*4 + r)*32),
                         *(unsigned short*)&v16, __ATOMIC_RELAXED, __HIP_MEMORY_SCOPE_AGENT);
    }
  }
  VMWAIT(0);
  __syncthreads();
  if (tid == 0)
    __hip_atomic_store(&progH[bid], (unsigned)(dt+1), __ATOMIC_RELAXED, __HIP_MEMORY_SCOPE_AGENT);

  // ---- phase 3: W1 (hhpre = hid @ W1^T + b1), blocks 0..111 ----
  if (bid < 112){
    const int mq = bid / 28, ng = bid % 28;
    // wait on quarter-mq pre flags
    if (wave == 0){
      unsigned v = AL(&progH[mq*64 + lane]);
      while (__ballot(v >= (unsigned)(dt+1)) != ~0ULL){
        __builtin_amdgcn_s_sleep(2);
        v = AL(&progH[mq*64 + lane]);
      }
    }
    __syncthreads();
    __builtin_amdgcn_sched_barrier(0);

    const int r0w = mq*64 + wave*16;
    const int w1rb = r0w >> 5, w1y = wave & 1;
    const size_t w1abase = (size_t)w1rb*32768 + (size_t)w1y*512 + la*32 + lb*8;
    const bf16* w1b0 = w1pk + (size_t)(ng*4 + 0)*(32*512);
    const bf16* w1b1 = w1pk + (size_t)(ng*4 + 1)*(32*512);
    const bf16* w1b2 = w1pk + (size_t)(ng*4 + 2)*(32*512);
    const bf16* w1b3 = w1pk + (size_t)(ng*4 + 3)*(32*512);
    const float s0 = sb1[(ng*4+0)*16 + la];
    const float s1 = sb1[(ng*4+1)*16 + la];
    const float s2 = sb1[(ng*4+2)*16 + la];
    const float s3 = sb1[(ng*4+3)*16 + la];

    ull wa0,wa1,wa2,wa3, wb0,wb1,wb2,wb3;
    uint4 wq00,wq01,wq02,wq03, wq10,wq11,wq12,wq13;
    uint4 wq20,wq21,wq22,wq23, wq30,wq31,wq32,wq33;

    WLD(0,0) WLD(1,1) WLD(2,2) WLD(3,3)
    f32x4 c0 = {0.f,0.f,0.f,0.f}, c1 = c0, c2 = c0, c3 = c0;
    WCC(0) WLD(0,4)
    WCC(1) WLD(1,5)
    WCC(2) WLD(2,6)
    WCC(3) WLD(3,7)
    WCC(0) WLD(0,8)
    WCC(1) WLD(1,9)
    WCC(2) WLD(2,10)
    WCC(3) WLD(3,11)
    WCC(0) WLD(0,12)
    WCC(1) WLD(1,13)
    WCC(2) WLD(2,14)
    WCC(3) WLD(3,15)
    WCC(0) WLD(0,16)
    WCC(1) WLD(1,17)
    WCC(2) WLD(2,18)
    WCC(3) WLD(3,19)
    WCC(0) WLD(0,20)
    WCC(1) WLD(1,21)
    WCC(2) WLD(2,22)
    WCC(3) WLD(3,23)
    WCC(0) WLD(0,24)
    WCC(1) WLD(1,25)
    WCC(2) WLD(2,26)
    WCC(3) WLD(3,27)
    WCC(0) WLD(0,28)
    WCC(1) WLD(1,29)
    WCC(2) WLD(2,30)
    WCC(3) WLD(3,31)
    WCC(0)
    WCC(1)
    WCC(2)
    WCC(3)
    #pragma unroll
    for (int r = 0; r < 4; ++r){
      int row = r0w + lb*4 + r;
      hhpre_out[(size_t)row*1792 + (ng*4+0)*16 + la] = c0[r] + s0;
      hhpre_out[(size_t)row*1792 + (ng*4+1)*16 + la] = c1[r] + s1;
      hhpre_out[(size_t)row*1792 + (ng*4+2)*16 + la] = c2[r] + s2;
      hhpre_out[(size_t)row*1792 + (ng*4+3)*16 + la] = c3[r] + s3;
    }
  }
}

// ---------------- pipelined generic GEMM (preamble only) ----------------
__global__ __launch_bounds__(256) void gemm64(
    const bf16* __restrict__ Am, const bf16* __restrict__ Bm, int K,
    const float* __restrict__ bias, const float* __restrict__ addmat,
    float* __restrict__ C, bf16* __restrict__ Cbf, int N, int MODE)
{
  __shared__ bf16 As[3][64*64];
  __shared__ bf16 Bs[3][64*64];
  const int tid = threadIdx.x;
  const int wave = tid >> 6, lane = tid & 63;
  const int m0 = blockIdx.x*64, n0 = blockIdx.y*64;
  const int fr = lane & 31, kh = lane >> 5;
  const int wm = (wave >> 1)*32, wn = (wave & 1)*32;
  const int KT = K >> 6;

  f32x16 acc = {0.f,0.f,0.f,0.f,0.f,0.f,0.f,0.f,0.f,0.f,0.f,0.f,0.f,0.f,0.f,0.f};

  auto STAGE = [&](int buf, int kt){
    #pragma unroll
    for (int q = 0; q < 2; ++q){
      int idx = q*256 + tid;
      int row = idx >> 3, cp = idx & 7, csw = cp ^ (row & 7);
      GLD16(&As[buf][idx*8], Am + (size_t)(m0+row)*K + kt*64 + csw*8);
    }
    #pragma unroll
    for (int q = 0; q < 2; ++q){
      int idx = q*256 + tid;
      int row = idx >> 3, cp = idx & 7, csw = cp ^ (row & 7);
      GLD16(&Bs[buf][idx*8], Bm + (size_t)(n0+row)*K + kt*64 + csw*8);
    }
  };
  auto COMPUTE = [&](int buf){
    const bf16* Ab = &As[buf][0];
    const bf16* Bb = &Bs[buf][0];
    #pragma unroll
    for (int ks = 0; ks < 4; ++ks){
      int ca = ks*2 + kh;
      v8bf av = *(const v8bf*)&Ab[(wm+fr)*64 + ((ca ^ ((wm+fr)&7))*8)];
      v8bf bv = *(const v8bf*)&Bb[(wn+fr)*64 + ((ca ^ ((wn+fr)&7))*8)];
      acc = __builtin_amdgcn_mfma_f32_32x32x16_bf16(av, bv, acc, 0, 0, 0);
    }
  };

  STAGE(0, 0);
  if (KT > 1){ STAGE(1, 1); VMWAIT(4); } else { VMWAIT(0); }
  BARRIER();
  for (int kt = 0; kt < KT; ++kt){
    if (kt + 2 < KT) STAGE((kt+2)%3, kt+2);
    COMPUTE(kt%3);
    if (kt + 2 < KT){ VMWAIT(4); BARRIER(); }
    else if (kt + 1 < KT){ VMWAIT(0); BARRIER(); }
  }

  const int col = n0 + wn + fr;
  float bb = bias ? bias[col] : 0.f;
  #pragma unroll
  for (int r = 0; r < 16; ++r){
    int row = m0 + wm + (r&3) + 8*(r>>2) + 4*kh;
    float v = acc[r] + bb;
    if (MODE == 1) v = fmaxf(v, 0.f) + addmat[(size_t)row*N + col];
    if (C)   C[(size_t)row*N + col] = v;
    if (Cbf) Cbf[(size_t)row*N + col] = __float2bfloat16(v);
  }
}

// ---------------- attention: one block per (b,h) ----------------
__global__ __launch_bounds__(256) void k_attn(const bf16* __restrict__ qkv,
                                              bf16* __restrict__ ctxbf){
  __shared__ char smem[65536];
  bf16* qs = (bf16*)smem;
  bf16* ks = qs + 64*256;
  float* sc = (float*)smem;
  float* cs = (float*)(smem + 32768);
  const int h = blockIdx.x, b = blockIdx.y;
  const int tid = threadIdx.x, wave = tid >> 6, lane = tid & 63;
  const int fr = lane & 31, kh = lane >> 5;
  const int wm = (wave >> 1)*32, wn = (wave & 1)*32;

  #pragma unroll
  for (int i = 0; i < 8; ++i){
    int idx = i*256 + tid;
    int row = idx >> 5, cp = idx & 31, csw = cp ^ (row & 7);
    GLD16(&qs[idx*8], qkv + (size_t)(b*F_ + row)*3072 + h*DH_ + csw*8);
  }
  #pragma unroll
  for (int i = 0; i < 8; ++i){
    int idx = i*256 + tid;
    int row = idx >> 5, cp = idx & 31, csw = cp ^ (row & 7);
    GLD16(&ks[idx*8], qkv + (size_t)(b*F_ + row)*3072 + H_ + h*DH_ + csw*8);
  }
  __syncthreads();

  f32x16 acc = {0.f,0.f,0.f,0.f,0.f,0.f,0.f,0.f,0.f,0.f,0.f,0.f,0.f,0.f,0.f,0.f};
  #pragma unroll
  for (int i = 0; i < 16; ++i){
    int ca = i*2 + kh;
    v8bf av = *(const v8bf*)&qs[((wm+fr)*32 + (ca ^ ((wm+fr)&7)))*8];
    v8bf bv = *(const v8bf*)&ks[((wn+fr)*32 + (ca ^ ((wn+fr)&7)))*8];
    acc = __builtin_amdgcn_mfma_f32_32x32x16_bf16(av, bv, acc, 0, 0, 0);
  }
  __syncthreads();
  #pragma unroll
  for (int r = 0; r < 16; ++r){
    int row = wm + (r&3) + 8*(r>>2) + 4*kh;
    sc[row*65 + (wn+fr)] = acc[r]*0.0625f;
  }
  __syncthreads();
  if (tid < F_){
    float m = -1e30f;
    for (int k2 = 0; k2 < F_; ++k2) m = fmaxf(m, sc[tid*65+k2]);
    float s = 0.f;
    for (int k2 = 0; k2 < F_; ++k2){ float e = __expf(sc[tid*65+k2]-m); sc[tid*65+k2] = e; s += e; }
    float is = 1.f/s;
    for (int k2 = 0; k2 < F_; ++k2) sc[tid*65+k2] *= is;
  }
  __syncthreads();
  if (tid < F_){
    float s = 0.f;
    for (int r = 0; r < F_; ++r) s += sc[r*65+tid];
    cs[tid] = s;
  }
  __syncthreads();
  float a = 0.f;
  for (int k2 = 0; k2 < F_; ++k2){
    float v = __bfloat162float(qkv[(size_t)(b*F_+k2)*3072 + 2*H_ + h*DH_ + tid]);
    a += cs[k2]*v;
  }
  ctxbf[(size_t)b*H_ + h*DH_ + tid] = __float2bfloat16(a * (1.f/61.f));
}

// ---------------- SPL final step ----------------
__global__ __launch_bounds__(128) void spl_all(const float* __restrict__ hh_pre, const float* __restrict__ w1par,
                        const float* __restrict__ W2, const float* __restrict__ b2,
                        float* __restrict__ x, bf16* __restrict__ xpk,
                        float* __restrict__ out, int tstep){
  __shared__ float preds_s[4][128];
  __shared__ float hh_s[128][5];
  int b0 = blockIdx.x*4, t = threadIdx.x;   // grid 64, block 128
  for (int L = 0; L < 3; ++L){
    for (int ji = LVO[L]; ji < LVO[L+1]; ++ji){
      int j = LVJ[ji], p = PAR_[j];
      float acc[4];
      #pragma unroll
      for (int bb = 0; bb < 4; ++bb) acc[bb] = hh_pre[(size_t)(b0+bb)*1792 + j*128 + t];
      if (p >= 0){
        #pragma unroll
        for (int ii = 0; ii < 9; ++ii){
          float w = w1par[(j*9 + ii)*128 + t];
          #pragma unroll
          for (int bb = 0; bb < 4; ++bb) acc[bb] += w * preds_s[bb][p*9 + ii];
        }
      }
      #pragma unroll
      for (int bb = 0; bb < 4; ++bb) hh_s[t][bb] = fmaxf(acc[bb], 0.f);
      __syncthreads();
      if (t < 72){
        int pp = t >> 1, half = t & 1;
        int bb = pp/9, oi = pp%9;
        const float* w2r = W2 + (size_t)(j*9 + oi)*128 + half*64;
        float s = 0.f;
        #pragma unroll
        for (int tt = 0; tt < 64; ++tt) s += hh_s[half*64 + tt][bb] * w2r[tt];
        s += __shfl_xor(s, 1);
        if (half == 0) preds_s[bb][j*9 + oi] = tanhf(s + b2[j*9 + oi]);
      }
      __syncthreads();
    }
  }
  for (int i = t; i < 4*D_; i += 128){
    int bb = i / D_, d = i % D_;
    int row = b0 + bb;
    size_t xi = (size_t)row*D_ + d;
    float v = x[xi] + preds_s[bb][d];
    x[xi] = v;
    xpk[((row>>5)*4 + (d>>5))*1024 + (row&31)*32 + (d&31)] = __float2bfloat16(v);
    out[((size_t)row*PRED_ + tstep)*D_ + d] = v;
  }
}

// ---------------- launch ----------------
extern "C" void kernel_launch(void* const* d_in, const int* in_sizes, int n_in,
                              void* d_out, int out_size, void* d_ws, size_t ws_size,
                              hipStream_t stream){
  (void)in_sizes; (void)n_in; (void)out_size; (void)ws_size;
  const float* poses = (const float*)d_in[0];
  const float* gWih  = (const float*)d_in[1];
  const float* gWhh  = (const float*)d_in[2];
  const float* gbih  = (const float*)d_in[3];
  const float* gbhh  = (const float*)d_in[4];
  const float* preW  = (const float*)d_in[5];
  const float* preb  = (const float*)d_in[6];
  const float* fpW   = (const float*)d_in[7];
  const float* fpb   = (const float*)d_in[8];
  const float* inW   = (const float*)d_in[9];
  const float* inb   = (const float*)d_in[10];
  const float* outW  = (const float*)d_in[11];
  const float* outb  = (const float*)d_in[12];
  const float* sW1   = (const float*)d_in[13];
  const float* sb1   = (const float*)d_in[14];
  const float* sW2   = (const float*)d_in[15];
  const float* sb2   = (const float*)d_in[16];
  float* out = (float*)d_out;

  char* w = (char*)d_ws;
  size_t off = 0;
  auto alloc = [&](size_t bytes)->char*{ char* p = w + off; off += (bytes + 255) & ~(size_t)255; return p; };
  float* cosT   = (float*)alloc(7320*4);
  float* bc     = (float*)alloc(3072*4);
  float* motion = (float*)alloc((size_t)256*1024*4);
  float* hA     = (float*)alloc((size_t)256*1024*4);
  float* hB     = (float*)alloc((size_t)256*1024*4);
  float* xcur   = (float*)alloc((size_t)256*126*4);
  float* hhpre  = (float*)alloc((size_t)256*1792*4);
  float* bcat   = (float*)alloc(4096*4);
  float* w1par  = (float*)alloc(14*9*128*4);
  unsigned* prog= (unsigned*)alloc(4096);
  bf16* posespk = (bf16*)alloc((size_t)121*32768*2);
  bf16* Wcat    = (bf16*)alloc((size_t)4096*1152*2);
  bf16* Wpk     = (bf16*)alloc((size_t)64*108*512*2);
  bf16* prepk   = (bf16*)alloc((size_t)64*32*512*2);
  bf16* w1pk    = (bf16*)alloc((size_t)112*32*512*2);
  bf16* outbf   = (bf16*)alloc((size_t)1024*1024*2);
  bf16* inbf    = (bf16*)alloc((size_t)3072*1024*2);
  bf16* fpwt    = (bf16*)alloc((size_t)128*1024*2);
  bf16* ctxbf   = (bf16*)alloc((size_t)256*1024*2);
  bf16* hpkA    = (bf16*)alloc((size_t)256*1024*2);
  bf16* hpkB    = (bf16*)alloc((size_t)256*1024*2);
  bf16* hidpk   = (bf16*)alloc((size_t)256*1024*2);
  bf16* xpk     = (bf16*)alloc((size_t)32768*2);
  bf16* Wcbf    = (bf16*)alloc((size_t)3072*128*2);
  bf16* freqbf  = (bf16*)alloc((size_t)B_*F_*128*2);
  bf16* qkvbf   = (bf16*)alloc((size_t)15680*3072*2);

  hipMemsetAsync(hpkA, 0, (size_t)256*1024*2, stream);
  hipMemsetAsync(prog, 0, 4096, stream);

  k_cos<<<29, 256, 0, stream>>>(cosT);
  k_dft2<<<B_, 256, 0, stream>>>(poses, cosT, freqbf);
  c_poses<<<dim3(SEED_, B_), 128, 0, stream>>>(poses, posespk);
  c_xinit<<<B_, 128, 0, stream>>>(poses, xcur, xpk);
  c_wcat<<<4096, 256, 0, stream>>>(gWih, gWhh, Wcat);
  c_bcat<<<16, 256, 0, stream>>>(gbih, gbhh, bcat);
  c_wpk<<<1728, 256, 0, stream>>>(Wcat, Wpk);
  c_ppk<<<512, 256, 0, stream>>>(preW, prepk);
  c_w1pk<<<896, 256, 0, stream>>>(sW1, w1pk);
  c_w1par<<<63, 256, 0, stream>>>(sW1, w1par);
  c_bf<<<4096, 256, 0, stream>>>(outW, outbf, 1024*1024);
  c_bf<<<12288, 256, 0, stream>>>(inW, inbf, 3072*1024);
  c_fpwt<<<128, 256, 0, stream>>>(fpW, fpwt);
  k_bc<<<768, 256, 0, stream>>>(inW, inb, fpb, bc);

  // Wc = inproj @ fp_W  (3072 x 128, bf16)
  gemm64<<<dim3(48, 2), 256, 0, stream>>>(inbf, fpwt, 1024, nullptr, nullptr, nullptr, Wcbf, 128, 0);
  // qkv = freq @ Wc^T + bc  (15616 x 3072, bf16)
  gemm64<<<dim3(244, 48), 256, 0, stream>>>(freqbf, Wcbf, 128, bc, nullptr, nullptr, qkvbf, 3072, 0);
  k_attn<<<dim3(HEADS_, B_), 256, 0, stream>>>(qkvbf, ctxbf);
  // motion_ctx = ctx_mean @ outproj^T + outb
  gemm64<<<dim3(4, 16), 256, 0, stream>>>(ctxbf, outbf, 1024, outb, nullptr, motion, nullptr, 1024, 0);

  // encoder: cooperative, 256 blocks x 256 threads (all CUs), fence-free coherent h
  {
    const bf16* a0 = posespk; int a1 = 32768; int a2 = SEED_; int a3 = 1;
    const bf16* a4 = Wpk; const float* a5 = bcat;
    const float* a6 = hA; float* a7 = hA; bf16* a8 = nullptr;
    bf16* a9 = hpkA; bf16* a10 = hpkB; unsigned* a11 = prog;
    void* args[] = { &a0, &a1, &a2, &a3, &a4, &a5, &a6, &a7, &a8, &a9, &a10, &a11 };
    hipLaunchCooperativeKernel(reinterpret_cast<void*>(gru_wave), dim3(256), dim3(256),
                               args, 0, stream);
  }

  float* hc = hA;  float* hn = hB;
  bf16* hpc = hpkA; bf16* hpn = hpkB;
  unsigned* progS = prog + 256;
  unsigned* progG = prog + 512;
  unsigned* progH = prog + 768;

  // decoder: 24 steps x one merged dec_step; final SPL
  for (int t = 0; t < PRED_; ++t){
    dec_step<<<256, 256, 0, stream>>>(xpk, Wpk, bcat, hc, hn, hpc, hpn,
                                      hhpre, hhpre, w1par, sW2, sb2,
                                      prepk, preb, motion, hidpk, w1pk, sb1,
                                      xcur, xpk, out, t, progS, progG, progH);
    { float* tf = hc; hc = hn; hn = tf; bf16* tb = hpc; hpc = hpn; hpn = tb; }
  }
  spl_all<<<64, 128, 0, stream>>>(hhpre, w1par, sW2, sb2, xcur, xpk, out, PRED_-1);
}